// Round 3
// baseline (14257.451 us; speedup 1.0000x reference)
//
#include <hip/hip_runtime.h>
#include <hip/hip_bf16.h>

#define H 256
#define NACC 100000
#define NTX  300000
#define NE   600000
#define NM   300000
#define BK 16

typedef unsigned short u16;
typedef unsigned int u32;

__device__ __forceinline__ float bf2f(u32 u) {
    union { u32 i; float f; } v; v.i = u << 16; return v.f;
}
__device__ __forceinline__ u16 f2bf(float f) {
    union { float f; u32 i; } v; v.f = f;
    u32 r = v.i + 0x7FFFu + ((v.i >> 16) & 1u);
    return (u16)(r >> 16);
}

// ---------------- zero fill ----------------
__global__ void fillz_kernel(u32* __restrict__ p, long long n) {
    long long i = (long long)blockIdx.x * blockDim.x + threadIdx.x;
    long long st = (long long)gridDim.x * blockDim.x;
    for (; i < n; i += st) p[i] = 0u;
}

// ---------------- input projection: out = relu(x @ W.T + b) as bf16 ----------------
__global__ void proj_kernel(const float* __restrict__ x, const float* __restrict__ W,
                            const float* __restrict__ b, u16* __restrict__ out,
                            int N, int K) {
    __shared__ float xs[32];
    int n = blockIdx.x;
    int t = threadIdx.x;
    if (t < K) xs[t] = x[(size_t)n * K + t];
    __syncthreads();
    float s = b[t];
    for (int k = 0; k < K; k += 4) {
        float4 w = *(const float4*)(W + (size_t)t * K + k);
        s += xs[k] * w.x + xs[k + 1] * w.y + xs[k + 2] * w.z + xs[k + 3] * w.w;
    }
    out[(size_t)n * H + t] = f2bf(fmaxf(s, 0.0f));
}

// ---------------- CSR build: count, scan (3 kernels), fill ----------------
__global__ void count_kernel(const int* __restrict__ dst, int E, int* __restrict__ cnt) {
    int e = blockIdx.x * blockDim.x + threadIdx.x;
    if (e < E) atomicAdd(&cnt[dst[e]], 1);
}

// per-block (1024 items, 256 thr x 4) local exclusive scan into loc; block totals into bsum
__global__ void scan1_kernel(const int* __restrict__ cnt, int N,
                             int* __restrict__ loc, int* __restrict__ bsum) {
    __shared__ int sh[256];
    int b = blockIdx.x, t = threadIdx.x;
    int base = b * 1024 + t * 4;
    int v0 = (base + 0 < N) ? cnt[base + 0] : 0;
    int v1 = (base + 1 < N) ? cnt[base + 1] : 0;
    int v2 = (base + 2 < N) ? cnt[base + 2] : 0;
    int v3 = (base + 3 < N) ? cnt[base + 3] : 0;
    int s = v0 + v1 + v2 + v3;
    sh[t] = s;
    __syncthreads();
    for (int o = 1; o < 256; o <<= 1) {
        int y = (t >= o) ? sh[t - o] : 0;
        __syncthreads();
        sh[t] += y;
        __syncthreads();
    }
    int run = sh[t] - s;  // exclusive prefix of this thread's quad within block
    if (base + 0 < N) loc[base + 0] = run; run += v0;
    if (base + 1 < N) loc[base + 1] = run; run += v1;
    if (base + 2 < N) loc[base + 2] = run; run += v2;
    if (base + 3 < N) loc[base + 3] = run;
    if (t == 0) bsum[b] = sh[255];
}

__global__ void scan2_kernel(int* __restrict__ bsum, int nb) {
    __shared__ int sh[1024];
    int t = threadIdx.x;
    int v = (t < nb) ? bsum[t] : 0;
    sh[t] = v;
    __syncthreads();
    for (int o = 1; o < 1024; o <<= 1) {
        int y = (t >= o) ? sh[t - o] : 0;
        __syncthreads();
        sh[t] += y;
        __syncthreads();
    }
    if (t < nb) bsum[t] = sh[t] - v;  // exclusive
}

__global__ void scan3_kernel(int* __restrict__ ptr, const int* __restrict__ bsum,
                             int N, int total) {
    int i = blockIdx.x * blockDim.x + threadIdx.x;
    if (i < N) ptr[i] += bsum[i >> 10];
    else if (i == N) ptr[N] = total;
}

__global__ void fillcsr_kernel(const int* __restrict__ src, const int* __restrict__ dst, int E,
                               const int* __restrict__ ptr, int* __restrict__ cur,
                               int* __restrict__ perm) {
    int e = blockIdx.x * blockDim.x + threadIdx.x;
    if (e < E) {
        int d = dst[e];
        int pos = ptr[d] + atomicAdd(&cur[d], 1);
        perm[pos] = src[e];
    }
}

__global__ void invcnt_kernel(const int* __restrict__ cnt, float* __restrict__ inv, int N) {
    int i = blockIdx.x * blockDim.x + threadIdx.x;
    if (i < N) inv[i] = 1.0f / (float)max(cnt[i], 1);
}

// ---------------- gather-mean: out[w] = mean_{s in CSR[lo+w]} feat[s]  (bf16 in/out) ----------------
__launch_bounds__(256)
__global__ void gmean_kernel(const u16* __restrict__ feat, const int* __restrict__ ptr,
                             const int* __restrict__ perm, u16* __restrict__ outm,
                             int rows, int lo) {
    int w = (blockIdx.x << 2) + (threadIdx.x >> 6);
    if (w >= rows) return;
    int lane = threadIdx.x & 63;
    int d = lo + w;
    int e0 = ptr[d], e1 = ptr[d + 1];
    float a0 = 0.f, a1 = 0.f, a2 = 0.f, a3 = 0.f;
    for (int e = e0; e < e1; ++e) {
        int s = perm[e];
        uint2 v = *(const uint2*)(feat + (size_t)s * H + (lane << 2));
        a0 += bf2f(v.x & 0xffff); a1 += bf2f(v.x >> 16);
        a2 += bf2f(v.y & 0xffff); a3 += bf2f(v.y >> 16);
    }
    int deg = e1 - e0;
    float sc = (deg > 0) ? (1.0f / (float)deg) : 0.0f;
    uint2 pk;
    pk.x = (u32)f2bf(a0 * sc) | ((u32)f2bf(a1 * sc) << 16);
    pk.y = (u32)f2bf(a2 * sc) | ((u32)f2bf(a3 * sc) << 16);
    *(uint2*)(outm + (size_t)w * H + (lane << 2)) = pk;
}

// ---------------- edge-parallel scatter (src-chunked): agg[dst] += feat[src-lo] ----------------
__global__ void scatter_src_kernel(const u16* __restrict__ feat, const int* __restrict__ src,
                                   const int* __restrict__ dst, float* __restrict__ agg,
                                   int E, int lo, int hi) {
    int idx = blockIdx.x * blockDim.x + threadIdx.x;
    int e = idx >> 5;
    if (e >= E) return;
    int s = src[e];
    if (s < lo || s >= hi) return;
    int d = dst[e];
    int c = (idx & 31) << 3;
    uint4 v = *(const uint4*)(feat + (size_t)(s - lo) * H + c);
    float* dp = agg + (size_t)d * H + c;
    atomicAdd(dp + 0, bf2f(v.x & 0xffff)); atomicAdd(dp + 1, bf2f(v.x >> 16));
    atomicAdd(dp + 2, bf2f(v.y & 0xffff)); atomicAdd(dp + 3, bf2f(v.y >> 16));
    atomicAdd(dp + 4, bf2f(v.z & 0xffff)); atomicAdd(dp + 5, bf2f(v.z >> 16));
    atomicAdd(dp + 6, bf2f(v.w & 0xffff)); atomicAdd(dp + 7, bf2f(v.w >> 16));
}

// ---------------- fused SAGE combine (row-stripe, in-place-safe) ----------------
// MODE 0: A-left = agg(fp32) * invc[row]; MODE 1: A-left = mean(bf16)
template <int MODE>
__launch_bounds__(256)
__global__ void combine_kernel(const void* __restrict__ aggv, const float* __restrict__ invc,
                               const u16* __restrict__ xd,
                               const float* __restrict__ Wl, const float* __restrict__ Wr,
                               const float* __restrict__ bl,
                               const float* __restrict__ bng, const float* __restrict__ bnb,
                               const float* __restrict__ bnm, const float* __restrict__ bnv,
                               u16* __restrict__ outF, int rows) {
    __shared__ float As[BK][68];
    __shared__ float Bs[BK][260];
    int tid = threadIdx.x;
    int row0 = blockIdx.x * 64;
    int rs = tid >> 2, kq = (tid & 3) << 2;
    int grow = row0 + rs;
    bool rok = grow < rows;
    float inv = (MODE == 0 && rok) ? invc[grow] : 0.0f;
    int tr = tid >> 4, tc = tid & 15;
    float acc[4][16];
#pragma unroll
    for (int i = 0; i < 4; ++i)
#pragma unroll
        for (int j = 0; j < 16; ++j) acc[i][j] = 0.0f;

    for (int kb = 0; kb < 512; kb += BK) {
        {
            int kg = kb + kq;
            float a0, a1, a2, a3;
            if (!rok) { a0 = a1 = a2 = a3 = 0.0f; }
            else if (kg < 256) {
                if (MODE == 0) {
                    float4 v = *(const float4*)((const float*)aggv + (size_t)grow * H + kg);
                    a0 = v.x * inv; a1 = v.y * inv; a2 = v.z * inv; a3 = v.w * inv;
                } else {
                    uint2 v = *(const uint2*)((const u16*)aggv + (size_t)grow * H + kg);
                    a0 = bf2f(v.x & 0xffff); a1 = bf2f(v.x >> 16);
                    a2 = bf2f(v.y & 0xffff); a3 = bf2f(v.y >> 16);
                }
            } else {
                uint2 v = *(const uint2*)(xd + (size_t)grow * H + (kg - 256));
                a0 = bf2f(v.x & 0xffff); a1 = bf2f(v.x >> 16);
                a2 = bf2f(v.y & 0xffff); a3 = bf2f(v.y >> 16);
            }
            As[kq + 0][rs] = a0; As[kq + 1][rs] = a1;
            As[kq + 2][rs] = a2; As[kq + 3][rs] = a3;
        }
        {
            const float* Wsrc = (kb < 256) ? Wl : Wr;
            const float* p = Wsrc + (size_t)tid * H + (kb & 255);
#pragma unroll
            for (int q = 0; q < 4; ++q) {
                float4 w = *(const float4*)(p + (q << 2));
                Bs[(q << 2) + 0][tid] = w.x; Bs[(q << 2) + 1][tid] = w.y;
                Bs[(q << 2) + 2][tid] = w.z; Bs[(q << 2) + 3][tid] = w.w;
            }
        }
        __syncthreads();
#pragma unroll
        for (int k = 0; k < BK; ++k) {
            float4 a = *(const float4*)(&As[k][tr << 2]);
            float av[4] = { a.x, a.y, a.z, a.w };
#pragma unroll
            for (int j = 0; j < 4; ++j) {
                float4 b = *(const float4*)(&Bs[k][(j << 6) + (tc << 2)]);
                float bv[4] = { b.x, b.y, b.z, b.w };
#pragma unroll
                for (int i = 0; i < 4; ++i)
#pragma unroll
                    for (int c = 0; c < 4; ++c)
                        acc[i][(j << 2) + c] += av[i] * bv[c];
            }
        }
        __syncthreads();
    }
#pragma unroll
    for (int j = 0; j < 4; ++j) {
        int cb = (j << 6) + (tc << 2);
        float4 blv = *(const float4*)(bl + cb);
        float4 g   = *(const float4*)(bng + cb);
        float4 be  = *(const float4*)(bnb + cb);
        float4 mm  = *(const float4*)(bnm + cb);
        float4 vv  = *(const float4*)(bnv + cb);
        float s0 = g.x * rsqrtf(vv.x + 1e-5f);
        float s1 = g.y * rsqrtf(vv.y + 1e-5f);
        float s2 = g.z * rsqrtf(vv.z + 1e-5f);
        float s3 = g.w * rsqrtf(vv.w + 1e-5f);
#pragma unroll
        for (int i = 0; i < 4; ++i) {
            int r = row0 + (tr << 2) + i;
            if (r < rows) {
                float o0 = fmaxf((acc[i][(j << 2) + 0] + blv.x - mm.x) * s0 + be.x, 0.0f);
                float o1 = fmaxf((acc[i][(j << 2) + 1] + blv.y - mm.y) * s1 + be.y, 0.0f);
                float o2 = fmaxf((acc[i][(j << 2) + 2] + blv.z - mm.z) * s2 + be.z, 0.0f);
                float o3 = fmaxf((acc[i][(j << 2) + 3] + blv.w - mm.w) * s3 + be.w, 0.0f);
                uint2 pk;
                pk.x = (u32)f2bf(o0) | ((u32)f2bf(o1) << 16);
                pk.y = (u32)f2bf(o2) | ((u32)f2bf(o3) << 16);
                *(uint2*)(outF + (size_t)r * H + cb) = pk;
            }
        }
    }
}

// ---------------- fused edge MLP head (row-stripe, K=544, shuffle-reduced W2 dot) ----------------
__launch_bounds__(256)
__global__ void mlp_kernel(const u16* __restrict__ accF, const int* __restrict__ sidx,
                           const int* __restrict__ ridx, const float* __restrict__ txr,
                           const float* __restrict__ W1, const float* __restrict__ b1,
                           const float* __restrict__ W2, const float* __restrict__ b2,
                           float* __restrict__ out, int M) {
    __shared__ float As[BK][68];
    __shared__ float Bs[BK][260];
    int tid = threadIdx.x;
    int row0 = blockIdx.x * 64;
    int rs = tid >> 2, kq = (tid & 3) << 2;
    int grow = row0 + rs;
    bool rok = grow < M;
    int si = rok ? sidx[grow] : 0;
    int ri = rok ? ridx[grow] : 0;
    int tr = tid >> 4, tc = tid & 15;
    float acc[4][16];
#pragma unroll
    for (int i = 0; i < 4; ++i)
#pragma unroll
        for (int j = 0; j < 16; ++j) acc[i][j] = 0.0f;

    for (int kb = 0; kb < 544; kb += BK) {
        {
            int kg = kb + kq;
            float a0, a1, a2, a3;
            if (!rok) { a0 = a1 = a2 = a3 = 0.0f; }
            else if (kg < 256) {
                uint2 v = *(const uint2*)(accF + (size_t)si * H + kg);
                a0 = bf2f(v.x & 0xffff); a1 = bf2f(v.x >> 16);
                a2 = bf2f(v.y & 0xffff); a3 = bf2f(v.y >> 16);
            } else if (kg < 512) {
                uint2 v = *(const uint2*)(accF + (size_t)ri * H + (kg - 256));
                a0 = bf2f(v.x & 0xffff); a1 = bf2f(v.x >> 16);
                a2 = bf2f(v.y & 0xffff); a3 = bf2f(v.y >> 16);
            } else {
                float4 v = *(const float4*)(txr + (size_t)grow * 32 + (kg - 512));
                a0 = v.x; a1 = v.y; a2 = v.z; a3 = v.w;
            }
            As[kq + 0][rs] = a0; As[kq + 1][rs] = a1;
            As[kq + 2][rs] = a2; As[kq + 3][rs] = a3;
        }
        {
            const float* p = W1 + (size_t)tid * 544 + kb;
#pragma unroll
            for (int q = 0; q < 4; ++q) {
                float4 w = *(const float4*)(p + (q << 2));
                Bs[(q << 2) + 0][tid] = w.x; Bs[(q << 2) + 1][tid] = w.y;
                Bs[(q << 2) + 2][tid] = w.z; Bs[(q << 2) + 3][tid] = w.w;
            }
        }
        __syncthreads();
#pragma unroll
        for (int k = 0; k < BK; ++k) {
            float4 a = *(const float4*)(&As[k][tr << 2]);
            float av[4] = { a.x, a.y, a.z, a.w };
#pragma unroll
            for (int j = 0; j < 4; ++j) {
                float4 b = *(const float4*)(&Bs[k][(j << 6) + (tc << 2)]);
                float bv[4] = { b.x, b.y, b.z, b.w };
#pragma unroll
                for (int i = 0; i < 4; ++i)
#pragma unroll
                    for (int c = 0; c < 4; ++c)
                        acc[i][(j << 2) + c] += av[i] * bv[c];
            }
        }
        __syncthreads();
    }
    float partial[4] = { 0.f, 0.f, 0.f, 0.f };
#pragma unroll
    for (int j = 0; j < 4; ++j) {
        int cb = (j << 6) + (tc << 2);
        float4 b1v = *(const float4*)(b1 + cb);
        float4 w2v = *(const float4*)(W2 + cb);
#pragma unroll
        for (int i = 0; i < 4; ++i) {
            partial[i] += fmaxf(acc[i][(j << 2) + 0] + b1v.x, 0.0f) * w2v.x
                        + fmaxf(acc[i][(j << 2) + 1] + b1v.y, 0.0f) * w2v.y
                        + fmaxf(acc[i][(j << 2) + 2] + b1v.z, 0.0f) * w2v.z
                        + fmaxf(acc[i][(j << 2) + 3] + b1v.w, 0.0f) * w2v.w;
        }
    }
    float bias = b2[0];
#pragma unroll
    for (int i = 0; i < 4; ++i) {
        float p = partial[i];
        p += __shfl_xor(p, 1);
        p += __shfl_xor(p, 2);
        p += __shfl_xor(p, 4);
        p += __shfl_xor(p, 8);
        int r = row0 + (tr << 2) + i;
        if (tc == 0 && r < M) out[r] = p + bias;
    }
}

// ---------------- host ----------------
static inline void fz(void* p, size_t bytes, hipStream_t s) {
    long long n = (long long)(bytes >> 2);
    int g = (int)(((n + 255) / 256 < 2048) ? (n + 255) / 256 : 2048);
    fillz_kernel<<<g, 256, 0, s>>>((u32*)p, n);
}

extern "C" void kernel_launch(void* const* d_in, const int* in_sizes, int n_in,
                              void* d_out, int out_size, void* d_ws, size_t ws_size,
                              hipStream_t stream) {
    const float* x_acc  = (const float*)d_in[0];
    const float* x_tx   = (const float*)d_in[1];
    const float* tx_raw = (const float*)d_in[2];
    const int* ei_sends = (const int*)d_in[3];
    const int* ei_recv  = (const int*)d_in[4];
    const int* sidx     = (const int*)d_in[5];
    const int* ridx     = (const int*)d_in[6];
    const float* W_acc  = (const float*)d_in[7];
    const float* b_acc  = (const float*)d_in[8];
    const float* W_tx   = (const float*)d_in[9];
    const float* b_tx   = (const float*)d_in[10];
    const float* Wl_at  = (const float*)d_in[11];
    const float* bl_at  = (const float*)d_in[12];
    const float* Wr_at  = (const float*)d_in[13];
    const float* Wl_ta  = (const float*)d_in[14];
    const float* bl_ta  = (const float*)d_in[15];
    const float* Wr_ta  = (const float*)d_in[16];
    const float* bng    = (const float*)d_in[17];
    const float* bnb    = (const float*)d_in[18];
    const float* bnm    = (const float*)d_in[19];
    const float* bnv    = (const float*)d_in[20];
    const float* W1     = (const float*)d_in[21];
    const float* b1     = (const float*)d_in[22];
    const float* W2     = (const float*)d_in[23];
    const float* b2     = (const float*)d_in[24];
    float* out = (float*)d_out;

    char* wsp = (char*)d_ws;
    size_t off = 0;
    auto alloc = [&](size_t bytes) -> void* {
        void* p = wsp + off;
        off = (off + bytes + 255) & ~(size_t)255;
        return p;
    };

    // common buffers (~107.7 MB)
    u16* A0f  = (u16*)alloc((size_t)NACC * H * 2);
    u16* A1f  = (u16*)alloc((size_t)NACC * H * 2);
    int* cntA = (int*)alloc((size_t)(NACC + 1) * 4);
    int* bsum = (int*)alloc(4096);
    int* cntT = (int*)alloc((size_t)(NTX + 1) * 4);
    int* ptrT = (int*)alloc((size_t)(NTX + 1) * 4);
    int* permS = (int*)alloc((size_t)NE * 4);

    const bool big = ws_size >= 322000000ull;
    const int EG = (NE + 255) / 256;
    const int nbA = (NACC + 1023) / 1024, nbT = (NTX + 1023) / 1024;

    // sends CSR (dst = tx) — used by both plans
    fz(cntT, (size_t)NTX * 4, stream);
    count_kernel<<<EG, 256, 0, stream>>>(ei_sends + NE, NE, cntT);
    scan1_kernel<<<nbT, 256, 0, stream>>>(cntT, NTX, ptrT, bsum);
    scan2_kernel<<<1, 1024, 0, stream>>>(bsum, nbT);
    scan3_kernel<<<(NTX + 256) / 256 + 1, 256, 0, stream>>>(ptrT, bsum, NTX, NE);
    fz(cntT, (size_t)NTX * 4, stream);
    fillcsr_kernel<<<EG, 256, 0, stream>>>(ei_sends, ei_sends + NE, NE, ptrT, cntT, permS);

    // acc projection
    proj_kernel<<<NACC, 256, 0, stream>>>(x_acc, W_acc, b_acc, A0f, NACC, 16);

    if (big) {
        // -------- PLAN BIG: full T features, CSR gather everywhere, no float atomics --------
        u16* T0f   = (u16*)alloc((size_t)NTX * H * 2);
        u16* meanA = (u16*)alloc((size_t)NACC * H * 2);
        int* ptrA  = (int*)alloc((size_t)(NACC + 1) * 4);
        int* permR = (int*)alloc((size_t)NE * 4);
        size_t rem = (ws_size > off + 1048576) ? ws_size - off - 1048576 : 0;
        long long Cll = (long long)(rem / ((size_t)H * 2));
        int C = (Cll > NTX) ? NTX : (int)Cll;
        if (C < 2048) C = 2048;
        u16* meanTc = (u16*)alloc((size_t)C * H * 2);

        // recv CSR (dst = acc)
        fz(cntA, (size_t)NACC * 4, stream);
        count_kernel<<<EG, 256, 0, stream>>>(ei_recv + NE, NE, cntA);
        scan1_kernel<<<nbA, 256, 0, stream>>>(cntA, NACC, ptrA, bsum);
        scan2_kernel<<<1, 1024, 0, stream>>>(bsum, nbA);
        scan3_kernel<<<(NACC + 256) / 256 + 1, 256, 0, stream>>>(ptrA, bsum, NACC, NE);
        fz(cntA, (size_t)NACC * 4, stream);
        fillcsr_kernel<<<EG, 256, 0, stream>>>(ei_recv, ei_recv + NE, NE, ptrA, cntA, permR);

        // tx projection
        proj_kernel<<<NTX, 256, 0, stream>>>(x_tx, W_tx, b_tx, T0f, NTX, 32);

        // L0 acc: mean over recv of T0, combine -> A1f
        gmean_kernel<<<(NACC + 3) / 4, 256, 0, stream>>>(T0f, ptrA, permR, meanA, NACC, 0);
        combine_kernel<1><<<(NACC + 63) / 64, 256, 0, stream>>>(
            meanA, nullptr, A0f, Wl_ta, Wr_ta, bl_ta, bng, bnb, bnm, bnv, A1f, NACC);

        // L0 tx: per chunk, mean over sends of A0, combine in place (T0 -> T1)
        for (int lo = 0; lo < NTX; lo += C) {
            int cur = (NTX - lo < C) ? (NTX - lo) : C;
            gmean_kernel<<<(cur + 3) / 4, 256, 0, stream>>>(A0f, ptrT, permS, meanTc, cur, lo);
            combine_kernel<1><<<(cur + 63) / 64, 256, 0, stream>>>(
                meanTc, nullptr, T0f + (size_t)lo * H, Wl_at, Wr_at, bl_at,
                bng, bnb, bnm, bnv, T0f + (size_t)lo * H, cur);
        }

        // L1 acc: mean over recv of T1, combine -> A0f (reuse)
        gmean_kernel<<<(NACC + 3) / 4, 256, 0, stream>>>(T0f, ptrA, permR, meanA, NACC, 0);
        combine_kernel<1><<<(NACC + 63) / 64, 256, 0, stream>>>(
            meanA, nullptr, A1f, Wl_ta + H * H, Wr_ta + H * H, bl_ta + H,
            bng + H, bnb + H, bnm + H, bnv + H, A0f, NACC);

        mlp_kernel<<<(NM + 63) / 64, 256, 0, stream>>>(
            A0f, sidx, ridx, tx_raw, W1, b1, W2, b2, out, NM);
    } else {
        // -------- PLAN SMALL: tx chunks on the fly, fp32 atomic scatter into one acc agg --------
        float* aggA = (float*)alloc((size_t)NACC * H * 4);
        float* invA = (float*)alloc((size_t)NACC * 4);
        size_t rem = (ws_size > off + 1048576) ? ws_size - off - 1048576 : 0;
        long long Cll = (long long)(rem / ((size_t)H * 4));  // T0c + meanTc, bf16 each
        int C = (Cll > NTX) ? NTX : (int)Cll;
        if (C < 2048) C = 2048;
        u16* T0c    = (u16*)alloc((size_t)C * H * 2);
        u16* meanTc = (u16*)alloc((size_t)C * H * 2);

        // acc in-degree -> inv
        fz(cntA, (size_t)NACC * 4, stream);
        count_kernel<<<EG, 256, 0, stream>>>(ei_recv + NE, NE, cntA);
        invcnt_kernel<<<(NACC + 255) / 256, 256, 0, stream>>>(cntA, invA, NACC);

        const int SGG = (NE * 32 + 255) / 256;

        // pass 1: L0 acc aggregation from on-the-fly T0 chunks
        fz(aggA, (size_t)NACC * H * 4, stream);
        for (int lo = 0; lo < NTX; lo += C) {
            int cur = (NTX - lo < C) ? (NTX - lo) : C;
            proj_kernel<<<cur, 256, 0, stream>>>(x_tx + (size_t)lo * 32, W_tx, b_tx, T0c, cur, 32);
            scatter_src_kernel<<<SGG, 256, 0, stream>>>(T0c, ei_recv, ei_recv + NE, aggA, NE, lo, lo + cur);
        }
        combine_kernel<0><<<(NACC + 63) / 64, 256, 0, stream>>>(
            aggA, invA, A0f, Wl_ta, Wr_ta, bl_ta, bng, bnb, bnm, bnv, A1f, NACC);

        // pass 2: recompute T0 chunks, make T1 chunks, scatter into agg for L1
        fz(aggA, (size_t)NACC * H * 4, stream);
        for (int lo = 0; lo < NTX; lo += C) {
            int cur = (NTX - lo < C) ? (NTX - lo) : C;
            proj_kernel<<<cur, 256, 0, stream>>>(x_tx + (size_t)lo * 32, W_tx, b_tx, T0c, cur, 32);
            gmean_kernel<<<(cur + 3) / 4, 256, 0, stream>>>(A0f, ptrT, permS, meanTc, cur, lo);
            combine_kernel<1><<<(cur + 63) / 64, 256, 0, stream>>>(
                meanTc, nullptr, T0c, Wl_at, Wr_at, bl_at,
                bng, bnb, bnm, bnv, T0c, cur);
            scatter_src_kernel<<<SGG, 256, 0, stream>>>(T0c, ei_recv, ei_recv + NE, aggA, NE, lo, lo + cur);
        }
        combine_kernel<0><<<(NACC + 63) / 64, 256, 0, stream>>>(
            aggA, invA, A1f, Wl_ta + H * H, Wr_ta + H * H, bl_ta + H,
            bng + H, bnb + H, bnm + H, bnv + H, A0f, NACC);

        mlp_kernel<<<(NM + 63) / 64, 256, 0, stream>>>(
            A0f, sidx, ridx, tx_raw, W1, b1, W2, b2, out, NM);
    }
}

// Round 4
// 8099.552 us; speedup vs baseline: 1.7603x; 1.7603x over previous
//
#include <hip/hip_runtime.h>
#include <hip/hip_bf16.h>

#define H 256
#define NACC 100000
#define NTX  300000
#define NE   600000
#define NM   300000
#define BK 16

typedef unsigned short u16;
typedef unsigned int u32;

__device__ __forceinline__ float bf2f(u32 u) {
    union { u32 i; float f; } v; v.i = u << 16; return v.f;
}
__device__ __forceinline__ u16 f2bf(float f) {
    union { float f; u32 i; } v; v.f = f;
    u32 r = v.i + 0x7FFFu + ((v.i >> 16) & 1u);
    return (u16)(r >> 16);
}

// ---------------- zero fill (NO hipMemsetAsync: breaks graph capture) ----------------
__global__ void fillz_kernel(u32* __restrict__ p, long long n) {
    long long i = (long long)blockIdx.x * blockDim.x + threadIdx.x;
    long long st = (long long)gridDim.x * blockDim.x;
    for (; i < n; i += st) p[i] = 0u;
}

// ---------------- input projection: out[n][t] = relu(x[n] . W[c0+t] + b[c0+t]) as bf16 ----------------
// blockDim.x = number of output cols this launch covers (64/128/256)
__global__ void proj_kernel(const float* __restrict__ x, const float* __restrict__ W,
                            const float* __restrict__ b, u16* __restrict__ out,
                            int N, int K, int c0, int ost) {
    __shared__ float xs[32];
    int n = blockIdx.x;
    int t = threadIdx.x;
    if (t < K) xs[t] = x[(size_t)n * K + t];
    __syncthreads();
    int col = c0 + t;
    float s = b[col];
    for (int k = 0; k < K; k += 4) {
        float4 w = *(const float4*)(W + (size_t)col * K + k);
        s += xs[k] * w.x + xs[k + 1] * w.y + xs[k + 2] * w.z + xs[k + 3] * w.w;
    }
    out[(size_t)n * ost + t] = f2bf(fmaxf(s, 0.0f));
}

// ---------------- CSR build: count, 3-kernel scan, fill (validated round 3) ----------------
__global__ void count_kernel(const int* __restrict__ dst, int E, int* __restrict__ cnt) {
    int e = blockIdx.x * blockDim.x + threadIdx.x;
    if (e < E) atomicAdd(&cnt[dst[e]], 1);
}

__global__ void scan1_kernel(const int* __restrict__ cnt, int N,
                             int* __restrict__ loc, int* __restrict__ bsum) {
    __shared__ int sh[256];
    int b = blockIdx.x, t = threadIdx.x;
    int base = b * 1024 + t * 4;
    int v0 = (base + 0 < N) ? cnt[base + 0] : 0;
    int v1 = (base + 1 < N) ? cnt[base + 1] : 0;
    int v2 = (base + 2 < N) ? cnt[base + 2] : 0;
    int v3 = (base + 3 < N) ? cnt[base + 3] : 0;
    int s = v0 + v1 + v2 + v3;
    sh[t] = s;
    __syncthreads();
    for (int o = 1; o < 256; o <<= 1) {
        int y = (t >= o) ? sh[t - o] : 0;
        __syncthreads();
        sh[t] += y;
        __syncthreads();
    }
    int run = sh[t] - s;
    if (base + 0 < N) loc[base + 0] = run; run += v0;
    if (base + 1 < N) loc[base + 1] = run; run += v1;
    if (base + 2 < N) loc[base + 2] = run; run += v2;
    if (base + 3 < N) loc[base + 3] = run;
    if (t == 0) bsum[b] = sh[255];
}

__global__ void scan2_kernel(int* __restrict__ bsum, int nb) {
    __shared__ int sh[1024];
    int t = threadIdx.x;
    int v = (t < nb) ? bsum[t] : 0;
    sh[t] = v;
    __syncthreads();
    for (int o = 1; o < 1024; o <<= 1) {
        int y = (t >= o) ? sh[t - o] : 0;
        __syncthreads();
        sh[t] += y;
        __syncthreads();
    }
    if (t < nb) bsum[t] = sh[t] - v;
}

__global__ void scan3_kernel(int* __restrict__ ptr, const int* __restrict__ bsum,
                             int N, int total) {
    int i = blockIdx.x * blockDim.x + threadIdx.x;
    if (i < N) ptr[i] += bsum[i >> 10];
    else if (i == N) ptr[N] = total;
}

__global__ void fillcsr_kernel(const int* __restrict__ src, const int* __restrict__ dst, int E,
                               const int* __restrict__ ptr, int* __restrict__ cur,
                               int* __restrict__ perm) {
    int e = blockIdx.x * blockDim.x + threadIdx.x;
    if (e < E) {
        int d = dst[e];
        int pos = ptr[d] + atomicAdd(&cur[d], 1);
        perm[pos] = src[e];
    }
}

// ---------------- gather-mean over a column-slice of width WS ----------------
// out[w][c0 + c] = mean_{s in CSR[lo+w]} feat[s][c],   c in [0, WS)
template <int WS>
__launch_bounds__(256)
__global__ void gmean_kernel(const u16* __restrict__ feat, int fstride,
                             const int* __restrict__ ptr, const int* __restrict__ perm,
                             u16* __restrict__ out, int ostride, int c0,
                             int rows, int lo) {
    constexpr int LPD = WS / 4;        // lanes per dst (each lane: 4 bf16 via uint2)
    constexpr int DPB = 256 / LPD;     // dsts per block
    int g = threadIdx.x / LPD;
    int ln = threadIdx.x % LPD;
    int w = blockIdx.x * DPB + g;
    if (w >= rows) return;
    int d = lo + w;
    int e0 = ptr[d], e1 = ptr[d + 1];
    float a0 = 0.f, a1 = 0.f, a2 = 0.f, a3 = 0.f;
    for (int e = e0; e < e1; ++e) {
        int s = perm[e];
        uint2 v = *(const uint2*)(feat + (size_t)s * fstride + (ln << 2));
        a0 += bf2f(v.x & 0xffff); a1 += bf2f(v.x >> 16);
        a2 += bf2f(v.y & 0xffff); a3 += bf2f(v.y >> 16);
    }
    int deg = e1 - e0;
    float sc = (deg > 0) ? (1.0f / (float)deg) : 0.0f;
    uint2 pk;
    pk.x = (u32)f2bf(a0 * sc) | ((u32)f2bf(a1 * sc) << 16);
    pk.y = (u32)f2bf(a2 * sc) | ((u32)f2bf(a3 * sc) << 16);
    *(uint2*)(out + (size_t)w * ostride + c0 + (ln << 2)) = pk;
}

// ---------------- fused SAGE combine, output-column-sliced ----------------
// out cols [c0, c0+COLS) = relu(bn(mean @ Wl.T + bl + xd @ Wr.T)) for those cols.
// mean/xd are full-width (stride H). outF row stride = ostride, col offset in out row = out_c0.
template <int COLS>
__launch_bounds__(256)
__global__ void combine_kernel(const u16* __restrict__ mean_, const u16* __restrict__ xd,
                               const float* __restrict__ Wl, const float* __restrict__ Wr,
                               const float* __restrict__ bl,
                               const float* __restrict__ bng, const float* __restrict__ bnb,
                               const float* __restrict__ bnm, const float* __restrict__ bnv,
                               u16* __restrict__ outF, int ostride, int out_c0,
                               int rows, int c0) {
    __shared__ float As[BK][68];
    __shared__ float Bs[BK][COLS + 4];
    constexpr int JN = COLS / 64;      // float4-groups of cols per thread
    constexpr int EPT = COLS / 16;     // k-elems staged per thread for B
    int tid = threadIdx.x;
    int row0 = blockIdx.x * 64;
    int rs = tid >> 2, kq = (tid & 3) << 2;
    int grow = row0 + rs;
    bool rok = grow < rows;
    int tr = tid >> 4, tc = tid & 15;
    float acc[4][JN * 4];
#pragma unroll
    for (int i = 0; i < 4; ++i)
#pragma unroll
        for (int j = 0; j < JN * 4; ++j) acc[i][j] = 0.0f;

    int bcol = tid % COLS;
    int bk0 = (tid / COLS) * EPT;

    for (int kb = 0; kb < 512; kb += BK) {
        // stage A (full-width K: first 256 = mean, last 256 = xd)
        {
            int kg = kb + kq;
            float a0, a1, a2, a3;
            if (!rok) { a0 = a1 = a2 = a3 = 0.0f; }
            else {
                const u16* p = (kg < 256) ? (mean_ + (size_t)grow * H + kg)
                                          : (xd + (size_t)grow * H + (kg - 256));
                uint2 v = *(const uint2*)p;
                a0 = bf2f(v.x & 0xffff); a1 = bf2f(v.x >> 16);
                a2 = bf2f(v.y & 0xffff); a3 = bf2f(v.y >> 16);
            }
            As[kq + 0][rs] = a0; As[kq + 1][rs] = a1;
            As[kq + 2][rs] = a2; As[kq + 3][rs] = a3;
        }
        // stage B: Bs[k][col] = W[c0+col][kb+k]
        {
            const float* Wsrc = (kb < 256) ? Wl : Wr;
            const float* p = Wsrc + (size_t)(c0 + bcol) * H + (kb & 255) + bk0;
#pragma unroll
            for (int q = 0; q < EPT / 4; ++q) {
                float4 w = *(const float4*)(p + (q << 2));
                Bs[bk0 + (q << 2) + 0][bcol] = w.x;
                Bs[bk0 + (q << 2) + 1][bcol] = w.y;
                Bs[bk0 + (q << 2) + 2][bcol] = w.z;
                Bs[bk0 + (q << 2) + 3][bcol] = w.w;
            }
        }
        __syncthreads();
#pragma unroll
        for (int k = 0; k < BK; ++k) {
            float4 a = *(const float4*)(&As[k][tr << 2]);
            float av[4] = { a.x, a.y, a.z, a.w };
#pragma unroll
            for (int j = 0; j < JN; ++j) {
                float4 b = *(const float4*)(&Bs[k][(j << 6) + (tc << 2)]);
                float bv[4] = { b.x, b.y, b.z, b.w };
#pragma unroll
                for (int i = 0; i < 4; ++i)
#pragma unroll
                    for (int c = 0; c < 4; ++c)
                        acc[i][(j << 2) + c] += av[i] * bv[c];
            }
        }
        __syncthreads();
    }
    // epilogue: + bl, BN, relu, pack bf16
#pragma unroll
    for (int j = 0; j < JN; ++j) {
        int cl = (j << 6) + (tc << 2);   // local col in slice
        int cg = c0 + cl;                // global col for params
        float4 blv = *(const float4*)(bl + cg);
        float4 g   = *(const float4*)(bng + cg);
        float4 be  = *(const float4*)(bnb + cg);
        float4 mm  = *(const float4*)(bnm + cg);
        float4 vv  = *(const float4*)(bnv + cg);
        float s0 = g.x * rsqrtf(vv.x + 1e-5f);
        float s1 = g.y * rsqrtf(vv.y + 1e-5f);
        float s2 = g.z * rsqrtf(vv.z + 1e-5f);
        float s3 = g.w * rsqrtf(vv.w + 1e-5f);
#pragma unroll
        for (int i = 0; i < 4; ++i) {
            int r = row0 + (tr << 2) + i;
            if (r < rows) {
                float o0 = fmaxf((acc[i][(j << 2) + 0] + blv.x - mm.x) * s0 + be.x, 0.0f);
                float o1 = fmaxf((acc[i][(j << 2) + 1] + blv.y - mm.y) * s1 + be.y, 0.0f);
                float o2 = fmaxf((acc[i][(j << 2) + 2] + blv.z - mm.z) * s2 + be.z, 0.0f);
                float o3 = fmaxf((acc[i][(j << 2) + 3] + blv.w - mm.w) * s3 + be.w, 0.0f);
                uint2 pk;
                pk.x = (u32)f2bf(o0) | ((u32)f2bf(o1) << 16);
                pk.y = (u32)f2bf(o2) | ((u32)f2bf(o3) << 16);
                *(uint2*)(outF + (size_t)r * ostride + out_c0 + cl) = pk;
            }
        }
    }
}

// ---------------- fused edge MLP head (unchanged from round 3 — validated) ----------------
__launch_bounds__(256)
__global__ void mlp_kernel(const u16* __restrict__ accF, const int* __restrict__ sidx,
                           const int* __restrict__ ridx, const float* __restrict__ txr,
                           const float* __restrict__ W1, const float* __restrict__ b1,
                           const float* __restrict__ W2, const float* __restrict__ b2,
                           float* __restrict__ out, int M) {
    __shared__ float As[BK][68];
    __shared__ float Bs[BK][260];
    int tid = threadIdx.x;
    int row0 = blockIdx.x * 64;
    int rs = tid >> 2, kq = (tid & 3) << 2;
    int grow = row0 + rs;
    bool rok = grow < M;
    int si = rok ? sidx[grow] : 0;
    int ri = rok ? ridx[grow] : 0;
    int tr = tid >> 4, tc = tid & 15;
    float acc[4][16];
#pragma unroll
    for (int i = 0; i < 4; ++i)
#pragma unroll
        for (int j = 0; j < 16; ++j) acc[i][j] = 0.0f;

    for (int kb = 0; kb < 544; kb += BK) {
        {
            int kg = kb + kq;
            float a0, a1, a2, a3;
            if (!rok) { a0 = a1 = a2 = a3 = 0.0f; }
            else if (kg < 256) {
                uint2 v = *(const uint2*)(accF + (size_t)si * H + kg);
                a0 = bf2f(v.x & 0xffff); a1 = bf2f(v.x >> 16);
                a2 = bf2f(v.y & 0xffff); a3 = bf2f(v.y >> 16);
            } else if (kg < 512) {
                uint2 v = *(const uint2*)(accF + (size_t)ri * H + (kg - 256));
                a0 = bf2f(v.x & 0xffff); a1 = bf2f(v.x >> 16);
                a2 = bf2f(v.y & 0xffff); a3 = bf2f(v.y >> 16);
            } else {
                float4 v = *(const float4*)(txr + (size_t)grow * 32 + (kg - 512));
                a0 = v.x; a1 = v.y; a2 = v.z; a3 = v.w;
            }
            As[kq + 0][rs] = a0; As[kq + 1][rs] = a1;
            As[kq + 2][rs] = a2; As[kq + 3][rs] = a3;
        }
        {
            const float* p = W1 + (size_t)tid * 544 + kb;
#pragma unroll
            for (int q = 0; q < 4; ++q) {
                float4 w = *(const float4*)(p + (q << 2));
                Bs[(q << 2) + 0][tid] = w.x; Bs[(q << 2) + 1][tid] = w.y;
                Bs[(q << 2) + 2][tid] = w.z; Bs[(q << 2) + 3][tid] = w.w;
            }
        }
        __syncthreads();
#pragma unroll
        for (int k = 0; k < BK; ++k) {
            float4 a = *(const float4*)(&As[k][tr << 2]);
            float av[4] = { a.x, a.y, a.z, a.w };
#pragma unroll
            for (int j = 0; j < 4; ++j) {
                float4 b = *(const float4*)(&Bs[k][(j << 6) + (tc << 2)]);
                float bv[4] = { b.x, b.y, b.z, b.w };
#pragma unroll
                for (int i = 0; i < 4; ++i)
#pragma unroll
                    for (int c = 0; c < 4; ++c)
                        acc[i][(j << 2) + c] += av[i] * bv[c];
            }
        }
        __syncthreads();
    }
    float partial[4] = { 0.f, 0.f, 0.f, 0.f };
#pragma unroll
    for (int j = 0; j < 4; ++j) {
        int cb = (j << 6) + (tc << 2);
        float4 b1v = *(const float4*)(b1 + cb);
        float4 w2v = *(const float4*)(W2 + cb);
#pragma unroll
        for (int i = 0; i < 4; ++i) {
            partial[i] += fmaxf(acc[i][(j << 2) + 0] + b1v.x, 0.0f) * w2v.x
                        + fmaxf(acc[i][(j << 2) + 1] + b1v.y, 0.0f) * w2v.y
                        + fmaxf(acc[i][(j << 2) + 2] + b1v.z, 0.0f) * w2v.z
                        + fmaxf(acc[i][(j << 2) + 3] + b1v.w, 0.0f) * w2v.w;
        }
    }
    float bias = b2[0];
#pragma unroll
    for (int i = 0; i < 4; ++i) {
        float p = partial[i];
        p += __shfl_xor(p, 1);
        p += __shfl_xor(p, 2);
        p += __shfl_xor(p, 4);
        p += __shfl_xor(p, 8);
        int r = row0 + (tr << 2) + i;
        if (tc == 0 && r < M) out[r] = p + bias;
    }
}

// ---------------- host ----------------
static inline void fz(void* p, size_t bytes, hipStream_t s) {
    long long n = (long long)(bytes >> 2);
    int g = (int)(((n + 255) / 256 < 2048) ? (n + 255) / 256 : 2048);
    fillz_kernel<<<g, 256, 0, s>>>((u32*)p, n);
}

extern "C" void kernel_launch(void* const* d_in, const int* in_sizes, int n_in,
                              void* d_out, int out_size, void* d_ws, size_t ws_size,
                              hipStream_t stream) {
    const float* x_acc  = (const float*)d_in[0];
    const float* x_tx   = (const float*)d_in[1];
    const float* tx_raw = (const float*)d_in[2];
    const int* ei_sends = (const int*)d_in[3];
    const int* ei_recv  = (const int*)d_in[4];
    const int* sidx     = (const int*)d_in[5];
    const int* ridx     = (const int*)d_in[6];
    const float* W_acc  = (const float*)d_in[7];
    const float* b_acc  = (const float*)d_in[8];
    const float* W_tx   = (const float*)d_in[9];
    const float* b_tx   = (const float*)d_in[10];
    const float* Wl_at  = (const float*)d_in[11];
    const float* bl_at  = (const float*)d_in[12];
    const float* Wr_at  = (const float*)d_in[13];
    const float* Wl_ta  = (const float*)d_in[14];
    const float* bl_ta  = (const float*)d_in[15];
    const float* Wr_ta  = (const float*)d_in[16];
    const float* bng    = (const float*)d_in[17];
    const float* bnb    = (const float*)d_in[18];
    const float* bnm    = (const float*)d_in[19];
    const float* bnv    = (const float*)d_in[20];
    const float* W1     = (const float*)d_in[21];
    const float* b1     = (const float*)d_in[22];
    const float* W2     = (const float*)d_in[23];
    const float* b2     = (const float*)d_in[24];
    float* out = (float*)d_out;

    // ---- pick slice count S and chunk rows CC from ws_size ----
    auto need = [](int S, int CC) -> size_t {
        size_t t = 0;
        t += 3ull * NACC * H * 2;            // A0f, A1f, meanbuf
        t += (size_t)(NTX + 1) * 4 + 4096;   // cnt, bsum
        t += (size_t)(NTX + 1) * 4;          // ptrT
        t += (size_t)NE * 4;                 // permS
        t += (size_t)(NACC + 1) * 4;         // ptrA
        t += (size_t)NE * 4;                 // permR
        t += 2ull * CC * H * 2;              // T0c, meanTc
        t += (size_t)NTX * (H / S) * 2;      // Tslice
        t += 16 * 256 + 65536;               // align slack
        return t;
    };
    int S, CC;
    if      (need(1, 16384) <= ws_size) { S = 1; CC = 16384; }
    else if (need(2, 16384) <= ws_size) { S = 2; CC = 16384; }
    else if (need(4, 16384) <= ws_size) { S = 4; CC = 16384; }
    else                                { S = 4; CC = 2048;  }
    const int WSL = H / S;   // slice width: 256 / 128 / 64

    char* wsp = (char*)d_ws;
    size_t off = 0;
    auto alloc = [&](size_t bytes) -> void* {
        void* p = wsp + off;
        off = (off + bytes + 255) & ~(size_t)255;
        return p;
    };
    u16* A0f     = (u16*)alloc((size_t)NACC * H * 2);
    u16* A1f     = (u16*)alloc((size_t)NACC * H * 2);
    u16* meanbuf = (u16*)alloc((size_t)NACC * H * 2);
    int* cnt     = (int*)alloc((size_t)(NTX + 1) * 4);
    int* bsum    = (int*)alloc(4096);
    int* ptrT    = (int*)alloc((size_t)(NTX + 1) * 4);
    int* permS   = (int*)alloc((size_t)NE * 4);
    int* ptrA    = (int*)alloc((size_t)(NACC + 1) * 4);
    int* permR   = (int*)alloc((size_t)NE * 4);
    u16* T0c     = (u16*)alloc((size_t)CC * H * 2);
    u16* meanTc  = (u16*)alloc((size_t)CC * H * 2);
    u16* Tslice  = (u16*)alloc((size_t)NTX * WSL * 2);

    const int EG = (NE + 255) / 256;
    const int nbT = (NTX + 1023) / 1024, nbA = (NACC + 1023) / 1024;

    // ---- CSR sends (dst = tx) ----
    fz(cnt, (size_t)NTX * 4, stream);
    count_kernel<<<EG, 256, 0, stream>>>(ei_sends + NE, NE, cnt);
    scan1_kernel<<<nbT, 256, 0, stream>>>(cnt, NTX, ptrT, bsum);
    scan2_kernel<<<1, 1024, 0, stream>>>(bsum, nbT);
    scan3_kernel<<<(NTX + 256) / 256 + 1, 256, 0, stream>>>(ptrT, bsum, NTX, NE);
    fz(cnt, (size_t)NTX * 4, stream);
    fillcsr_kernel<<<EG, 256, 0, stream>>>(ei_sends, ei_sends + NE, NE, ptrT, cnt, permS);

    // ---- CSR recv (dst = acc) ----
    fz(cnt, (size_t)NACC * 4, stream);
    count_kernel<<<EG, 256, 0, stream>>>(ei_recv + NE, NE, cnt);
    scan1_kernel<<<nbA, 256, 0, stream>>>(cnt, NACC, ptrA, bsum);
    scan2_kernel<<<1, 1024, 0, stream>>>(bsum, nbA);
    scan3_kernel<<<(NACC + 256) / 256 + 1, 256, 0, stream>>>(ptrA, bsum, NACC, NE);
    fz(cnt, (size_t)NACC * 4, stream);
    fillcsr_kernel<<<EG, 256, 0, stream>>>(ei_recv, ei_recv + NE, NE, ptrA, cnt, permR);

    // ---- acc projection ----
    proj_kernel<<<NACC, 256, 0, stream>>>(x_acc, W_acc, b_acc, A0f, NACC, 16, 0, H);

    // ---- Phase A (L0 acc side): slices of T0 -> meanbuf -> combine -> A1f ----
    for (int s = 0; s < S; ++s) {
        int c0 = s * WSL;
        proj_kernel<<<NTX, WSL, 0, stream>>>(x_tx, W_tx, b_tx, Tslice, NTX, 32, c0, WSL);
        if (WSL == 256)
            gmean_kernel<256><<<(NACC + 3) / 4, 256, 0, stream>>>(Tslice, WSL, ptrA, permR, meanbuf, H, c0, NACC, 0);
        else if (WSL == 128)
            gmean_kernel<128><<<(NACC + 7) / 8, 256, 0, stream>>>(Tslice, WSL, ptrA, permR, meanbuf, H, c0, NACC, 0);
        else
            gmean_kernel<64><<<(NACC + 15) / 16, 256, 0, stream>>>(Tslice, WSL, ptrA, permR, meanbuf, H, c0, NACC, 0);
    }
    combine_kernel<256><<<(NACC + 63) / 64, 256, 0, stream>>>(
        meanbuf, A0f, Wl_ta, Wr_ta, bl_ta, bng, bnb, bnm, bnv, A1f, H, 0, NACC, 0);

    // ---- Phase B (L1 acc side): slices of T1 -> meanbuf -> combine -> A2 (into A0f) ----
    for (int s = 0; s < S; ++s) {
        int c0 = s * WSL;
        for (int lo = 0; lo < NTX; lo += CC) {
            int cur = (NTX - lo < CC) ? (NTX - lo) : CC;
            proj_kernel<<<cur, 256, 0, stream>>>(x_tx + (size_t)lo * 32, W_tx, b_tx, T0c, cur, 32, 0, H);
            gmean_kernel<256><<<(cur + 3) / 4, 256, 0, stream>>>(A0f, H, ptrT, permS, meanTc, H, 0, cur, lo);
            if (WSL == 256)
                combine_kernel<256><<<(cur + 63) / 64, 256, 0, stream>>>(
                    meanTc, T0c, Wl_at, Wr_at, bl_at, bng, bnb, bnm, bnv,
                    Tslice + (size_t)lo * WSL, WSL, 0, cur, c0);
            else if (WSL == 128)
                combine_kernel<128><<<(cur + 63) / 64, 256, 0, stream>>>(
                    meanTc, T0c, Wl_at, Wr_at, bl_at, bng, bnb, bnm, bnv,
                    Tslice + (size_t)lo * WSL, WSL, 0, cur, c0);
            else
                combine_kernel<64><<<(cur + 63) / 64, 256, 0, stream>>>(
                    meanTc, T0c, Wl_at, Wr_at, bl_at, bng, bnb, bnm, bnv,
                    Tslice + (size_t)lo * WSL, WSL, 0, cur, c0);
        }
        if (WSL == 256)
            gmean_kernel<256><<<(NACC + 3) / 4, 256, 0, stream>>>(Tslice, WSL, ptrA, permR, meanbuf, H, c0, NACC, 0);
        else if (WSL == 128)
            gmean_kernel<128><<<(NACC + 7) / 8, 256, 0, stream>>>(Tslice, WSL, ptrA, permR, meanbuf, H, c0, NACC, 0);
        else
            gmean_kernel<64><<<(NACC + 15) / 16, 256, 0, stream>>>(Tslice, WSL, ptrA, permR, meanbuf, H, c0, NACC, 0);
    }
    combine_kernel<256><<<(NACC + 63) / 64, 256, 0, stream>>>(
        meanbuf, A1f, Wl_ta + H * H, Wr_ta + H * H, bl_ta + H,
        bng + H, bnb + H, bnm + H, bnv + H, A0f, H, 0, NACC, 0);

    // ---- edge MLP head ----
    mlp_kernel<<<(NM + 63) / 64, 256, 0, stream>>>(
        A0f, sidx, ridx, tx_raw, W1, b1, W2, b2, out, NM);
}

// Round 5
// 5254.457 us; speedup vs baseline: 2.7134x; 1.5415x over previous
//
#include <hip/hip_runtime.h>
#include <hip/hip_bf16.h>

#define H 256
#define NACC 100000
#define NTX  300000
#define NE   600000
#define NM   300000

typedef unsigned short u16;
typedef unsigned int u32;
typedef __bf16 bf16x8 __attribute__((ext_vector_type(8)));
typedef float f32x4 __attribute__((ext_vector_type(4)));

__device__ __forceinline__ float bf2f(u32 u) {
    union { u32 i; float f; } v; v.i = u << 16; return v.f;
}
__device__ __forceinline__ u16 f2bf(float f) {
    union { float f; u32 i; } v; v.f = f;
    u32 r = v.i + 0x7FFFu + ((v.i >> 16) & 1u);
    return (u16)(r >> 16);
}

// ---------------- zero fill (no hipMemsetAsync: breaks graph capture) ----------------
__global__ void fillz_kernel(u32* __restrict__ p, long long n) {
    long long i = (long long)blockIdx.x * blockDim.x + threadIdx.x;
    long long st = (long long)gridDim.x * blockDim.x;
    for (; i < n; i += st) p[i] = 0u;
}

// ---------------- weight prep: fp32 -> bf16 concat [col][512], W1 [col][544], BN fold ----------------
__global__ void wcat_kernel(const float* __restrict__ Wl, const float* __restrict__ Wr,
                            u16* __restrict__ dst) {
    int c = blockIdx.x, t = threadIdx.x;
    dst[(size_t)c * 512 + t]       = f2bf(Wl[(size_t)c * 256 + t]);
    dst[(size_t)c * 512 + 256 + t] = f2bf(Wr[(size_t)c * 256 + t]);
}
__global__ void w1cvt_kernel(const float* __restrict__ W1, u16* __restrict__ dst) {
    int c = blockIdx.x, t = threadIdx.x;
    for (int k = t; k < 544; k += 256)
        dst[(size_t)c * 544 + k] = f2bf(W1[(size_t)c * 544 + k]);
}
__global__ void bnprep_kernel(const float* __restrict__ bl, const float* __restrict__ g,
                              const float* __restrict__ be, const float* __restrict__ m,
                              const float* __restrict__ v,
                              float* __restrict__ S, float* __restrict__ B) {
    int c = threadIdx.x;
    float s = g[c] * rsqrtf(v[c] + 1e-5f);
    S[c] = s;
    B[c] = (bl[c] - m[c]) * s + be[c];
}

// ---------------- input projection: out = relu(x @ W.T + b) as bf16 (cols c0..c0+blockDim) --------
__global__ void proj_kernel(const float* __restrict__ x, const float* __restrict__ W,
                            const float* __restrict__ b, u16* __restrict__ out,
                            int N, int K, int c0, int ost) {
    __shared__ float xs[32];
    int n = blockIdx.x;
    int t = threadIdx.x;
    if (t < K) xs[t] = x[(size_t)n * K + t];
    __syncthreads();
    int col = c0 + t;
    float s = b[col];
    for (int k = 0; k < K; k += 4) {
        float4 w = *(const float4*)(W + (size_t)col * K + k);
        s += xs[k] * w.x + xs[k + 1] * w.y + xs[k + 2] * w.z + xs[k + 3] * w.w;
    }
    out[(size_t)n * ost + t] = f2bf(fmaxf(s, 0.0f));
}

// ---------------- CSR build (validated round 3/4) ----------------
__global__ void count_kernel(const int* __restrict__ dst, int E, int* __restrict__ cnt) {
    int e = blockIdx.x * blockDim.x + threadIdx.x;
    if (e < E) atomicAdd(&cnt[dst[e]], 1);
}
__global__ void scan1_kernel(const int* __restrict__ cnt, int N,
                             int* __restrict__ loc, int* __restrict__ bsum) {
    __shared__ int sh[256];
    int b = blockIdx.x, t = threadIdx.x;
    int base = b * 1024 + t * 4;
    int v0 = (base + 0 < N) ? cnt[base + 0] : 0;
    int v1 = (base + 1 < N) ? cnt[base + 1] : 0;
    int v2 = (base + 2 < N) ? cnt[base + 2] : 0;
    int v3 = (base + 3 < N) ? cnt[base + 3] : 0;
    int s = v0 + v1 + v2 + v3;
    sh[t] = s;
    __syncthreads();
    for (int o = 1; o < 256; o <<= 1) {
        int y = (t >= o) ? sh[t - o] : 0;
        __syncthreads();
        sh[t] += y;
        __syncthreads();
    }
    int run = sh[t] - s;
    if (base + 0 < N) loc[base + 0] = run; run += v0;
    if (base + 1 < N) loc[base + 1] = run; run += v1;
    if (base + 2 < N) loc[base + 2] = run; run += v2;
    if (base + 3 < N) loc[base + 3] = run;
    if (t == 0) bsum[b] = sh[255];
}
__global__ void scan2_kernel(int* __restrict__ bsum, int nb) {
    __shared__ int sh[1024];
    int t = threadIdx.x;
    int v = (t < nb) ? bsum[t] : 0;
    sh[t] = v;
    __syncthreads();
    for (int o = 1; o < 1024; o <<= 1) {
        int y = (t >= o) ? sh[t - o] : 0;
        __syncthreads();
        sh[t] += y;
        __syncthreads();
    }
    if (t < nb) bsum[t] = sh[t] - v;
}
__global__ void scan3_kernel(int* __restrict__ ptr, const int* __restrict__ bsum,
                             int N, int total) {
    int i = blockIdx.x * blockDim.x + threadIdx.x;
    if (i < N) ptr[i] += bsum[i >> 10];
    else if (i == N) ptr[N] = total;
}
__global__ void fillcsr_kernel(const int* __restrict__ src, const int* __restrict__ dst, int E,
                               const int* __restrict__ ptr, int* __restrict__ cur,
                               int* __restrict__ perm) {
    int e = blockIdx.x * blockDim.x + threadIdx.x;
    if (e < E) {
        int d = dst[e];
        int pos = ptr[d] + atomicAdd(&cur[d], 1);
        perm[pos] = src[e];
    }
}

// ---------------- gather-mean over a column-slice of width WS (validated round 4) ------------
template <int WS>
__launch_bounds__(256)
__global__ void gmean_kernel(const u16* __restrict__ feat, int fstride,
                             const int* __restrict__ ptr, const int* __restrict__ perm,
                             u16* __restrict__ out, int ostride, int c0,
                             int rows, int lo) {
    constexpr int LPD = WS / 4;
    constexpr int DPB = 256 / LPD;
    int g = threadIdx.x / LPD;
    int ln = threadIdx.x % LPD;
    int w = blockIdx.x * DPB + g;
    if (w >= rows) return;
    int d = lo + w;
    int e0 = ptr[d], e1 = ptr[d + 1];
    float a0 = 0.f, a1 = 0.f, a2 = 0.f, a3 = 0.f;
    for (int e = e0; e < e1; ++e) {
        int s = perm[e];
        uint2 v = *(const uint2*)(feat + (size_t)s * fstride + (ln << 2));
        a0 += bf2f(v.x & 0xffff); a1 += bf2f(v.x >> 16);
        a2 += bf2f(v.y & 0xffff); a3 += bf2f(v.y >> 16);
    }
    int deg = e1 - e0;
    float sc = (deg > 0) ? (1.0f / (float)deg) : 0.0f;
    uint2 pk;
    pk.x = (u32)f2bf(a0 * sc) | ((u32)f2bf(a1 * sc) << 16);
    pk.y = (u32)f2bf(a2 * sc) | ((u32)f2bf(a3 * sc) << 16);
    *(uint2*)(out + (size_t)w * ostride + c0 + (ln << 2)) = pk;
}

// ---------------- MFMA SAGE combine: out = relu(gemm*bnS + bnB), col-sliced ----------------
// block = 64 rows x COLS cols, 4 waves (wave w: cols [w*COLS/4, ...)), K = 512 (mean || xd).
// A frag (16x16x32 bf16): lane l -> row l&15, k = (l>>4)*8 + j. B frag: col l&15, same k.
// C/D: col = l&15, row = (l>>4)*4 + reg  [m89 verified].
template <int COLS>
__launch_bounds__(256)
__global__ void combine_mfma(const u16* __restrict__ mean_, const u16* __restrict__ xd,
                             const u16* __restrict__ Wcat,
                             const float* __restrict__ bnS, const float* __restrict__ bnB,
                             u16* __restrict__ outF, int ostride, int out_c0,
                             int rows, int c0) {
    constexpr int NCT = COLS / 16;      // col-tiles per block
    constexpr int CTW = NCT / 4;        // col-tiles per wave
    constexpr int PPT = (COLS * 4) / 256;
    __shared__ __align__(16) u16 Af[4][64][8];
    __shared__ __align__(16) u16 Bf[NCT][64][8];
    int tid = threadIdx.x;
    int w = tid >> 6, lane = tid & 63;
    int row0 = blockIdx.x * 64;
    int arow = tid >> 2, akg = tid & 3;
    bool arok = (row0 + arow) < rows;
    const u16* am = mean_ + (size_t)(row0 + arow) * H;
    const u16* ax = xd + (size_t)(row0 + arow) * H;
    int awslot = (akg * 16 + (arow & 15)) ^ (akg << 2);   // XOR-swizzled A store slot
    int arslot = lane ^ ((lane >> 4) << 2);               // matching read slot
    int bc = tid % COLS;
    int bkg0 = (tid / COLS) * PPT;
    const u16* wp0 = Wcat + (size_t)(c0 + bc) * 512 + bkg0 * 8;

    f32x4 acc[4][CTW];
#pragma unroll
    for (int i = 0; i < 4; ++i)
#pragma unroll
        for (int j = 0; j < CTW; ++j) acc[i][j] = (f32x4){0.f, 0.f, 0.f, 0.f};

    for (int kb = 0; kb < 512; kb += 32) {
        // stage A fragment-ordered
        uint4 av = make_uint4(0, 0, 0, 0);
        if (arok) {
            int kg = kb + akg * 8;
            av = (kg < 256) ? *(const uint4*)(am + kg) : *(const uint4*)(ax + (kg - 256));
        }
        *(uint4*)(&Af[arow >> 4][awslot][0]) = av;
        // stage B fragment-ordered
#pragma unroll
        for (int q = 0; q < PPT; ++q) {
            uint4 wv = *(const uint4*)(wp0 + kb + q * 8);
            *(uint4*)(&Bf[bc >> 4][(bkg0 + q) * 16 + (bc & 15)][0]) = wv;
        }
        __syncthreads();
        bf16x8 afr[4];
#pragma unroll
        for (int rt = 0; rt < 4; ++rt)
            afr[rt] = *(const bf16x8*)(&Af[rt][arslot][0]);
#pragma unroll
        for (int ctl = 0; ctl < CTW; ++ctl) {
            bf16x8 b = *(const bf16x8*)(&Bf[w * CTW + ctl][lane][0]);
#pragma unroll
            for (int rt = 0; rt < 4; ++rt)
                acc[rt][ctl] = __builtin_amdgcn_mfma_f32_16x16x32_bf16(afr[rt], b, acc[rt][ctl], 0, 0, 0);
        }
        __syncthreads();
    }
    // epilogue: BN-folded scale/shift + relu, bf16 store
    int rb = (lane >> 4) * 4;
    int ccol = lane & 15;
#pragma unroll
    for (int ctl = 0; ctl < CTW; ++ctl) {
        int clocal = (w * CTW + ctl) * 16 + ccol;
        int cg = c0 + clocal;
        float s = bnS[cg], sh = bnB[cg];
#pragma unroll
        for (int rt = 0; rt < 4; ++rt) {
#pragma unroll
            for (int q = 0; q < 4; ++q) {
                int r = row0 + rt * 16 + rb + q;
                if (r < rows)
                    outF[(size_t)r * ostride + out_c0 + clocal] = f2bf(fmaxf(acc[rt][ctl][q] * s + sh, 0.0f));
            }
        }
    }
}

// ---------------- MFMA edge-MLP head: out[m] = relu(er @ W1.T + b1) @ W2.T + b2 --------------
__launch_bounds__(256)
__global__ void mlp_mfma(const u16* __restrict__ accF, const int* __restrict__ sidx,
                         const int* __restrict__ ridx, const float* __restrict__ txr,
                         const u16* __restrict__ W1c, const float* __restrict__ b1,
                         const float* __restrict__ W2, const float* __restrict__ b2,
                         float* __restrict__ out, int M) {
    __shared__ __align__(16) u16 Af[4][64][8];
    __shared__ __align__(16) u16 Bf[16][64][8];
    __shared__ float red[4][64];
    int tid = threadIdx.x;
    int w = tid >> 6, lane = tid & 63;
    int row0 = blockIdx.x * 64;
    int arow = tid >> 2, akg = tid & 3;
    int grow = row0 + arow;
    bool arok = grow < M;
    int si = arok ? sidx[grow] : 0;
    int ri = arok ? ridx[grow] : 0;
    int awslot = (akg * 16 + (arow & 15)) ^ (akg << 2);
    int arslot = lane ^ ((lane >> 4) << 2);
    const u16* wp0 = W1c + (size_t)tid * 544;

    f32x4 acc[4][4];
#pragma unroll
    for (int i = 0; i < 4; ++i)
#pragma unroll
        for (int j = 0; j < 4; ++j) acc[i][j] = (f32x4){0.f, 0.f, 0.f, 0.f};

    for (int kb = 0; kb < 544; kb += 32) {
        uint4 av = make_uint4(0, 0, 0, 0);
        if (arok) {
            int kg = kb + akg * 8;
            if (kg < 256) av = *(const uint4*)(accF + (size_t)si * H + kg);
            else if (kg < 512) av = *(const uint4*)(accF + (size_t)ri * H + (kg - 256));
            else {
                float4 f0 = *(const float4*)(txr + (size_t)grow * 32 + (kg - 512));
                float4 f1 = *(const float4*)(txr + (size_t)grow * 32 + (kg - 512) + 4);
                av.x = (u32)f2bf(f0.x) | ((u32)f2bf(f0.y) << 16);
                av.y = (u32)f2bf(f0.z) | ((u32)f2bf(f0.w) << 16);
                av.z = (u32)f2bf(f1.x) | ((u32)f2bf(f1.y) << 16);
                av.w = (u32)f2bf(f1.z) | ((u32)f2bf(f1.w) << 16);
            }
        }
        *(uint4*)(&Af[arow >> 4][awslot][0]) = av;
#pragma unroll
        for (int q = 0; q < 4; ++q) {
            uint4 wv = *(const uint4*)(wp0 + kb + q * 8);
            *(uint4*)(&Bf[tid >> 4][q * 16 + (tid & 15)][0]) = wv;
        }
        __syncthreads();
        bf16x8 afr[4];
#pragma unroll
        for (int rt = 0; rt < 4; ++rt)
            afr[rt] = *(const bf16x8*)(&Af[rt][arslot][0]);
#pragma unroll
        for (int ctl = 0; ctl < 4; ++ctl) {
            bf16x8 b = *(const bf16x8*)(&Bf[w * 4 + ctl][lane][0]);
#pragma unroll
            for (int rt = 0; rt < 4; ++rt)
                acc[rt][ctl] = __builtin_amdgcn_mfma_f32_16x16x32_bf16(afr[rt], b, acc[rt][ctl], 0, 0, 0);
        }
        __syncthreads();
    }
    // epilogue: relu(h + b1) . W2, reduce 16 col-lanes, then across 4 waves via LDS
    float part[4][4];
#pragma unroll
    for (int rt = 0; rt < 4; ++rt)
#pragma unroll
        for (int q = 0; q < 4; ++q) part[rt][q] = 0.0f;
#pragma unroll
    for (int ctl = 0; ctl < 4; ++ctl) {
        int cg = (w * 4 + ctl) * 16 + (lane & 15);
        float b1v = b1[cg], w2v = W2[cg];
#pragma unroll
        for (int rt = 0; rt < 4; ++rt)
#pragma unroll
            for (int q = 0; q < 4; ++q)
                part[rt][q] += fmaxf(acc[rt][ctl][q] + b1v, 0.0f) * w2v;
    }
    int rb = (lane >> 4) * 4;
#pragma unroll
    for (int rt = 0; rt < 4; ++rt)
#pragma unroll
        for (int q = 0; q < 4; ++q) {
            float p = part[rt][q];
            p += __shfl_xor(p, 1);
            p += __shfl_xor(p, 2);
            p += __shfl_xor(p, 4);
            p += __shfl_xor(p, 8);
            if ((lane & 15) == 0) red[w][rt * 16 + rb + q] = p;
        }
    __syncthreads();
    if (tid < 64) {
        int r = row0 + tid;
        if (r < M)
            out[r] = red[0][tid] + red[1][tid] + red[2][tid] + red[3][tid] + b2[0];
    }
}

// ---------------- host ----------------
static inline void fz(void* p, size_t bytes, hipStream_t s) {
    long long n = (long long)(bytes >> 2);
    int g = (int)(((n + 255) / 256 < 2048) ? (n + 255) / 256 : 2048);
    fillz_kernel<<<g, 256, 0, s>>>((u32*)p, n);
}
static inline size_t al256(size_t x) { return (x + 255) & ~(size_t)255; }

extern "C" void kernel_launch(void* const* d_in, const int* in_sizes, int n_in,
                              void* d_out, int out_size, void* d_ws, size_t ws_size,
                              hipStream_t stream) {
    const float* x_acc  = (const float*)d_in[0];
    const float* x_tx   = (const float*)d_in[1];
    const float* tx_raw = (const float*)d_in[2];
    const int* ei_sends = (const int*)d_in[3];
    const int* ei_recv  = (const int*)d_in[4];
    const int* sidx     = (const int*)d_in[5];
    const int* ridx     = (const int*)d_in[6];
    const float* W_acc  = (const float*)d_in[7];
    const float* b_acc  = (const float*)d_in[8];
    const float* W_tx   = (const float*)d_in[9];
    const float* b_tx   = (const float*)d_in[10];
    const float* Wl_at  = (const float*)d_in[11];
    const float* bl_at  = (const float*)d_in[12];
    const float* Wr_at  = (const float*)d_in[13];
    const float* Wl_ta  = (const float*)d_in[14];
    const float* bl_ta  = (const float*)d_in[15];
    const float* Wr_ta  = (const float*)d_in[16];
    const float* bng    = (const float*)d_in[17];
    const float* bnb    = (const float*)d_in[18];
    const float* bnm    = (const float*)d_in[19];
    const float* bnv    = (const float*)d_in[20];
    const float* W1     = (const float*)d_in[21];
    const float* b1     = (const float*)d_in[22];
    const float* W2     = (const float*)d_in[23];
    const float* b2     = (const float*)d_in[24];
    float* out = (float*)d_out;

    // shared fixed costs (bytes)
    const size_t szFeatA = (size_t)NACC * H * 2;
    const size_t szFeatT = (size_t)NTX * H * 2;
    const size_t szCSR = al256((NTX + 1) * 4) + al256(4096) + al256((NTX + 1) * 4)
                       + al256((size_t)NE * 4) + al256((NACC + 1) * 4) + al256((size_t)NE * 4);
    const size_t szW = 3 * al256(256 * 512 * 2) + al256(256 * 544 * 2) + 2 * al256(3 * 256 * 4);
    const int CCF = 32768;
    size_t needF = 2 * al256(szFeatA) + al256(szFeatT) + al256((size_t)CCF * H * 2)
                 + szCSR + szW + 65536;
    auto needS = [&](int S, int CC) {
        return 3 * al256(szFeatA) + szCSR + szW + 2 * al256((size_t)CC * H * 2)
             + al256((size_t)NTX * (H / S) * 2) + 65536;
    };
    int plan, S = 2, CC = CCF;
    if (needF <= ws_size)               { plan = 0; }
    else if (needS(2, 16384) <= ws_size) { plan = 1; S = 2; CC = 16384; }
    else if (needS(4, 16384) <= ws_size) { plan = 1; S = 4; CC = 16384; }
    else                                 { plan = 1; S = 4; CC = 2048; }

    char* wsp = (char*)d_ws;
    size_t off = 0;
    auto alloc = [&](size_t bytes) -> void* {
        void* p = wsp + off;
        off = al256(off + bytes);
        return p;
    };
    // common
    int* cnt   = (int*)alloc((NTX + 1) * 4);
    int* bsum  = (int*)alloc(4096);
    int* ptrT  = (int*)alloc((NTX + 1) * 4);
    int* permS = (int*)alloc((size_t)NE * 4);
    int* ptrA  = (int*)alloc((NACC + 1) * 4);
    int* permR = (int*)alloc((size_t)NE * 4);
    u16* Wc[3];
    Wc[0] = (u16*)alloc(256 * 512 * 2);   // cfg0: L0 ta (acc side)
    Wc[1] = (u16*)alloc(256 * 512 * 2);   // cfg1: L0 at (tx side)
    Wc[2] = (u16*)alloc(256 * 512 * 2);   // cfg2: L1 ta
    u16* W1c = (u16*)alloc(256 * 544 * 2);
    float* bnS = (float*)alloc(3 * 256 * 4);
    float* bnB = (float*)alloc(3 * 256 * 4);
    u16* A0f = (u16*)alloc(szFeatA);
    u16* A1f = (u16*)alloc(szFeatA);

    // ---- weight prep ----
    wcat_kernel<<<256, 256, 0, stream>>>(Wl_ta, Wr_ta, Wc[0]);
    wcat_kernel<<<256, 256, 0, stream>>>(Wl_at, Wr_at, Wc[1]);
    wcat_kernel<<<256, 256, 0, stream>>>(Wl_ta + H * H, Wr_ta + H * H, Wc[2]);
    w1cvt_kernel<<<256, 256, 0, stream>>>(W1, W1c);
    bnprep_kernel<<<1, 256, 0, stream>>>(bl_ta, bng, bnb, bnm, bnv, bnS, bnB);
    bnprep_kernel<<<1, 256, 0, stream>>>(bl_at, bng, bnb, bnm, bnv, bnS + 256, bnB + 256);
    bnprep_kernel<<<1, 256, 0, stream>>>(bl_ta + H, bng + H, bnb + H, bnm + H, bnv + H,
                                         bnS + 512, bnB + 512);

    // ---- CSR sends (dst = tx) ----
    const int EG = (NE + 255) / 256;
    const int nbT = (NTX + 1023) / 1024, nbA = (NACC + 1023) / 1024;
    fz(cnt, (size_t)NTX * 4, stream);
    count_kernel<<<EG, 256, 0, stream>>>(ei_sends + NE, NE, cnt);
    scan1_kernel<<<nbT, 256, 0, stream>>>(cnt, NTX, ptrT, bsum);
    scan2_kernel<<<1, 1024, 0, stream>>>(bsum, nbT);
    scan3_kernel<<<(NTX + 256) / 256 + 1, 256, 0, stream>>>(ptrT, bsum, NTX, NE);
    fz(cnt, (size_t)NTX * 4, stream);
    fillcsr_kernel<<<EG, 256, 0, stream>>>(ei_sends, ei_sends + NE, NE, ptrT, cnt, permS);
    // ---- CSR recv (dst = acc) ----
    fz(cnt, (size_t)NACC * 4, stream);
    count_kernel<<<EG, 256, 0, stream>>>(ei_recv + NE, NE, cnt);
    scan1_kernel<<<nbA, 256, 0, stream>>>(cnt, NACC, ptrA, bsum);
    scan2_kernel<<<1, 1024, 0, stream>>>(bsum, nbA);
    scan3_kernel<<<(NACC + 256) / 256 + 1, 256, 0, stream>>>(ptrA, bsum, NACC, NE);
    fz(cnt, (size_t)NACC * 4, stream);
    fillcsr_kernel<<<EG, 256, 0, stream>>>(ei_recv, ei_recv + NE, NE, ptrA, cnt, permR);

    // ---- acc projection ----
    proj_kernel<<<NACC, 256, 0, stream>>>(x_acc, W_acc, b_acc, A0f, NACC, 16, 0, H);

    const int gA = (NACC + 63) / 64, gM = (NM + 63) / 64;

    if (plan == 0) {
        // ======== PLAN FULL: T materialized once; aliasing: meanbuf<-A0f, A2<-T1 ========
        u16* T1     = (u16*)alloc(szFeatT);
        u16* meanTc = (u16*)alloc((size_t)CCF * H * 2);
        u16* A2 = (u16*)T1;   // L1 output overlays T1 (dead by then)

        // T0 full-width into T1 buffer
        proj_kernel<<<NTX, 256, 0, stream>>>(x_tx, W_tx, b_tx, T1, NTX, 32, 0, H);
        // L0 acc: mean_recv(T0) -> A1f; combine cfg0 (root A0f) in-place -> A1f
        gmean_kernel<256><<<(NACC + 3) / 4, 256, 0, stream>>>(T1, H, ptrA, permR, A1f, H, 0, NACC, 0);
        combine_mfma<256><<<gA, 256, 0, stream>>>(A1f, A0f, Wc[0], bnS, bnB, A1f, H, 0, NACC, 0);
        // L0 tx per chunk: mean_sends(A0f) -> meanTc; combine cfg1 in-place T0->T1
        for (int lo = 0; lo < NTX; lo += CCF) {
            int cur = (NTX - lo < CCF) ? (NTX - lo) : CCF;
            gmean_kernel<256><<<(cur + 3) / 4, 256, 0, stream>>>(A0f, H, ptrT, permS, meanTc, H, 0, cur, lo);
            combine_mfma<256><<<(cur + 63) / 64, 256, 0, stream>>>(
                meanTc, T1 + (size_t)lo * H, Wc[1], bnS + 256, bnB + 256,
                T1 + (size_t)lo * H, H, 0, cur, 0);
        }
        // L1 acc: mean_recv(T1) -> meanbuf(=A0f, now dead); combine cfg2 (root A1f) -> A2(=T1)
        gmean_kernel<256><<<(NACC + 3) / 4, 256, 0, stream>>>(T1, H, ptrA, permR, A0f, H, 0, NACC, 0);
        combine_mfma<256><<<gA, 256, 0, stream>>>(A0f, A1f, Wc[2], bnS + 512, bnB + 512, A2, H, 0, NACC, 0);
        // head
        mlp_mfma<<<gM, 256, 0, stream>>>(A2, sidx, ridx, tx_raw, W1c, b1, W2, b2, out, NM);
    } else {
        // ======== PLAN SLICED (round-4 structure, MFMA combines) ========
        u16* meanbuf = (u16*)alloc(szFeatA);
        u16* T0c     = (u16*)alloc((size_t)CC * H * 2);
        u16* meanTc  = (u16*)alloc((size_t)CC * H * 2);
        const int WSL = H / S;
        u16* Tslice  = (u16*)alloc((size_t)NTX * WSL * 2);

        // Phase A: L0 acc
        for (int s = 0; s < S; ++s) {
            int c0 = s * WSL;
            proj_kernel<<<NTX, WSL, 0, stream>>>(x_tx, W_tx, b_tx, Tslice, NTX, 32, c0, WSL);
            if (WSL == 128)
                gmean_kernel<128><<<(NACC + 7) / 8, 256, 0, stream>>>(Tslice, WSL, ptrA, permR, meanbuf, H, c0, NACC, 0);
            else
                gmean_kernel<64><<<(NACC + 15) / 16, 256, 0, stream>>>(Tslice, WSL, ptrA, permR, meanbuf, H, c0, NACC, 0);
        }
        combine_mfma<256><<<gA, 256, 0, stream>>>(meanbuf, A0f, Wc[0], bnS, bnB, A1f, H, 0, NACC, 0);
        // Phase B: T1 slices -> L1 means
        for (int s = 0; s < S; ++s) {
            int c0 = s * WSL;
            for (int lo = 0; lo < NTX; lo += CC) {
                int cur = (NTX - lo < CC) ? (NTX - lo) : CC;
                proj_kernel<<<cur, 256, 0, stream>>>(x_tx + (size_t)lo * 32, W_tx, b_tx, T0c, cur, 32, 0, H);
                gmean_kernel<256><<<(cur + 3) / 4, 256, 0, stream>>>(A0f, H, ptrT, permS, meanTc, H, 0, cur, lo);
                if (WSL == 128)
                    combine_mfma<128><<<(cur + 63) / 64, 256, 0, stream>>>(
                        meanTc, T0c, Wc[1], bnS + 256, bnB + 256,
                        Tslice + (size_t)lo * WSL, WSL, 0, cur, c0);
                else
                    combine_mfma<64><<<(cur + 63) / 64, 256, 0, stream>>>(
                        meanTc, T0c, Wc[1], bnS + 256, bnB + 256,
                        Tslice + (size_t)lo * WSL, WSL, 0, cur, c0);
            }
            if (WSL == 128)
                gmean_kernel<128><<<(NACC + 7) / 8, 256, 0, stream>>>(Tslice, WSL, ptrA, permR, meanbuf, H, c0, NACC, 0);
            else
                gmean_kernel<64><<<(NACC + 15) / 16, 256, 0, stream>>>(Tslice, WSL, ptrA, permR, meanbuf, H, c0, NACC, 0);
        }
        combine_mfma<256><<<gA, 256, 0, stream>>>(meanbuf, A1f, Wc[2], bnS + 512, bnB + 512, A0f, H, 0, NACC, 0);
        mlp_mfma<<<gM, 256, 0, stream>>>(A0f, sidx, ridx, tx_raw, W1c, b1, W2, b2, out, NM);
    }
}

// Round 6
// 2416.712 us; speedup vs baseline: 5.8995x; 2.1742x over previous
//
#include <hip/hip_runtime.h>
#include <hip/hip_bf16.h>

#define H 256
#define NACC 100000
#define NTX  300000
#define NE   600000
#define NM   300000

typedef unsigned short u16;
typedef unsigned int u32;
typedef __bf16 bf16x8 __attribute__((ext_vector_type(8)));
typedef float f32x4 __attribute__((ext_vector_type(4)));

__device__ __forceinline__ float bf2f(u32 u) {
    union { u32 i; float f; } v; v.i = u << 16; return v.f;
}
__device__ __forceinline__ u16 f2bf(float f) {
    union { float f; u32 i; } v; v.f = f;
    u32 r = v.i + 0x7FFFu + ((v.i >> 16) & 1u);
    return (u16)(r >> 16);
}

// ---------------- zero fill (no hipMemsetAsync: breaks graph capture) ----------------
__global__ void fillz_kernel(u32* __restrict__ p, long long n) {
    long long i = (long long)blockIdx.x * blockDim.x + threadIdx.x;
    long long st = (long long)gridDim.x * blockDim.x;
    for (; i < n; i += st) p[i] = 0u;
}

// ---------------- weight prep ----------------
__global__ void wcat_kernel(const float* __restrict__ Wl, const float* __restrict__ Wr,
                            u16* __restrict__ dst) {
    int c = blockIdx.x, t = threadIdx.x;
    dst[(size_t)c * 512 + t]       = f2bf(Wl[(size_t)c * 256 + t]);
    dst[(size_t)c * 512 + 256 + t] = f2bf(Wr[(size_t)c * 256 + t]);
}
__global__ void w1cvt_kernel(const float* __restrict__ W1, u16* __restrict__ dst) {
    int c = blockIdx.x, t = threadIdx.x;
    for (int k = t; k < 544; k += 256)
        dst[(size_t)c * 544 + k] = f2bf(W1[(size_t)c * 544 + k]);
}
__global__ void bnprep_kernel(const float* __restrict__ bl, const float* __restrict__ g,
                              const float* __restrict__ be, const float* __restrict__ m,
                              const float* __restrict__ v,
                              float* __restrict__ S, float* __restrict__ B) {
    int c = threadIdx.x;
    float s = g[c] * rsqrtf(v[c] + 1e-5f);
    S[c] = s;
    B[c] = (bl[c] - m[c]) * s + be[c];
}

// ---------------- proj2: 128-row tile GEMM, col-pair per thread, weights in regs ----------------
// out[r][lt] = relu(x[r] . W[c0+lt] + b[c0+lt]) as bf16, lt in [0, NC)
template <int K, int NC>
__launch_bounds__(256)
__global__ void proj2_kernel(const float* __restrict__ x, const float* __restrict__ W,
                             const float* __restrict__ b, u16* __restrict__ out,
                             int N, int c0, int ost) {
    __shared__ float xs[128][K + 4];
    constexpr int NG = 512 / NC;      // rowgroups (2/4/8)
    constexpr int RPT = 128 / NG;     // rows per thread
    int tid = threadIdx.x;
    int row0 = blockIdx.x * 128;
    // stage x tile (coalesced float4)
    constexpr int NF4 = 128 * K / 4;
    for (int f = tid; f < NF4; f += 256) {
        int r = f / (K / 4), kq = (f % (K / 4)) * 4;
        int gr = row0 + r;
        float4 v = (gr < N) ? *(const float4*)(x + (size_t)gr * K + kq)
                            : make_float4(0.f, 0.f, 0.f, 0.f);
        *(float4*)&xs[r][kq] = v;
    }
    // weights for this thread's col pair
    int lt2 = (tid % (NC / 2)) * 2;
    int g = tid / (NC / 2);
    float wa[K], wb[K];
    const float* wpa = W + (size_t)(c0 + lt2) * K;
#pragma unroll
    for (int k = 0; k < K; k += 4) {
        float4 va = *(const float4*)(wpa + k);
        float4 vb = *(const float4*)(wpa + K + k);
        wa[k] = va.x; wa[k + 1] = va.y; wa[k + 2] = va.z; wa[k + 3] = va.w;
        wb[k] = vb.x; wb[k + 1] = vb.y; wb[k + 2] = vb.z; wb[k + 3] = vb.w;
    }
    float b0 = b[c0 + lt2], b1 = b[c0 + lt2 + 1];
    __syncthreads();
#pragma unroll
    for (int rr = 0; rr < RPT; ++rr) {
        int r = g * RPT + rr;
        int gr = row0 + r;
        float a0 = b0, a1 = b1;
#pragma unroll
        for (int k = 0; k < K; k += 4) {
            float4 xv = *(const float4*)&xs[r][k];
            a0 += xv.x * wa[k] + xv.y * wa[k + 1] + xv.z * wa[k + 2] + xv.w * wa[k + 3];
            a1 += xv.x * wb[k] + xv.y * wb[k + 1] + xv.z * wb[k + 2] + xv.w * wb[k + 3];
        }
        if (gr < N) {
            u32 pk = (u32)f2bf(fmaxf(a0, 0.f)) | ((u32)f2bf(fmaxf(a1, 0.f)) << 16);
            *(u32*)(out + (size_t)gr * ost + lt2) = pk;
        }
    }
}

// ---------------- CSR build (validated) ----------------
__global__ void count_kernel(const int* __restrict__ dst, int E, int* __restrict__ cnt) {
    int e = blockIdx.x * blockDim.x + threadIdx.x;
    if (e < E) atomicAdd(&cnt[dst[e]], 1);
}
__global__ void scan1_kernel(const int* __restrict__ cnt, int N,
                             int* __restrict__ loc, int* __restrict__ bsum) {
    __shared__ int sh[256];
    int b = blockIdx.x, t = threadIdx.x;
    int base = b * 1024 + t * 4;
    int v0 = (base + 0 < N) ? cnt[base + 0] : 0;
    int v1 = (base + 1 < N) ? cnt[base + 1] : 0;
    int v2 = (base + 2 < N) ? cnt[base + 2] : 0;
    int v3 = (base + 3 < N) ? cnt[base + 3] : 0;
    int s = v0 + v1 + v2 + v3;
    sh[t] = s;
    __syncthreads();
    for (int o = 1; o < 256; o <<= 1) {
        int y = (t >= o) ? sh[t - o] : 0;
        __syncthreads();
        sh[t] += y;
        __syncthreads();
    }
    int run = sh[t] - s;
    if (base + 0 < N) loc[base + 0] = run; run += v0;
    if (base + 1 < N) loc[base + 1] = run; run += v1;
    if (base + 2 < N) loc[base + 2] = run; run += v2;
    if (base + 3 < N) loc[base + 3] = run;
    if (t == 0) bsum[b] = sh[255];
}
__global__ void scan2_kernel(int* __restrict__ bsum, int nb) {
    __shared__ int sh[1024];
    int t = threadIdx.x;
    int v = (t < nb) ? bsum[t] : 0;
    sh[t] = v;
    __syncthreads();
    for (int o = 1; o < 1024; o <<= 1) {
        int y = (t >= o) ? sh[t - o] : 0;
        __syncthreads();
        sh[t] += y;
        __syncthreads();
    }
    if (t < nb) bsum[t] = sh[t] - v;
}
__global__ void scan3_kernel(int* __restrict__ ptr, const int* __restrict__ bsum,
                             int N, int total) {
    int i = blockIdx.x * blockDim.x + threadIdx.x;
    if (i < N) ptr[i] += bsum[i >> 10];
    else if (i == N) ptr[N] = total;
}
__global__ void fillcsr_kernel(const int* __restrict__ src, const int* __restrict__ dst, int E,
                               const int* __restrict__ ptr, int* __restrict__ cur,
                               int* __restrict__ perm) {
    int e = blockIdx.x * blockDim.x + threadIdx.x;
    if (e < E) {
        int d = dst[e];
        int pos = ptr[d] + atomicAdd(&cur[d], 1);
        perm[pos] = src[e];
    }
}

// ---------------- gather-mean over a column-slice of width WS (validated) ------------
template <int WS>
__launch_bounds__(256)
__global__ void gmean_kernel(const u16* __restrict__ feat, int fstride,
                             const int* __restrict__ ptr, const int* __restrict__ perm,
                             u16* __restrict__ out, int ostride, int c0,
                             int rows, int lo) {
    constexpr int LPD = WS / 4;
    constexpr int DPB = 256 / LPD;
    int g = threadIdx.x / LPD;
    int ln = threadIdx.x % LPD;
    int w = blockIdx.x * DPB + g;
    if (w >= rows) return;
    int d = lo + w;
    int e0 = ptr[d], e1 = ptr[d + 1];
    float a0 = 0.f, a1 = 0.f, a2 = 0.f, a3 = 0.f;
    for (int e = e0; e < e1; ++e) {
        int s = perm[e];
        uint2 v = *(const uint2*)(feat + (size_t)s * fstride + (ln << 2));
        a0 += bf2f(v.x & 0xffff); a1 += bf2f(v.x >> 16);
        a2 += bf2f(v.y & 0xffff); a3 += bf2f(v.y >> 16);
    }
    int deg = e1 - e0;
    float sc = (deg > 0) ? (1.0f / (float)deg) : 0.0f;
    uint2 pk;
    pk.x = (u32)f2bf(a0 * sc) | ((u32)f2bf(a1 * sc) << 16);
    pk.y = (u32)f2bf(a2 * sc) | ((u32)f2bf(a3 * sc) << 16);
    *(uint2*)(out + (size_t)w * ostride + c0 + (ln << 2)) = pk;
}

// ---------------- MFMA SAGE combine (validated round 5) ----------------
template <int COLS>
__launch_bounds__(256)
__global__ void combine_mfma(const u16* __restrict__ mean_, const u16* __restrict__ xd,
                             const u16* __restrict__ Wcat,
                             const float* __restrict__ bnS, const float* __restrict__ bnB,
                             u16* __restrict__ outF, int ostride, int out_c0,
                             int rows, int c0) {
    constexpr int NCT = COLS / 16;
    constexpr int CTW = NCT / 4;
    constexpr int PPT = (COLS * 4) / 256;
    __shared__ __align__(16) u16 Af[4][64][8];
    __shared__ __align__(16) u16 Bf[NCT][64][8];
    int tid = threadIdx.x;
    int w = tid >> 6, lane = tid & 63;
    int row0 = blockIdx.x * 64;
    int arow = tid >> 2, akg = tid & 3;
    bool arok = (row0 + arow) < rows;
    const u16* am = mean_ + (size_t)(row0 + arow) * H;
    const u16* ax = xd + (size_t)(row0 + arow) * H;
    int awslot = (akg * 16 + (arow & 15)) ^ (akg << 2);
    int arslot = lane ^ ((lane >> 4) << 2);
    int bc = tid % COLS;
    int bkg0 = (tid / COLS) * PPT;
    const u16* wp0 = Wcat + (size_t)(c0 + bc) * 512 + bkg0 * 8;

    f32x4 acc[4][CTW];
#pragma unroll
    for (int i = 0; i < 4; ++i)
#pragma unroll
        for (int j = 0; j < CTW; ++j) acc[i][j] = (f32x4){0.f, 0.f, 0.f, 0.f};

    for (int kb = 0; kb < 512; kb += 32) {
        uint4 av = make_uint4(0, 0, 0, 0);
        if (arok) {
            int kg = kb + akg * 8;
            av = (kg < 256) ? *(const uint4*)(am + kg) : *(const uint4*)(ax + (kg - 256));
        }
        *(uint4*)(&Af[arow >> 4][awslot][0]) = av;
#pragma unroll
        for (int q = 0; q < PPT; ++q) {
            uint4 wv = *(const uint4*)(wp0 + kb + q * 8);
            *(uint4*)(&Bf[bc >> 4][(bkg0 + q) * 16 + (bc & 15)][0]) = wv;
        }
        __syncthreads();
        bf16x8 afr[4];
#pragma unroll
        for (int rt = 0; rt < 4; ++rt)
            afr[rt] = *(const bf16x8*)(&Af[rt][arslot][0]);
#pragma unroll
        for (int ctl = 0; ctl < CTW; ++ctl) {
            bf16x8 b = *(const bf16x8*)(&Bf[w * CTW + ctl][lane][0]);
#pragma unroll
            for (int rt = 0; rt < 4; ++rt)
                acc[rt][ctl] = __builtin_amdgcn_mfma_f32_16x16x32_bf16(afr[rt], b, acc[rt][ctl], 0, 0, 0);
        }
        __syncthreads();
    }
    int rb = (lane >> 4) * 4;
    int ccol = lane & 15;
#pragma unroll
    for (int ctl = 0; ctl < CTW; ++ctl) {
        int clocal = (w * CTW + ctl) * 16 + ccol;
        int cg = c0 + clocal;
        float s = bnS[cg], sh = bnB[cg];
#pragma unroll
        for (int rt = 0; rt < 4; ++rt) {
#pragma unroll
            for (int q = 0; q < 4; ++q) {
                int r = row0 + rt * 16 + rb + q;
                if (r < rows)
                    outF[(size_t)r * ostride + out_c0 + clocal] = f2bf(fmaxf(acc[rt][ctl][q] * s + sh, 0.0f));
            }
        }
    }
}

// ---------------- MFMA edge-MLP head (validated round 5) --------------
__launch_bounds__(256)
__global__ void mlp_mfma(const u16* __restrict__ accF, const int* __restrict__ sidx,
                         const int* __restrict__ ridx, const float* __restrict__ txr,
                         const u16* __restrict__ W1c, const float* __restrict__ b1,
                         const float* __restrict__ W2, const float* __restrict__ b2,
                         float* __restrict__ out, int M) {
    __shared__ __align__(16) u16 Af[4][64][8];
    __shared__ __align__(16) u16 Bf[16][64][8];
    __shared__ float red[4][64];
    int tid = threadIdx.x;
    int w = tid >> 6, lane = tid & 63;
    int row0 = blockIdx.x * 64;
    int arow = tid >> 2, akg = tid & 3;
    int grow = row0 + arow;
    bool arok = grow < M;
    int si = arok ? sidx[grow] : 0;
    int ri = arok ? ridx[grow] : 0;
    int awslot = (akg * 16 + (arow & 15)) ^ (akg << 2);
    int arslot = lane ^ ((lane >> 4) << 2);
    const u16* wp0 = W1c + (size_t)tid * 544;

    f32x4 acc[4][4];
#pragma unroll
    for (int i = 0; i < 4; ++i)
#pragma unroll
        for (int j = 0; j < 4; ++j) acc[i][j] = (f32x4){0.f, 0.f, 0.f, 0.f};

    for (int kb = 0; kb < 544; kb += 32) {
        uint4 av = make_uint4(0, 0, 0, 0);
        if (arok) {
            int kg = kb + akg * 8;
            if (kg < 256) av = *(const uint4*)(accF + (size_t)si * H + kg);
            else if (kg < 512) av = *(const uint4*)(accF + (size_t)ri * H + (kg - 256));
            else {
                float4 f0 = *(const float4*)(txr + (size_t)grow * 32 + (kg - 512));
                float4 f1 = *(const float4*)(txr + (size_t)grow * 32 + (kg - 512) + 4);
                av.x = (u32)f2bf(f0.x) | ((u32)f2bf(f0.y) << 16);
                av.y = (u32)f2bf(f0.z) | ((u32)f2bf(f0.w) << 16);
                av.z = (u32)f2bf(f1.x) | ((u32)f2bf(f1.y) << 16);
                av.w = (u32)f2bf(f1.z) | ((u32)f2bf(f1.w) << 16);
            }
        }
        *(uint4*)(&Af[arow >> 4][awslot][0]) = av;
#pragma unroll
        for (int q = 0; q < 4; ++q) {
            uint4 wv = *(const uint4*)(wp0 + kb + q * 8);
            *(uint4*)(&Bf[tid >> 4][q * 16 + (tid & 15)][0]) = wv;
        }
        __syncthreads();
        bf16x8 afr[4];
#pragma unroll
        for (int rt = 0; rt < 4; ++rt)
            afr[rt] = *(const bf16x8*)(&Af[rt][arslot][0]);
#pragma unroll
        for (int ctl = 0; ctl < 4; ++ctl) {
            bf16x8 b = *(const bf16x8*)(&Bf[w * 4 + ctl][lane][0]);
#pragma unroll
            for (int rt = 0; rt < 4; ++rt)
                acc[rt][ctl] = __builtin_amdgcn_mfma_f32_16x16x32_bf16(afr[rt], b, acc[rt][ctl], 0, 0, 0);
        }
        __syncthreads();
    }
    float part[4][4];
#pragma unroll
    for (int rt = 0; rt < 4; ++rt)
#pragma unroll
        for (int q = 0; q < 4; ++q) part[rt][q] = 0.0f;
#pragma unroll
    for (int ctl = 0; ctl < 4; ++ctl) {
        int cg = (w * 4 + ctl) * 16 + (lane & 15);
        float b1v = b1[cg], w2v = W2[cg];
#pragma unroll
        for (int rt = 0; rt < 4; ++rt)
#pragma unroll
            for (int q = 0; q < 4; ++q)
                part[rt][q] += fmaxf(acc[rt][ctl][q] + b1v, 0.0f) * w2v;
    }
    int rb = (lane >> 4) * 4;
#pragma unroll
    for (int rt = 0; rt < 4; ++rt)
#pragma unroll
        for (int q = 0; q < 4; ++q) {
            float p = part[rt][q];
            p += __shfl_xor(p, 1);
            p += __shfl_xor(p, 2);
            p += __shfl_xor(p, 4);
            p += __shfl_xor(p, 8);
            if ((lane & 15) == 0) red[w][rt * 16 + rb + q] = p;
        }
    __syncthreads();
    if (tid < 64) {
        int r = row0 + tid;
        if (r < M)
            out[r] = red[0][tid] + red[1][tid] + red[2][tid] + red[3][tid] + b2[0];
    }
}

// ---------------- host ----------------
static inline void fz(void* p, size_t bytes, hipStream_t s) {
    long long n = (long long)(bytes >> 2);
    int g = (int)(((n + 255) / 256 < 2048) ? (n + 255) / 256 : 2048);
    fillz_kernel<<<g, 256, 0, s>>>((u32*)p, n);
}
static inline size_t al256(size_t x) { return (x + 255) & ~(size_t)255; }

extern "C" void kernel_launch(void* const* d_in, const int* in_sizes, int n_in,
                              void* d_out, int out_size, void* d_ws, size_t ws_size,
                              hipStream_t stream) {
    const float* x_acc  = (const float*)d_in[0];
    const float* x_tx   = (const float*)d_in[1];
    const float* tx_raw = (const float*)d_in[2];
    const int* ei_sends = (const int*)d_in[3];
    const int* ei_recv  = (const int*)d_in[4];
    const int* sidx     = (const int*)d_in[5];
    const int* ridx     = (const int*)d_in[6];
    const float* W_acc  = (const float*)d_in[7];
    const float* b_acc  = (const float*)d_in[8];
    const float* W_tx   = (const float*)d_in[9];
    const float* b_tx   = (const float*)d_in[10];
    const float* Wl_at  = (const float*)d_in[11];
    const float* bl_at  = (const float*)d_in[12];
    const float* Wr_at  = (const float*)d_in[13];
    const float* Wl_ta  = (const float*)d_in[14];
    const float* bl_ta  = (const float*)d_in[15];
    const float* Wr_ta  = (const float*)d_in[16];
    const float* bng    = (const float*)d_in[17];
    const float* bnb    = (const float*)d_in[18];
    const float* bnm    = (const float*)d_in[19];
    const float* bnv    = (const float*)d_in[20];
    const float* W1     = (const float*)d_in[21];
    const float* b1     = (const float*)d_in[22];
    const float* W2     = (const float*)d_in[23];
    const float* b2     = (const float*)d_in[24];
    float* out = (float*)d_out;

    const size_t szFeatA = (size_t)NACC * H * 2;
    const size_t szFeatT = (size_t)NTX * H * 2;
    const size_t szCSR = al256((NTX + 1) * 4) + al256(4096) + al256((NTX + 1) * 4)
                       + al256((size_t)NE * 4) + al256((NACC + 1) * 4) + al256((size_t)NE * 4);
    const size_t szW = 3 * al256(256 * 512 * 2) + al256(256 * 544 * 2) + 2 * al256(3 * 256 * 4);

    // plan FULL feasibility: fixed part + adaptive meanTc chunk
    size_t fixedF = szCSR + szW + 2 * al256(szFeatA) + al256(szFeatT) + 131072;
    long long remF = (long long)ws_size - (long long)fixedF;
    long long ccf = remF > 0 ? remF / (H * 2) : 0;
    int CCf = (int)((ccf > 32768) ? 32768 : ccf);
    CCf &= ~255;
    auto needS = [&](int S, int CC) {
        return 3 * al256(szFeatA) + szCSR + szW + 2 * al256((size_t)CC * H * 2)
             + al256((size_t)NTX * (H / S) * 2) + 65536;
    };
    int plan, S = 2, CC = 16384;
    if (CCf >= 4096)                     { plan = 0; }
    else if (needS(2, 16384) <= ws_size) { plan = 1; S = 2; CC = 16384; }
    else if (needS(4, 16384) <= ws_size) { plan = 1; S = 4; CC = 16384; }
    else                                 { plan = 1; S = 4; CC = 2048; }

    char* wsp = (char*)d_ws;
    size_t off = 0;
    auto alloc = [&](size_t bytes) -> void* {
        void* p = wsp + off;
        off = al256(off + bytes);
        return p;
    };
    int* cnt   = (int*)alloc((NTX + 1) * 4);
    int* bsum  = (int*)alloc(4096);
    int* ptrT  = (int*)alloc((NTX + 1) * 4);
    int* permS = (int*)alloc((size_t)NE * 4);
    int* ptrA  = (int*)alloc((NACC + 1) * 4);
    int* permR = (int*)alloc((size_t)NE * 4);
    u16* Wc[3];
    Wc[0] = (u16*)alloc(256 * 512 * 2);
    Wc[1] = (u16*)alloc(256 * 512 * 2);
    Wc[2] = (u16*)alloc(256 * 512 * 2);
    u16* W1c = (u16*)alloc(256 * 544 * 2);
    float* bnS = (float*)alloc(3 * 256 * 4);
    float* bnB = (float*)alloc(3 * 256 * 4);
    u16* A0f = (u16*)alloc(szFeatA);
    u16* A1f = (u16*)alloc(szFeatA);

    // ---- weight prep ----
    wcat_kernel<<<256, 256, 0, stream>>>(Wl_ta, Wr_ta, Wc[0]);
    wcat_kernel<<<256, 256, 0, stream>>>(Wl_at, Wr_at, Wc[1]);
    wcat_kernel<<<256, 256, 0, stream>>>(Wl_ta + H * H, Wr_ta + H * H, Wc[2]);
    w1cvt_kernel<<<256, 256, 0, stream>>>(W1, W1c);
    bnprep_kernel<<<1, 256, 0, stream>>>(bl_ta, bng, bnb, bnm, bnv, bnS, bnB);
    bnprep_kernel<<<1, 256, 0, stream>>>(bl_at, bng, bnb, bnm, bnv, bnS + 256, bnB + 256);
    bnprep_kernel<<<1, 256, 0, stream>>>(bl_ta + H, bng + H, bnb + H, bnm + H, bnv + H,
                                         bnS + 512, bnB + 512);

    // ---- CSR sends (dst = tx) ----
    const int EG = (NE + 255) / 256;
    const int nbT = (NTX + 1023) / 1024, nbA = (NACC + 1023) / 1024;
    fz(cnt, (size_t)NTX * 4, stream);
    count_kernel<<<EG, 256, 0, stream>>>(ei_sends + NE, NE, cnt);
    scan1_kernel<<<nbT, 256, 0, stream>>>(cnt, NTX, ptrT, bsum);
    scan2_kernel<<<1, 1024, 0, stream>>>(bsum, nbT);
    scan3_kernel<<<(NTX + 256) / 256 + 1, 256, 0, stream>>>(ptrT, bsum, NTX, NE);
    fz(cnt, (size_t)NTX * 4, stream);
    fillcsr_kernel<<<EG, 256, 0, stream>>>(ei_sends, ei_sends + NE, NE, ptrT, cnt, permS);
    // ---- CSR recv (dst = acc) ----
    fz(cnt, (size_t)NACC * 4, stream);
    count_kernel<<<EG, 256, 0, stream>>>(ei_recv + NE, NE, cnt);
    scan1_kernel<<<nbA, 256, 0, stream>>>(cnt, NACC, ptrA, bsum);
    scan2_kernel<<<1, 1024, 0, stream>>>(bsum, nbA);
    scan3_kernel<<<(NACC + 256) / 256 + 1, 256, 0, stream>>>(ptrA, bsum, NACC, NE);
    fz(cnt, (size_t)NACC * 4, stream);
    fillcsr_kernel<<<EG, 256, 0, stream>>>(ei_recv, ei_recv + NE, NE, ptrA, cnt, permR);

    // ---- acc projection ----
    proj2_kernel<16, 256><<<(NACC + 127) / 128, 256, 0, stream>>>(x_acc, W_acc, b_acc, A0f, NACC, 0, H);

    const int gA = (NACC + 63) / 64, gM = (NM + 63) / 64;

    if (plan == 0) {
        // ======== PLAN FULL ========
        u16* T1     = (u16*)alloc(szFeatT);
        u16* meanTc = (u16*)alloc((size_t)CCf * H * 2);
        u16* A2 = (u16*)T1;

        proj2_kernel<32, 256><<<(NTX + 127) / 128, 256, 0, stream>>>(x_tx, W_tx, b_tx, T1, NTX, 0, H);
        gmean_kernel<256><<<(NACC + 3) / 4, 256, 0, stream>>>(T1, H, ptrA, permR, A1f, H, 0, NACC, 0);
        combine_mfma<256><<<gA, 256, 0, stream>>>(A1f, A0f, Wc[0], bnS, bnB, A1f, H, 0, NACC, 0);
        for (int lo = 0; lo < NTX; lo += CCf) {
            int cur = (NTX - lo < CCf) ? (NTX - lo) : CCf;
            gmean_kernel<256><<<(cur + 3) / 4, 256, 0, stream>>>(A0f, H, ptrT, permS, meanTc, H, 0, cur, lo);
            combine_mfma<256><<<(cur + 63) / 64, 256, 0, stream>>>(
                meanTc, T1 + (size_t)lo * H, Wc[1], bnS + 256, bnB + 256,
                T1 + (size_t)lo * H, H, 0, cur, 0);
        }
        gmean_kernel<256><<<(NACC + 3) / 4, 256, 0, stream>>>(T1, H, ptrA, permR, A0f, H, 0, NACC, 0);
        combine_mfma<256><<<gA, 256, 0, stream>>>(A0f, A1f, Wc[2], bnS + 512, bnB + 512, A2, H, 0, NACC, 0);
        mlp_mfma<<<gM, 256, 0, stream>>>(A2, sidx, ridx, tx_raw, W1c, b1, W2, b2, out, NM);
    } else {
        // ======== PLAN SLICED ========
        u16* meanbuf = (u16*)alloc(szFeatA);
        u16* T0c     = (u16*)alloc((size_t)CC * H * 2);
        u16* meanTc  = (u16*)alloc((size_t)CC * H * 2);
        const int WSL = H / S;
        u16* Tslice  = (u16*)alloc((size_t)NTX * WSL * 2);

        for (int s = 0; s < S; ++s) {
            int c0 = s * WSL;
            if (WSL == 128)
                proj2_kernel<32, 128><<<(NTX + 127) / 128, 256, 0, stream>>>(x_tx, W_tx, b_tx, Tslice, NTX, c0, WSL);
            else
                proj2_kernel<32, 64><<<(NTX + 127) / 128, 256, 0, stream>>>(x_tx, W_tx, b_tx, Tslice, NTX, c0, WSL);
            if (WSL == 128)
                gmean_kernel<128><<<(NACC + 7) / 8, 256, 0, stream>>>(Tslice, WSL, ptrA, permR, meanbuf, H, c0, NACC, 0);
            else
                gmean_kernel<64><<<(NACC + 15) / 16, 256, 0, stream>>>(Tslice, WSL, ptrA, permR, meanbuf, H, c0, NACC, 0);
        }
        combine_mfma<256><<<gA, 256, 0, stream>>>(meanbuf, A0f, Wc[0], bnS, bnB, A1f, H, 0, NACC, 0);
        for (int s = 0; s < S; ++s) {
            int c0 = s * WSL;
            for (int lo = 0; lo < NTX; lo += CC) {
                int cur = (NTX - lo < CC) ? (NTX - lo) : CC;
                proj2_kernel<32, 256><<<(cur + 127) / 128, 256, 0, stream>>>(x_tx + (size_t)lo * 32, W_tx, b_tx, T0c, cur, 0, H);
                gmean_kernel<256><<<(cur + 3) / 4, 256, 0, stream>>>(A0f, H, ptrT, permS, meanTc, H, 0, cur, lo);
                if (WSL == 128)
                    combine_mfma<128><<<(cur + 63) / 64, 256, 0, stream>>>(
                        meanTc, T0c, Wc[1], bnS + 256, bnB + 256,
                        Tslice + (size_t)lo * WSL, WSL, 0, cur, c0);
                else
                    combine_mfma<64><<<(cur + 63) / 64, 256, 0, stream>>>(
                        meanTc, T0c, Wc[1], bnS + 256, bnB + 256,
                        Tslice + (size_t)lo * WSL, WSL, 0, cur, c0);
            }
            if (WSL == 128)
                gmean_kernel<128><<<(NACC + 7) / 8, 256, 0, stream>>>(Tslice, WSL, ptrA, permR, meanbuf, H, c0, NACC, 0);
            else
                gmean_kernel<64><<<(NACC + 15) / 16, 256, 0, stream>>>(Tslice, WSL, ptrA, permR, meanbuf, H, c0, NACC, 0);
        }
        combine_mfma<256><<<gA, 256, 0, stream>>>(meanbuf, A1f, Wc[2], bnS + 512, bnB + 512, A0f, H, 0, NACC, 0);
        mlp_mfma<<<gM, 256, 0, stream>>>(A0f, sidx, ridx, tx_raw, W1c, b1, W2, b2, out, NM);
    }
}

// Round 7
// 1369.728 us; speedup vs baseline: 10.4090x; 1.7644x over previous
//
#include <hip/hip_runtime.h>
#include <hip/hip_bf16.h>

#define H 256
#define NACC 100000
#define NTX  300000
#define NE   600000
#define NM   300000

typedef unsigned short u16;
typedef unsigned int u32;
typedef __bf16 bf16x8 __attribute__((ext_vector_type(8)));
typedef float f32x4 __attribute__((ext_vector_type(4)));

__device__ __forceinline__ float bf2f(u32 u) {
    union { u32 i; float f; } v; v.i = u << 16; return v.f;
}
__device__ __forceinline__ u16 f2bf(float f) {
    union { float f; u32 i; } v; v.f = f;
    u32 r = v.i + 0x7FFFu + ((v.i >> 16) & 1u);
    return (u16)(r >> 16);
}
__device__ __forceinline__ u32 pk2(float a, float b) {
    return (u32)f2bf(a) | ((u32)f2bf(b) << 16);
}

// ---------------- zero fill (no hipMemsetAsync: breaks graph capture) ----------------
__global__ void fillz_kernel(u32* __restrict__ p, long long n) {
    long long i = (long long)blockIdx.x * blockDim.x + threadIdx.x;
    long long st = (long long)gridDim.x * blockDim.x;
    for (; i < n; i += st) p[i] = 0u;
}

// ---------------- weight prep ----------------
__global__ void wcat_kernel(const float* __restrict__ Wl, const float* __restrict__ Wr,
                            u16* __restrict__ dst) {
    int c = blockIdx.x, t = threadIdx.x;
    dst[(size_t)c * 512 + t]       = f2bf(Wl[(size_t)c * 256 + t]);
    dst[(size_t)c * 512 + 256 + t] = f2bf(Wr[(size_t)c * 256 + t]);
}
__global__ void w1cvt_kernel(const float* __restrict__ W1, u16* __restrict__ dst) {
    int c = blockIdx.x, t = threadIdx.x;
    for (int k = t; k < 544; k += 256)
        dst[(size_t)c * 544 + k] = f2bf(W1[(size_t)c * 544 + k]);
}
// project-weight to bf16 [256][32], zero-padded past K
__global__ void wproj_kernel(const float* __restrict__ W, u16* __restrict__ dst, int K) {
    int c = blockIdx.x, t = threadIdx.x;   // 32 threads
    dst[(size_t)c * 32 + t] = (t < K) ? f2bf(W[(size_t)c * K + t]) : (u16)0;
}
__global__ void bnprep_kernel(const float* __restrict__ bl, const float* __restrict__ g,
                              const float* __restrict__ be, const float* __restrict__ m,
                              const float* __restrict__ v,
                              float* __restrict__ S, float* __restrict__ B) {
    int c = threadIdx.x;
    float s = g[c] * rsqrtf(v[c] + 1e-5f);
    S[c] = s;
    B[c] = (bl[c] - m[c]) * s + be[c];
}

// ---------------- MFMA projection: out = relu(x @ Wb.T + b) bf16, 128 rows x 256 cols/block ------
// KK = logical K of x (16 or 32); Wb is [256][32] bf16 zero-padded.
template <int KK>
__launch_bounds__(256)
__global__ void proj_mfma(const float* __restrict__ x, const u16* __restrict__ Wb,
                          const float* __restrict__ b, u16* __restrict__ out, int N) {
    __shared__ __align__(16) u16 Af[8][64][8];
    __shared__ __align__(16) u16 Bf[16][64][8];
    int tid = threadIdx.x;
    int w = tid >> 6, lane = tid & 63;
    int row0 = blockIdx.x * 128;
    // stage A: thread -> row r = tid>>1, half h = tid&1 (k-groups 2h, 2h+1)
    {
        int r = tid >> 1, h = tid & 1;
        int gr = row0 + r;
        int rt = r >> 4, rr = r & 15;
        uint4 p0 = make_uint4(0, 0, 0, 0), p1 = p0;
        if (gr < N && (KK == 32 || h == 0)) {
            const float* xp = x + (size_t)gr * KK + h * 16;
            float4 f0 = *(const float4*)(xp);
            float4 f1 = *(const float4*)(xp + 4);
            float4 f2 = *(const float4*)(xp + 8);
            float4 f3 = *(const float4*)(xp + 12);
            p0 = make_uint4(pk2(f0.x, f0.y), pk2(f0.z, f0.w), pk2(f1.x, f1.y), pk2(f1.z, f1.w));
            p1 = make_uint4(pk2(f2.x, f2.y), pk2(f2.z, f2.w), pk2(f3.x, f3.y), pk2(f3.z, f3.w));
        }
        int kg0 = 2 * h;
        *(uint4*)(&Af[rt][(kg0 * 16 + rr) ^ (kg0 << 2)][0]) = p0;
        *(uint4*)(&Af[rt][((kg0 + 1) * 16 + rr) ^ ((kg0 + 1) << 2)][0]) = p1;
    }
    // stage B: thread = col
    {
        const u16* wp = Wb + (size_t)tid * 32;
#pragma unroll
        for (int q = 0; q < 4; ++q) {
            uint4 wv = *(const uint4*)(wp + q * 8);
            *(uint4*)(&Bf[tid >> 4][q * 16 + (tid & 15)][0]) = wv;
        }
    }
    __syncthreads();
    int arslot = lane ^ ((lane >> 4) << 2);
    f32x4 acc[8][4];
#pragma unroll
    for (int rt = 0; rt < 8; ++rt) {
        bf16x8 afr = *(const bf16x8*)(&Af[rt][arslot][0]);
#pragma unroll
        for (int ct = 0; ct < 4; ++ct) {
            bf16x8 bfr = *(const bf16x8*)(&Bf[w * 4 + ct][lane][0]);
            acc[rt][ct] = __builtin_amdgcn_mfma_f32_16x16x32_bf16(
                afr, bfr, (f32x4){0.f, 0.f, 0.f, 0.f}, 0, 0, 0);
        }
    }
    int rb = (lane >> 4) * 4, cc = lane & 15;
#pragma unroll
    for (int ct = 0; ct < 4; ++ct) {
        int cg = (w * 4 + ct) * 16 + cc;
        float bv = b[cg];
#pragma unroll
        for (int rt = 0; rt < 8; ++rt)
#pragma unroll
            for (int q = 0; q < 4; ++q) {
                int r = row0 + rt * 16 + rb + q;
                if (r < N)
                    out[(size_t)r * H + cg] = f2bf(fmaxf(acc[rt][ct][q] + bv, 0.0f));
            }
    }
}

// ---------------- CSR build (validated) ----------------
__global__ void count_kernel(const int* __restrict__ dst, int E, int* __restrict__ cnt) {
    int e = blockIdx.x * blockDim.x + threadIdx.x;
    if (e < E) atomicAdd(&cnt[dst[e]], 1);
}
__global__ void scan1_kernel(const int* __restrict__ cnt, int N,
                             int* __restrict__ loc, int* __restrict__ bsum) {
    __shared__ int sh[256];
    int b = blockIdx.x, t = threadIdx.x;
    int base = b * 1024 + t * 4;
    int v0 = (base + 0 < N) ? cnt[base + 0] : 0;
    int v1 = (base + 1 < N) ? cnt[base + 1] : 0;
    int v2 = (base + 2 < N) ? cnt[base + 2] : 0;
    int v3 = (base + 3 < N) ? cnt[base + 3] : 0;
    int s = v0 + v1 + v2 + v3;
    sh[t] = s;
    __syncthreads();
    for (int o = 1; o < 256; o <<= 1) {
        int y = (t >= o) ? sh[t - o] : 0;
        __syncthreads();
        sh[t] += y;
        __syncthreads();
    }
    int run = sh[t] - s;
    if (base + 0 < N) loc[base + 0] = run; run += v0;
    if (base + 1 < N) loc[base + 1] = run; run += v1;
    if (base + 2 < N) loc[base + 2] = run; run += v2;
    if (base + 3 < N) loc[base + 3] = run;
    if (t == 0) bsum[b] = sh[255];
}
__global__ void scan2_kernel(int* __restrict__ bsum, int nb) {
    __shared__ int sh[1024];
    int t = threadIdx.x;
    int v = (t < nb) ? bsum[t] : 0;
    sh[t] = v;
    __syncthreads();
    for (int o = 1; o < 1024; o <<= 1) {
        int y = (t >= o) ? sh[t - o] : 0;
        __syncthreads();
        sh[t] += y;
        __syncthreads();
    }
    if (t < nb) bsum[t] = sh[t] - v;
}
__global__ void scan3_kernel(int* __restrict__ ptr, const int* __restrict__ bsum,
                             int N, int total) {
    int i = blockIdx.x * blockDim.x + threadIdx.x;
    if (i < N) ptr[i] += bsum[i >> 10];
    else if (i == N) ptr[N] = total;
}
__global__ void fillcsr_kernel(const int* __restrict__ src, const int* __restrict__ dst, int E,
                               const int* __restrict__ ptr, int* __restrict__ cur,
                               int* __restrict__ perm) {
    int e = blockIdx.x * blockDim.x + threadIdx.x;
    if (e < E) {
        int d = dst[e];
        int pos = ptr[d] + atomicAdd(&cur[d], 1);
        perm[pos] = src[e];
    }
}

// ---------------- gather-mean (kept for sliced fallback) ------------
template <int WS>
__launch_bounds__(256)
__global__ void gmean_kernel(const u16* __restrict__ feat, int fstride,
                             const int* __restrict__ ptr, const int* __restrict__ perm,
                             u16* __restrict__ out, int ostride, int c0,
                             int rows, int lo) {
    constexpr int LPD = WS / 4;
    constexpr int DPB = 256 / LPD;
    int g = threadIdx.x / LPD;
    int ln = threadIdx.x % LPD;
    int w = blockIdx.x * DPB + g;
    if (w >= rows) return;
    int d = lo + w;
    int e0 = ptr[d], e1 = ptr[d + 1];
    float a0 = 0.f, a1 = 0.f, a2 = 0.f, a3 = 0.f;
    for (int e = e0; e < e1; ++e) {
        int s = perm[e];
        uint2 v = *(const uint2*)(feat + (size_t)s * fstride + (ln << 2));
        a0 += bf2f(v.x & 0xffff); a1 += bf2f(v.x >> 16);
        a2 += bf2f(v.y & 0xffff); a3 += bf2f(v.y >> 16);
    }
    int deg = e1 - e0;
    float sc = (deg > 0) ? (1.0f / (float)deg) : 0.0f;
    uint2 pk;
    pk.x = pk2(a0 * sc, a1 * sc);
    pk.y = pk2(a2 * sc, a3 * sc);
    *(uint2*)(out + (size_t)w * ostride + c0 + (ln << 2)) = pk;
}

// ---------------- proj2 (kept for sliced fallback) ----------------
template <int K, int NC>
__launch_bounds__(256)
__global__ void proj2_kernel(const float* __restrict__ x, const float* __restrict__ W,
                             const float* __restrict__ b, u16* __restrict__ out,
                             int N, int c0, int ost) {
    __shared__ float xs[128][K + 4];
    constexpr int NG = 512 / NC;
    constexpr int RPT = 128 / NG;
    int tid = threadIdx.x;
    int row0 = blockIdx.x * 128;
    constexpr int NF4 = 128 * K / 4;
    for (int f = tid; f < NF4; f += 256) {
        int r = f / (K / 4), kq = (f % (K / 4)) * 4;
        int gr = row0 + r;
        float4 v = (gr < N) ? *(const float4*)(x + (size_t)gr * K + kq)
                            : make_float4(0.f, 0.f, 0.f, 0.f);
        *(float4*)&xs[r][kq] = v;
    }
    int lt2 = (tid % (NC / 2)) * 2;
    int g = tid / (NC / 2);
    float wa[K], wb[K];
    const float* wpa = W + (size_t)(c0 + lt2) * K;
#pragma unroll
    for (int k = 0; k < K; k += 4) {
        float4 va = *(const float4*)(wpa + k);
        float4 vb = *(const float4*)(wpa + K + k);
        wa[k] = va.x; wa[k + 1] = va.y; wa[k + 2] = va.z; wa[k + 3] = va.w;
        wb[k] = vb.x; wb[k + 1] = vb.y; wb[k + 2] = vb.z; wb[k + 3] = vb.w;
    }
    float b0 = b[c0 + lt2], b1 = b[c0 + lt2 + 1];
    __syncthreads();
#pragma unroll
    for (int rr = 0; rr < RPT; ++rr) {
        int r = g * RPT + rr;
        int gr = row0 + r;
        float a0 = b0, a1 = b1;
#pragma unroll
        for (int k = 0; k < K; k += 4) {
            float4 xv = *(const float4*)&xs[r][k];
            a0 += xv.x * wa[k] + xv.y * wa[k + 1] + xv.z * wa[k + 2] + xv.w * wa[k + 3];
            a1 += xv.x * wb[k] + xv.y * wb[k + 1] + xv.z * wb[k + 2] + xv.w * wb[k + 3];
        }
        if (gr < N) {
            u32 pk = (u32)f2bf(fmaxf(a0, 0.f)) | ((u32)f2bf(fmaxf(a1, 0.f)) << 16);
            *(u32*)(out + (size_t)gr * ost + lt2) = pk;
        }
    }
}

// ---------------- fused gather-mean + MFMA combine (plan FULL) ----------------
// out = relu((mean_csr(featG) || xd) @ Wcat.T * bnS + bnB); 64 rows x 256 cols/block.
__launch_bounds__(256)
__global__ void combine_gather(const u16* __restrict__ featG, const int* __restrict__ ptr,
                               const int* __restrict__ perm, const u16* __restrict__ xd,
                               const u16* __restrict__ Wcat,
                               const float* __restrict__ bnS, const float* __restrict__ bnB,
                               u16* __restrict__ outF, int rows) {
    __shared__ __align__(16) u16 Af[4][64][8];
    __shared__ __align__(16) u16 Bf[16][64][8];
    int tid = threadIdx.x;
    int w = tid >> 6, lane = tid & 63;
    int row0 = blockIdx.x * 64;
    int arow = tid >> 2, akg = tid & 3;
    int grow = row0 + arow;
    bool arok = grow < rows;
    int e0 = 0, e1 = 0;
    float inv = 0.0f;
    if (arok) {
        e0 = ptr[grow]; e1 = ptr[grow + 1];
        int dg = e1 - e0;
        inv = (dg > 0) ? 1.0f / (float)dg : 0.0f;
    }
    const u16* ax = xd + (size_t)grow * H;
    int awslot = (akg * 16 + (arow & 15)) ^ (akg << 2);
    int arslot = lane ^ ((lane >> 4) << 2);
    const u16* wp0 = Wcat + (size_t)tid * 512;

    f32x4 acc[4][4];
#pragma unroll
    for (int i = 0; i < 4; ++i)
#pragma unroll
        for (int j = 0; j < 4; ++j) acc[i][j] = (f32x4){0.f, 0.f, 0.f, 0.f};

    for (int kb = 0; kb < 512; kb += 32) {
        int kg = kb + akg * 8;
        uint4 av = make_uint4(0, 0, 0, 0);
        if (arok) {
            if (kg < 256) {
                float s0 = 0.f, s1 = 0.f, s2 = 0.f, s3 = 0.f,
                      s4 = 0.f, s5 = 0.f, s6 = 0.f, s7 = 0.f;
                for (int e = e0; e < e1; ++e) {
                    int sn = perm[e];
                    uint4 v = *(const uint4*)(featG + (size_t)sn * H + kg);
                    s0 += bf2f(v.x & 0xffff); s1 += bf2f(v.x >> 16);
                    s2 += bf2f(v.y & 0xffff); s3 += bf2f(v.y >> 16);
                    s4 += bf2f(v.z & 0xffff); s5 += bf2f(v.z >> 16);
                    s6 += bf2f(v.w & 0xffff); s7 += bf2f(v.w >> 16);
                }
                av.x = pk2(s0 * inv, s1 * inv); av.y = pk2(s2 * inv, s3 * inv);
                av.z = pk2(s4 * inv, s5 * inv); av.w = pk2(s6 * inv, s7 * inv);
            } else {
                av = *(const uint4*)(ax + (kg - 256));
            }
        }
        *(uint4*)(&Af[arow >> 4][awslot][0]) = av;
#pragma unroll
        for (int q = 0; q < 4; ++q) {
            uint4 wv = *(const uint4*)(wp0 + kb + q * 8);
            *(uint4*)(&Bf[tid >> 4][q * 16 + (tid & 15)][0]) = wv;
        }
        __syncthreads();
        bf16x8 afr[4];
#pragma unroll
        for (int rt = 0; rt < 4; ++rt)
            afr[rt] = *(const bf16x8*)(&Af[rt][arslot][0]);
#pragma unroll
        for (int ct = 0; ct < 4; ++ct) {
            bf16x8 bfr = *(const bf16x8*)(&Bf[w * 4 + ct][lane][0]);
#pragma unroll
            for (int rt = 0; rt < 4; ++rt)
                acc[rt][ct] = __builtin_amdgcn_mfma_f32_16x16x32_bf16(afr[rt], bfr, acc[rt][ct], 0, 0, 0);
        }
        __syncthreads();
    }
    int rb = (lane >> 4) * 4, cc = lane & 15;
#pragma unroll
    for (int ct = 0; ct < 4; ++ct) {
        int cg = (w * 4 + ct) * 16 + cc;
        float s = bnS[cg], sh = bnB[cg];
#pragma unroll
        for (int rt = 0; rt < 4; ++rt)
#pragma unroll
            for (int q = 0; q < 4; ++q) {
                int r = row0 + rt * 16 + rb + q;
                if (r < rows)
                    outF[(size_t)r * H + cg] = f2bf(fmaxf(acc[rt][ct][q] * s + sh, 0.0f));
            }
    }
}

// ---------------- MFMA SAGE combine (kept for sliced fallback) ----------------
template <int COLS>
__launch_bounds__(256)
__global__ void combine_mfma(const u16* __restrict__ mean_, const u16* __restrict__ xd,
                             const u16* __restrict__ Wcat,
                             const float* __restrict__ bnS, const float* __restrict__ bnB,
                             u16* __restrict__ outF, int ostride, int out_c0,
                             int rows, int c0) {
    constexpr int NCT = COLS / 16;
    constexpr int CTW = NCT / 4;
    constexpr int PPT = (COLS * 4) / 256;
    __shared__ __align__(16) u16 Af[4][64][8];
    __shared__ __align__(16) u16 Bf[NCT][64][8];
    int tid = threadIdx.x;
    int w = tid >> 6, lane = tid & 63;
    int row0 = blockIdx.x * 64;
    int arow = tid >> 2, akg = tid & 3;
    bool arok = (row0 + arow) < rows;
    const u16* am = mean_ + (size_t)(row0 + arow) * H;
    const u16* ax = xd + (size_t)(row0 + arow) * H;
    int awslot = (akg * 16 + (arow & 15)) ^ (akg << 2);
    int arslot = lane ^ ((lane >> 4) << 2);
    int bc = tid % COLS;
    int bkg0 = (tid / COLS) * PPT;
    const u16* wp0 = Wcat + (size_t)(c0 + bc) * 512 + bkg0 * 8;

    f32x4 acc[4][CTW];
#pragma unroll
    for (int i = 0; i < 4; ++i)
#pragma unroll
        for (int j = 0; j < CTW; ++j) acc[i][j] = (f32x4){0.f, 0.f, 0.f, 0.f};

    for (int kb = 0; kb < 512; kb += 32) {
        uint4 av = make_uint4(0, 0, 0, 0);
        if (arok) {
            int kg = kb + akg * 8;
            av = (kg < 256) ? *(const uint4*)(am + kg) : *(const uint4*)(ax + (kg - 256));
        }
        *(uint4*)(&Af[arow >> 4][awslot][0]) = av;
#pragma unroll
        for (int q = 0; q < PPT; ++q) {
            uint4 wv = *(const uint4*)(wp0 + kb + q * 8);
            *(uint4*)(&Bf[bc >> 4][(bkg0 + q) * 16 + (bc & 15)][0]) = wv;
        }
        __syncthreads();
        bf16x8 afr[4];
#pragma unroll
        for (int rt = 0; rt < 4; ++rt)
            afr[rt] = *(const bf16x8*)(&Af[rt][arslot][0]);
#pragma unroll
        for (int ctl = 0; ctl < CTW; ++ctl) {
            bf16x8 b = *(const bf16x8*)(&Bf[w * CTW + ctl][lane][0]);
#pragma unroll
            for (int rt = 0; rt < 4; ++rt)
                acc[rt][ctl] = __builtin_amdgcn_mfma_f32_16x16x32_bf16(afr[rt], b, acc[rt][ctl], 0, 0, 0);
        }
        __syncthreads();
    }
    int rb = (lane >> 4) * 4;
    int ccol = lane & 15;
#pragma unroll
    for (int ctl = 0; ctl < CTW; ++ctl) {
        int clocal = (w * CTW + ctl) * 16 + ccol;
        int cg = c0 + clocal;
        float s = bnS[cg], sh = bnB[cg];
#pragma unroll
        for (int rt = 0; rt < 4; ++rt) {
#pragma unroll
            for (int q = 0; q < 4; ++q) {
                int r = row0 + rt * 16 + rb + q;
                if (r < rows)
                    outF[(size_t)r * ostride + out_c0 + clocal] = f2bf(fmaxf(acc[rt][ctl][q] * s + sh, 0.0f));
            }
        }
    }
}

// ---------------- MFMA edge-MLP head (validated) --------------
__launch_bounds__(256)
__global__ void mlp_mfma(const u16* __restrict__ accF, const int* __restrict__ sidx,
                         const int* __restrict__ ridx, const float* __restrict__ txr,
                         const u16* __restrict__ W1c, const float* __restrict__ b1,
                         const float* __restrict__ W2, const float* __restrict__ b2,
                         float* __restrict__ out, int M) {
    __shared__ __align__(16) u16 Af[4][64][8];
    __shared__ __align__(16) u16 Bf[16][64][8];
    __shared__ float red[4][64];
    int tid = threadIdx.x;
    int w = tid >> 6, lane = tid & 63;
    int row0 = blockIdx.x * 64;
    int arow = tid >> 2, akg = tid & 3;
    int grow = row0 + arow;
    bool arok = grow < M;
    int si = arok ? sidx[grow] : 0;
    int ri = arok ? ridx[grow] : 0;
    int awslot = (akg * 16 + (arow & 15)) ^ (akg << 2);
    int arslot = lane ^ ((lane >> 4) << 2);
    const u16* wp0 = W1c + (size_t)tid * 544;

    f32x4 acc[4][4];
#pragma unroll
    for (int i = 0; i < 4; ++i)
#pragma unroll
        for (int j = 0; j < 4; ++j) acc[i][j] = (f32x4){0.f, 0.f, 0.f, 0.f};

    for (int kb = 0; kb < 544; kb += 32) {
        uint4 av = make_uint4(0, 0, 0, 0);
        if (arok) {
            int kg = kb + akg * 8;
            if (kg < 256) av = *(const uint4*)(accF + (size_t)si * H + kg);
            else if (kg < 512) av = *(const uint4*)(accF + (size_t)ri * H + (kg - 256));
            else {
                float4 f0 = *(const float4*)(txr + (size_t)grow * 32 + (kg - 512));
                float4 f1 = *(const float4*)(txr + (size_t)grow * 32 + (kg - 512) + 4);
                av.x = pk2(f0.x, f0.y); av.y = pk2(f0.z, f0.w);
                av.z = pk2(f1.x, f1.y); av.w = pk2(f1.z, f1.w);
            }
        }
        *(uint4*)(&Af[arow >> 4][awslot][0]) = av;
#pragma unroll
        for (int q = 0; q < 4; ++q) {
            uint4 wv = *(const uint4*)(wp0 + kb + q * 8);
            *(uint4*)(&Bf[tid >> 4][q * 16 + (tid & 15)][0]) = wv;
        }
        __syncthreads();
        bf16x8 afr[4];
#pragma unroll
        for (int rt = 0; rt < 4; ++rt)
            afr[rt] = *(const bf16x8*)(&Af[rt][arslot][0]);
#pragma unroll
        for (int ctl = 0; ctl < 4; ++ctl) {
            bf16x8 b = *(const bf16x8*)(&Bf[w * 4 + ctl][lane][0]);
#pragma unroll
            for (int rt = 0; rt < 4; ++rt)
                acc[rt][ctl] = __builtin_amdgcn_mfma_f32_16x16x32_bf16(afr[rt], b, acc[rt][ctl], 0, 0, 0);
        }
        __syncthreads();
    }
    float part[4][4];
#pragma unroll
    for (int rt = 0; rt < 4; ++rt)
#pragma unroll
        for (int q = 0; q < 4; ++q) part[rt][q] = 0.0f;
#pragma unroll
    for (int ctl = 0; ctl < 4; ++ctl) {
        int cg = (w * 4 + ctl) * 16 + (lane & 15);
        float b1v = b1[cg], w2v = W2[cg];
#pragma unroll
        for (int rt = 0; rt < 4; ++rt)
#pragma unroll
            for (int q = 0; q < 4; ++q)
                part[rt][q] += fmaxf(acc[rt][ctl][q] + b1v, 0.0f) * w2v;
    }
    int rb = (lane >> 4) * 4;
#pragma unroll
    for (int rt = 0; rt < 4; ++rt)
#pragma unroll
        for (int q = 0; q < 4; ++q) {
            float p = part[rt][q];
            p += __shfl_xor(p, 1);
            p += __shfl_xor(p, 2);
            p += __shfl_xor(p, 4);
            p += __shfl_xor(p, 8);
            if ((lane & 15) == 0) red[w][rt * 16 + rb + q] = p;
        }
    __syncthreads();
    if (tid < 64) {
        int r = row0 + tid;
        if (r < M)
            out[r] = red[0][tid] + red[1][tid] + red[2][tid] + red[3][tid] + b2[0];
    }
}

// ---------------- host ----------------
static inline void fz(void* p, size_t bytes, hipStream_t s) {
    long long n = (long long)(bytes >> 2);
    int g = (int)(((n + 255) / 256 < 2048) ? (n + 255) / 256 : 2048);
    fillz_kernel<<<g, 256, 0, s>>>((u32*)p, n);
}
static inline size_t al256(size_t x) { return (x + 255) & ~(size_t)255; }

extern "C" void kernel_launch(void* const* d_in, const int* in_sizes, int n_in,
                              void* d_out, int out_size, void* d_ws, size_t ws_size,
                              hipStream_t stream) {
    const float* x_acc  = (const float*)d_in[0];
    const float* x_tx   = (const float*)d_in[1];
    const float* tx_raw = (const float*)d_in[2];
    const int* ei_sends = (const int*)d_in[3];
    const int* ei_recv  = (const int*)d_in[4];
    const int* sidx     = (const int*)d_in[5];
    const int* ridx     = (const int*)d_in[6];
    const float* W_acc  = (const float*)d_in[7];
    const float* b_acc  = (const float*)d_in[8];
    const float* W_tx   = (const float*)d_in[9];
    const float* b_tx   = (const float*)d_in[10];
    const float* Wl_at  = (const float*)d_in[11];
    const float* bl_at  = (const float*)d_in[12];
    const float* Wr_at  = (const float*)d_in[13];
    const float* Wl_ta  = (const float*)d_in[14];
    const float* bl_ta  = (const float*)d_in[15];
    const float* Wr_ta  = (const float*)d_in[16];
    const float* bng    = (const float*)d_in[17];
    const float* bnb    = (const float*)d_in[18];
    const float* bnm    = (const float*)d_in[19];
    const float* bnv    = (const float*)d_in[20];
    const float* W1     = (const float*)d_in[21];
    const float* b1     = (const float*)d_in[22];
    const float* W2     = (const float*)d_in[23];
    const float* b2     = (const float*)d_in[24];
    float* out = (float*)d_out;

    const size_t szFeatA = (size_t)NACC * H * 2;
    const size_t szFeatT = (size_t)NTX * H * 2;
    const size_t szCSR = al256((NTX + 1) * 4) + al256(4096) + al256((NTX + 1) * 4)
                       + al256((size_t)NE * 4) + al256((NACC + 1) * 4) + al256((size_t)NE * 4);
    const size_t szW = 3 * al256(256 * 512 * 2) + al256(256 * 544 * 2)
                     + 2 * al256(3 * 256 * 4) + 2 * al256(256 * 32 * 2);

    size_t needF = szCSR + szW + 2 * al256(szFeatA) + al256(szFeatT) + 65536;
    auto needS = [&](int S, int CC) {
        return 3 * al256(szFeatA) + szCSR + szW + 2 * al256((size_t)CC * H * 2)
             + al256((size_t)NTX * (H / S) * 2) + 65536;
    };
    int plan, S = 2, CC = 16384;
    if (needF <= ws_size)                { plan = 0; }
    else if (needS(2, 16384) <= ws_size) { plan = 1; S = 2; CC = 16384; }
    else if (needS(4, 16384) <= ws_size) { plan = 1; S = 4; CC = 16384; }
    else                                 { plan = 1; S = 4; CC = 2048; }

    char* wsp = (char*)d_ws;
    size_t off = 0;
    auto alloc = [&](size_t bytes) -> void* {
        void* p = wsp + off;
        off = al256(off + bytes);
        return p;
    };
    int* cnt   = (int*)alloc((NTX + 1) * 4);
    int* bsum  = (int*)alloc(4096);
    int* ptrT  = (int*)alloc((NTX + 1) * 4);
    int* permS = (int*)alloc((size_t)NE * 4);
    int* ptrA  = (int*)alloc((NACC + 1) * 4);
    int* permR = (int*)alloc((size_t)NE * 4);
    u16* Wc[3];
    Wc[0] = (u16*)alloc(256 * 512 * 2);
    Wc[1] = (u16*)alloc(256 * 512 * 2);
    Wc[2] = (u16*)alloc(256 * 512 * 2);
    u16* W1c = (u16*)alloc(256 * 544 * 2);
    float* bnS = (float*)alloc(3 * 256 * 4);
    float* bnB = (float*)alloc(3 * 256 * 4);
    u16* WbA = (u16*)alloc(256 * 32 * 2);
    u16* WbT = (u16*)alloc(256 * 32 * 2);
    u16* A0f = (u16*)alloc(szFeatA);
    u16* A1f = (u16*)alloc(szFeatA);

    // ---- weight prep ----
    wcat_kernel<<<256, 256, 0, stream>>>(Wl_ta, Wr_ta, Wc[0]);
    wcat_kernel<<<256, 256, 0, stream>>>(Wl_at, Wr_at, Wc[1]);
    wcat_kernel<<<256, 256, 0, stream>>>(Wl_ta + H * H, Wr_ta + H * H, Wc[2]);
    w1cvt_kernel<<<256, 256, 0, stream>>>(W1, W1c);
    wproj_kernel<<<256, 32, 0, stream>>>(W_acc, WbA, 16);
    wproj_kernel<<<256, 32, 0, stream>>>(W_tx, WbT, 32);
    bnprep_kernel<<<1, 256, 0, stream>>>(bl_ta, bng, bnb, bnm, bnv, bnS, bnB);
    bnprep_kernel<<<1, 256, 0, stream>>>(bl_at, bng, bnb, bnm, bnv, bnS + 256, bnB + 256);
    bnprep_kernel<<<1, 256, 0, stream>>>(bl_ta + H, bng + H, bnb + H, bnm + H, bnv + H,
                                         bnS + 512, bnB + 512);

    // ---- CSR sends (dst = tx) ----
    const int EG = (NE + 255) / 256;
    const int nbT = (NTX + 1023) / 1024, nbA = (NACC + 1023) / 1024;
    fz(cnt, (size_t)NTX * 4, stream);
    count_kernel<<<EG, 256, 0, stream>>>(ei_sends + NE, NE, cnt);
    scan1_kernel<<<nbT, 256, 0, stream>>>(cnt, NTX, ptrT, bsum);
    scan2_kernel<<<1, 1024, 0, stream>>>(bsum, nbT);
    scan3_kernel<<<(NTX + 256) / 256 + 1, 256, 0, stream>>>(ptrT, bsum, NTX, NE);
    fz(cnt, (size_t)NTX * 4, stream);
    fillcsr_kernel<<<EG, 256, 0, stream>>>(ei_sends, ei_sends + NE, NE, ptrT, cnt, permS);
    // ---- CSR recv (dst = acc) ----
    fz(cnt, (size_t)NACC * 4, stream);
    count_kernel<<<EG, 256, 0, stream>>>(ei_recv + NE, NE, cnt);
    scan1_kernel<<<nbA, 256, 0, stream>>>(cnt, NACC, ptrA, bsum);
    scan2_kernel<<<1, 1024, 0, stream>>>(bsum, nbA);
    scan3_kernel<<<(NACC + 256) / 256 + 1, 256, 0, stream>>>(ptrA, bsum, NACC, NE);
    fz(cnt, (size_t)NACC * 4, stream);
    fillcsr_kernel<<<EG, 256, 0, stream>>>(ei_recv, ei_recv + NE, NE, ptrA, cnt, permR);

    // ---- acc projection (MFMA) ----
    proj_mfma<16><<<(NACC + 127) / 128, 256, 0, stream>>>(x_acc, WbA, b_acc, A0f, NACC);

    const int gA = (NACC + 63) / 64, gM = (NM + 63) / 64;

    if (plan == 0) {
        // ======== PLAN FULL (fused gather-combine; no mean buffers; no chunk loop) ========
        u16* T = (u16*)alloc(szFeatT);
        // T0 full-width
        proj_mfma<32><<<(NTX + 127) / 128, 256, 0, stream>>>(x_tx, WbT, b_tx, T, NTX);
        // L0 acc: gather T0 over recv, root A0f -> A1f   (must precede in-place T overwrite)
        combine_gather<<<gA, 256, 0, stream>>>(T, ptrA, permR, A0f, Wc[0], bnS, bnB, A1f, NACC);
        // L0 tx: gather A0f over sends, root T0 -> T1 in place (single launch)
        combine_gather<<<(NTX + 63) / 64, 256, 0, stream>>>(A0f, ptrT, permS, T, Wc[1],
                                                            bnS + 256, bnB + 256, T, NTX);
        // L1 acc: gather T1 over recv, root A1f -> A2 (reuse A0f)
        combine_gather<<<gA, 256, 0, stream>>>(T, ptrA, permR, A1f, Wc[2],
                                               bnS + 512, bnB + 512, A0f, NACC);
        mlp_mfma<<<gM, 256, 0, stream>>>(A0f, sidx, ridx, tx_raw, W1c, b1, W2, b2, out, NM);
    } else {
        // ======== PLAN SLICED (round-6 structure, validated) ========
        u16* meanbuf = (u16*)alloc(szFeatA);
        u16* T0c     = (u16*)alloc((size_t)CC * H * 2);
        u16* meanTc  = (u16*)alloc((size_t)CC * H * 2);
        const int WSL = H / S;
        u16* Tslice  = (u16*)alloc((size_t)NTX * WSL * 2);

        for (int s = 0; s < S; ++s) {
            int c0 = s * WSL;
            if (WSL == 128)
                proj2_kernel<32, 128><<<(NTX + 127) / 128, 256, 0, stream>>>(x_tx, W_tx, b_tx, Tslice, NTX, c0, WSL);
            else
                proj2_kernel<32, 64><<<(NTX + 127) / 128, 256, 0, stream>>>(x_tx, W_tx, b_tx, Tslice, NTX, c0, WSL);
            if (WSL == 128)
                gmean_kernel<128><<<(NACC + 7) / 8, 256, 0, stream>>>(Tslice, WSL, ptrA, permR, meanbuf, H, c0, NACC, 0);
            else
                gmean_kernel<64><<<(NACC + 15) / 16, 256, 0, stream>>>(Tslice, WSL, ptrA, permR, meanbuf, H, c0, NACC, 0);
        }
        combine_mfma<256><<<gA, 256, 0, stream>>>(meanbuf, A0f, Wc[0], bnS, bnB, A1f, H, 0, NACC, 0);
        for (int s = 0; s < S; ++s) {
            int c0 = s * WSL;
            for (int lo = 0; lo < NTX; lo += CC) {
                int cur = (NTX - lo < CC) ? (NTX - lo) : CC;
                proj2_kernel<32, 256><<<(cur + 127) / 128, 256, 0, stream>>>(x_tx + (size_t)lo * 32, W_tx, b_tx, T0c, cur, 0, H);
                gmean_kernel<256><<<(cur + 3) / 4, 256, 0, stream>>>(A0f, H, ptrT, permS, meanTc, H, 0, cur, lo);
                if (WSL == 128)
                    combine_mfma<128><<<(cur + 63) / 64, 256, 0, stream>>>(
                        meanTc, T0c, Wc[1], bnS + 256, bnB + 256,
                        Tslice + (size_t)lo * WSL, WSL, 0, cur, c0);
                else
                    combine_mfma<64><<<(cur + 63) / 64, 256, 0, stream>>>(
                        meanTc, T0c, Wc[1], bnS + 256, bnB + 256,
                        Tslice + (size_t)lo * WSL, WSL, 0, cur, c0);
            }
            if (WSL == 128)
                gmean_kernel<128><<<(NACC + 7) / 8, 256, 0, stream>>>(Tslice, WSL, ptrA, permR, meanbuf, H, c0, NACC, 0);
            else
                gmean_kernel<64><<<(NACC + 15) / 16, 256, 0, stream>>>(Tslice, WSL, ptrA, permR, meanbuf, H, c0, NACC, 0);
        }
        combine_mfma<256><<<gA, 256, 0, stream>>>(meanbuf, A1f, Wc[2], bnS + 512, bnB + 512, A0f, H, 0, NACC, 0);
        mlp_mfma<<<gM, 256, 0, stream>>>(A0f, sidx, ridx, tx_raw, W1c, b1, W2, b2, out, NM);
    }
}

// Round 8
// 1146.821 us; speedup vs baseline: 12.4321x; 1.1944x over previous
//
#include <hip/hip_runtime.h>
#include <hip/hip_bf16.h>

#define H 256
#define NACC 100000
#define NTX  300000
#define NE   600000
#define NM   300000

typedef unsigned short u16;
typedef unsigned int u32;
typedef __bf16 bf16x8 __attribute__((ext_vector_type(8)));
typedef float f32x4 __attribute__((ext_vector_type(4)));

__device__ __forceinline__ float bf2f(u32 u) {
    union { u32 i; float f; } v; v.i = u << 16; return v.f;
}
__device__ __forceinline__ u16 f2bf(float f) {
    union { float f; u32 i; } v; v.f = f;
    u32 r = v.i + 0x7FFFu + ((v.i >> 16) & 1u);
    return (u16)(r >> 16);
}
__device__ __forceinline__ u32 pk2(float a, float b) {
    return (u32)f2bf(a) | ((u32)f2bf(b) << 16);
}

// ---------------- zero fill (no hipMemsetAsync: breaks graph capture) ----------------
__global__ void fillz_kernel(u32* __restrict__ p, long long n) {
    long long i = (long long)blockIdx.x * blockDim.x + threadIdx.x;
    long long st = (long long)gridDim.x * blockDim.x;
    for (; i < n; i += st) p[i] = 0u;
}

// ---------------- weight prep ----------------
__global__ void wcat_kernel(const float* __restrict__ Wl, const float* __restrict__ Wr,
                            u16* __restrict__ dst) {
    int c = blockIdx.x, t = threadIdx.x;
    dst[(size_t)c * 512 + t]       = f2bf(Wl[(size_t)c * 256 + t]);
    dst[(size_t)c * 512 + 256 + t] = f2bf(Wr[(size_t)c * 256 + t]);
}
__global__ void w1cvt_kernel(const float* __restrict__ W1, u16* __restrict__ dst) {
    int c = blockIdx.x, t = threadIdx.x;
    for (int k = t; k < 544; k += 256)
        dst[(size_t)c * 544 + k] = f2bf(W1[(size_t)c * 544 + k]);
}
// project-weight to bf16 [256][32], zero-padded past K
__global__ void wproj_kernel(const float* __restrict__ W, u16* __restrict__ dst, int K) {
    int c = blockIdx.x, t = threadIdx.x;   // 32 threads
    dst[(size_t)c * 32 + t] = (t < K) ? f2bf(W[(size_t)c * K + t]) : (u16)0;
}
__global__ void bnprep_kernel(const float* __restrict__ bl, const float* __restrict__ g,
                              const float* __restrict__ be, const float* __restrict__ m,
                              const float* __restrict__ v,
                              float* __restrict__ S, float* __restrict__ B) {
    int c = threadIdx.x;
    float s = g[c] * rsqrtf(v[c] + 1e-5f);
    S[c] = s;
    B[c] = (bl[c] - m[c]) * s + be[c];
}

// ---------------- MFMA projection (validated round 7) ------
template <int KK>
__launch_bounds__(256)
__global__ void proj_mfma(const float* __restrict__ x, const u16* __restrict__ Wb,
                          const float* __restrict__ b, u16* __restrict__ out, int N) {
    __shared__ __align__(16) u16 Af[8][64][8];
    __shared__ __align__(16) u16 Bf[16][64][8];
    int tid = threadIdx.x;
    int w = tid >> 6, lane = tid & 63;
    int row0 = blockIdx.x * 128;
    {
        int r = tid >> 1, h = tid & 1;
        int gr = row0 + r;
        int rt = r >> 4, rr = r & 15;
        uint4 p0 = make_uint4(0, 0, 0, 0), p1 = p0;
        if (gr < N && (KK == 32 || h == 0)) {
            const float* xp = x + (size_t)gr * KK + h * 16;
            float4 f0 = *(const float4*)(xp);
            float4 f1 = *(const float4*)(xp + 4);
            float4 f2 = *(const float4*)(xp + 8);
            float4 f3 = *(const float4*)(xp + 12);
            p0 = make_uint4(pk2(f0.x, f0.y), pk2(f0.z, f0.w), pk2(f1.x, f1.y), pk2(f1.z, f1.w));
            p1 = make_uint4(pk2(f2.x, f2.y), pk2(f2.z, f2.w), pk2(f3.x, f3.y), pk2(f3.z, f3.w));
        }
        int kg0 = 2 * h;
        *(uint4*)(&Af[rt][(kg0 * 16 + rr) ^ (kg0 << 2)][0]) = p0;
        *(uint4*)(&Af[rt][((kg0 + 1) * 16 + rr) ^ ((kg0 + 1) << 2)][0]) = p1;
    }
    {
        const u16* wp = Wb + (size_t)tid * 32;
#pragma unroll
        for (int q = 0; q < 4; ++q) {
            uint4 wv = *(const uint4*)(wp + q * 8);
            *(uint4*)(&Bf[tid >> 4][q * 16 + (tid & 15)][0]) = wv;
        }
    }
    __syncthreads();
    int arslot = lane ^ ((lane >> 4) << 2);
    f32x4 acc[8][4];
#pragma unroll
    for (int rt = 0; rt < 8; ++rt) {
        bf16x8 afr = *(const bf16x8*)(&Af[rt][arslot][0]);
#pragma unroll
        for (int ct = 0; ct < 4; ++ct) {
            bf16x8 bfr = *(const bf16x8*)(&Bf[w * 4 + ct][lane][0]);
            acc[rt][ct] = __builtin_amdgcn_mfma_f32_16x16x32_bf16(
                afr, bfr, (f32x4){0.f, 0.f, 0.f, 0.f}, 0, 0, 0);
        }
    }
    int rb = (lane >> 4) * 4, cc = lane & 15;
#pragma unroll
    for (int ct = 0; ct < 4; ++ct) {
        int cg = (w * 4 + ct) * 16 + cc;
        float bv = b[cg];
#pragma unroll
        for (int rt = 0; rt < 8; ++rt)
#pragma unroll
            for (int q = 0; q < 4; ++q) {
                int r = row0 + rt * 16 + rb + q;
                if (r < N)
                    out[(size_t)r * H + cg] = f2bf(fmaxf(acc[rt][ct][q] + bv, 0.0f));
            }
    }
}

// ---------------- CSR build (validated) ----------------
__global__ void count_kernel(const int* __restrict__ dst, int E, int* __restrict__ cnt) {
    int e = blockIdx.x * blockDim.x + threadIdx.x;
    if (e < E) atomicAdd(&cnt[dst[e]], 1);
}
__global__ void scan1_kernel(const int* __restrict__ cnt, int N,
                             int* __restrict__ loc, int* __restrict__ bsum) {
    __shared__ int sh[256];
    int b = blockIdx.x, t = threadIdx.x;
    int base = b * 1024 + t * 4;
    int v0 = (base + 0 < N) ? cnt[base + 0] : 0;
    int v1 = (base + 1 < N) ? cnt[base + 1] : 0;
    int v2 = (base + 2 < N) ? cnt[base + 2] : 0;
    int v3 = (base + 3 < N) ? cnt[base + 3] : 0;
    int s = v0 + v1 + v2 + v3;
    sh[t] = s;
    __syncthreads();
    for (int o = 1; o < 256; o <<= 1) {
        int y = (t >= o) ? sh[t - o] : 0;
        __syncthreads();
        sh[t] += y;
        __syncthreads();
    }
    int run = sh[t] - s;
    if (base + 0 < N) loc[base + 0] = run; run += v0;
    if (base + 1 < N) loc[base + 1] = run; run += v1;
    if (base + 2 < N) loc[base + 2] = run; run += v2;
    if (base + 3 < N) loc[base + 3] = run;
    if (t == 0) bsum[b] = sh[255];
}
__global__ void scan2_kernel(int* __restrict__ bsum, int nb) {
    __shared__ int sh[1024];
    int t = threadIdx.x;
    int v = (t < nb) ? bsum[t] : 0;
    sh[t] = v;
    __syncthreads();
    for (int o = 1; o < 1024; o <<= 1) {
        int y = (t >= o) ? sh[t - o] : 0;
        __syncthreads();
        sh[t] += y;
        __syncthreads();
    }
    if (t < nb) bsum[t] = sh[t] - v;
}
__global__ void scan3_kernel(int* __restrict__ ptr, const int* __restrict__ bsum,
                             int N, int total) {
    int i = blockIdx.x * blockDim.x + threadIdx.x;
    if (i < N) ptr[i] += bsum[i >> 10];
    else if (i == N) ptr[N] = total;
}
__global__ void fillcsr_kernel(const int* __restrict__ src, const int* __restrict__ dst, int E,
                               const int* __restrict__ ptr, int* __restrict__ cur,
                               int* __restrict__ perm) {
    int e = blockIdx.x * blockDim.x + threadIdx.x;
    if (e < E) {
        int d = dst[e];
        int pos = ptr[d] + atomicAdd(&cur[d], 1);
        perm[pos] = src[e];
    }
}

// ---------------- gather-mean (kept for sliced fallback) ------------
template <int WS>
__launch_bounds__(256)
__global__ void gmean_kernel(const u16* __restrict__ feat, int fstride,
                             const int* __restrict__ ptr, const int* __restrict__ perm,
                             u16* __restrict__ out, int ostride, int c0,
                             int rows, int lo) {
    constexpr int LPD = WS / 4;
    constexpr int DPB = 256 / LPD;
    int g = threadIdx.x / LPD;
    int ln = threadIdx.x % LPD;
    int w = blockIdx.x * DPB + g;
    if (w >= rows) return;
    int d = lo + w;
    int e0 = ptr[d], e1 = ptr[d + 1];
    float a0 = 0.f, a1 = 0.f, a2 = 0.f, a3 = 0.f;
    for (int e = e0; e < e1; ++e) {
        int s = perm[e];
        uint2 v = *(const uint2*)(feat + (size_t)s * fstride + (ln << 2));
        a0 += bf2f(v.x & 0xffff); a1 += bf2f(v.x >> 16);
        a2 += bf2f(v.y & 0xffff); a3 += bf2f(v.y >> 16);
    }
    int deg = e1 - e0;
    float sc = (deg > 0) ? (1.0f / (float)deg) : 0.0f;
    uint2 pk;
    pk.x = pk2(a0 * sc, a1 * sc);
    pk.y = pk2(a2 * sc, a3 * sc);
    *(uint2*)(out + (size_t)w * ostride + c0 + (ln << 2)) = pk;
}

// ---------------- proj2 (kept for sliced fallback) ----------------
template <int K, int NC>
__launch_bounds__(256)
__global__ void proj2_kernel(const float* __restrict__ x, const float* __restrict__ W,
                             const float* __restrict__ b, u16* __restrict__ out,
                             int N, int c0, int ost) {
    __shared__ float xs[128][K + 4];
    constexpr int NG = 512 / NC;
    constexpr int RPT = 128 / NG;
    int tid = threadIdx.x;
    int row0 = blockIdx.x * 128;
    constexpr int NF4 = 128 * K / 4;
    for (int f = tid; f < NF4; f += 256) {
        int r = f / (K / 4), kq = (f % (K / 4)) * 4;
        int gr = row0 + r;
        float4 v = (gr < N) ? *(const float4*)(x + (size_t)gr * K + kq)
                            : make_float4(0.f, 0.f, 0.f, 0.f);
        *(float4*)&xs[r][kq] = v;
    }
    int lt2 = (tid % (NC / 2)) * 2;
    int g = tid / (NC / 2);
    float wa[K], wb[K];
    const float* wpa = W + (size_t)(c0 + lt2) * K;
#pragma unroll
    for (int k = 0; k < K; k += 4) {
        float4 va = *(const float4*)(wpa + k);
        float4 vb = *(const float4*)(wpa + K + k);
        wa[k] = va.x; wa[k + 1] = va.y; wa[k + 2] = va.z; wa[k + 3] = va.w;
        wb[k] = vb.x; wb[k + 1] = vb.y; wb[k + 2] = vb.z; wb[k + 3] = vb.w;
    }
    float b0 = b[c0 + lt2], b1 = b[c0 + lt2 + 1];
    __syncthreads();
#pragma unroll
    for (int rr = 0; rr < RPT; ++rr) {
        int r = g * RPT + rr;
        int gr = row0 + r;
        float a0 = b0, a1 = b1;
#pragma unroll
        for (int k = 0; k < K; k += 4) {
            float4 xv = *(const float4*)&xs[r][k];
            a0 += xv.x * wa[k] + xv.y * wa[k + 1] + xv.z * wa[k + 2] + xv.w * wa[k + 3];
            a1 += xv.x * wb[k] + xv.y * wb[k + 1] + xv.z * wb[k + 2] + xv.w * wb[k + 3];
        }
        if (gr < N) {
            u32 pk = (u32)f2bf(fmaxf(a0, 0.f)) | ((u32)f2bf(fmaxf(a1, 0.f)) << 16);
            *(u32*)(out + (size_t)gr * ost + lt2) = pk;
        }
    }
}

// ---------------- fused gather-mean + MFMA combine, v2: block pre-gather into LDS ----------------
// Phase 1: thread (row, colgroup) gathers 64 cols of the CSR mean, edge loop unrolled x2,
// packs bf16 into Am in MFMA fragment order (validated XOR swizzle).
// Phase 2: K-loop; kb<256 reads A straight from Am, kb>=256 stages xd as before.
__launch_bounds__(256)
__global__ void combine_gather(const u16* __restrict__ featG, const int* __restrict__ ptr,
                               const int* __restrict__ perm, const u16* __restrict__ xd,
                               const u16* __restrict__ Wcat,
                               const float* __restrict__ bnS, const float* __restrict__ bnB,
                               u16* __restrict__ outF, int rows) {
    __shared__ __align__(16) u16 Am[8][4][64][8];   // 32 KB: mean half, fragment-ordered
    __shared__ __align__(16) u16 Af[4][64][8];      // 4 KB: xd half per-K-step staging
    __shared__ __align__(16) u16 Bf[16][64][8];     // 16 KB
    int tid = threadIdx.x;
    int w = tid >> 6, lane = tid & 63;
    int row0 = blockIdx.x * 64;

    // ---- phase 1: block-level gather-mean into Am ----
    {
        int r = tid >> 2, g = tid & 3;
        int grow = row0 + r;
        float s[64];
#pragma unroll
        for (int i = 0; i < 64; ++i) s[i] = 0.0f;
        float inv = 0.0f;
        if (grow < rows) {
            int e0 = ptr[grow], e1 = ptr[grow + 1];
            int dg = e1 - e0;
            inv = (dg > 0) ? 1.0f / (float)dg : 0.0f;
            int e = e0;
            for (; e + 1 < e1; e += 2) {
                int n0 = perm[e], n1 = perm[e + 1];
                const u16* p0 = featG + (size_t)n0 * H + g * 64;
                const u16* p1 = featG + (size_t)n1 * H + g * 64;
#pragma unroll
                for (int q = 0; q < 8; ++q) {
                    uint4 v0 = *(const uint4*)(p0 + q * 8);
                    uint4 v1 = *(const uint4*)(p1 + q * 8);
                    s[q * 8 + 0] += bf2f(v0.x & 0xffff) + bf2f(v1.x & 0xffff);
                    s[q * 8 + 1] += bf2f(v0.x >> 16)    + bf2f(v1.x >> 16);
                    s[q * 8 + 2] += bf2f(v0.y & 0xffff) + bf2f(v1.y & 0xffff);
                    s[q * 8 + 3] += bf2f(v0.y >> 16)    + bf2f(v1.y >> 16);
                    s[q * 8 + 4] += bf2f(v0.z & 0xffff) + bf2f(v1.z & 0xffff);
                    s[q * 8 + 5] += bf2f(v0.z >> 16)    + bf2f(v1.z >> 16);
                    s[q * 8 + 6] += bf2f(v0.w & 0xffff) + bf2f(v1.w & 0xffff);
                    s[q * 8 + 7] += bf2f(v0.w >> 16)    + bf2f(v1.w >> 16);
                }
            }
            if (e < e1) {
                int n0 = perm[e];
                const u16* p0 = featG + (size_t)n0 * H + g * 64;
#pragma unroll
                for (int q = 0; q < 8; ++q) {
                    uint4 v0 = *(const uint4*)(p0 + q * 8);
                    s[q * 8 + 0] += bf2f(v0.x & 0xffff);
                    s[q * 8 + 1] += bf2f(v0.x >> 16);
                    s[q * 8 + 2] += bf2f(v0.y & 0xffff);
                    s[q * 8 + 3] += bf2f(v0.y >> 16);
                    s[q * 8 + 4] += bf2f(v0.z & 0xffff);
                    s[q * 8 + 5] += bf2f(v0.z >> 16);
                    s[q * 8 + 6] += bf2f(v0.w & 0xffff);
                    s[q * 8 + 7] += bf2f(v0.w >> 16);
                }
            }
        }
        int rt = r >> 4, rr = r & 15;
#pragma unroll
        for (int q = 0; q < 8; ++q) {
            int kgg = g * 8 + q;                 // global kgroup 0..31
            int kbs = kgg >> 2, akg = kgg & 3;   // kb-step, in-step group
            uint4 pv;
            pv.x = pk2(s[q * 8 + 0] * inv, s[q * 8 + 1] * inv);
            pv.y = pk2(s[q * 8 + 2] * inv, s[q * 8 + 3] * inv);
            pv.z = pk2(s[q * 8 + 4] * inv, s[q * 8 + 5] * inv);
            pv.w = pk2(s[q * 8 + 6] * inv, s[q * 8 + 7] * inv);
            *(uint4*)(&Am[kbs][rt][(akg * 16 + rr) ^ (akg << 2)][0]) = pv;
        }
    }

    // ---- phase 2: K-loop ----
    int arow = tid >> 2, akg = tid & 3;
    int grow = row0 + arow;
    bool arok = grow < rows;
    const u16* ax = xd + (size_t)grow * H;
    int awslot = (akg * 16 + (arow & 15)) ^ (akg << 2);
    int arslot = lane ^ ((lane >> 4) << 2);
    const u16* wp0 = Wcat + (size_t)tid * 512;

    f32x4 acc[4][4];
#pragma unroll
    for (int i = 0; i < 4; ++i)
#pragma unroll
        for (int j = 0; j < 4; ++j) acc[i][j] = (f32x4){0.f, 0.f, 0.f, 0.f};

    for (int kb = 0; kb < 512; kb += 32) {
        if (kb >= 256) {
            uint4 av = make_uint4(0, 0, 0, 0);
            if (arok) av = *(const uint4*)(ax + (kb + akg * 8 - 256));
            *(uint4*)(&Af[arow >> 4][awslot][0]) = av;
        }
#pragma unroll
        for (int q = 0; q < 4; ++q) {
            uint4 wv = *(const uint4*)(wp0 + kb + q * 8);
            *(uint4*)(&Bf[tid >> 4][q * 16 + (tid & 15)][0]) = wv;
        }
        __syncthreads();
        bf16x8 afr[4];
        if (kb < 256) {
            int kbs = kb >> 5;
#pragma unroll
            for (int rt = 0; rt < 4; ++rt)
                afr[rt] = *(const bf16x8*)(&Am[kbs][rt][arslot][0]);
        } else {
#pragma unroll
            for (int rt = 0; rt < 4; ++rt)
                afr[rt] = *(const bf16x8*)(&Af[rt][arslot][0]);
        }
#pragma unroll
        for (int ct = 0; ct < 4; ++ct) {
            bf16x8 bfr = *(const bf16x8*)(&Bf[w * 4 + ct][lane][0]);
#pragma unroll
            for (int rt = 0; rt < 4; ++rt)
                acc[rt][ct] = __builtin_amdgcn_mfma_f32_16x16x32_bf16(afr[rt], bfr, acc[rt][ct], 0, 0, 0);
        }
        __syncthreads();
    }
    int rb = (lane >> 4) * 4, cc = lane & 15;
#pragma unroll
    for (int ct = 0; ct < 4; ++ct) {
        int cg = (w * 4 + ct) * 16 + cc;
        float s = bnS[cg], sh = bnB[cg];
#pragma unroll
        for (int rt = 0; rt < 4; ++rt)
#pragma unroll
            for (int q = 0; q < 4; ++q) {
                int r = row0 + rt * 16 + rb + q;
                if (r < rows)
                    outF[(size_t)r * H + cg] = f2bf(fmaxf(acc[rt][ct][q] * s + sh, 0.0f));
            }
    }
}

// ---------------- MFMA SAGE combine (kept for sliced fallback) ----------------
template <int COLS>
__launch_bounds__(256)
__global__ void combine_mfma(const u16* __restrict__ mean_, const u16* __restrict__ xd,
                             const u16* __restrict__ Wcat,
                             const float* __restrict__ bnS, const float* __restrict__ bnB,
                             u16* __restrict__ outF, int ostride, int out_c0,
                             int rows, int c0) {
    constexpr int NCT = COLS / 16;
    constexpr int CTW = NCT / 4;
    constexpr int PPT = (COLS * 4) / 256;
    __shared__ __align__(16) u16 Af[4][64][8];
    __shared__ __align__(16) u16 Bf[NCT][64][8];
    int tid = threadIdx.x;
    int w = tid >> 6, lane = tid & 63;
    int row0 = blockIdx.x * 64;
    int arow = tid >> 2, akg = tid & 3;
    bool arok = (row0 + arow) < rows;
    const u16* am = mean_ + (size_t)(row0 + arow) * H;
    const u16* ax = xd + (size_t)(row0 + arow) * H;
    int awslot = (akg * 16 + (arow & 15)) ^ (akg << 2);
    int arslot = lane ^ ((lane >> 4) << 2);
    int bc = tid % COLS;
    int bkg0 = (tid / COLS) * PPT;
    const u16* wp0 = Wcat + (size_t)(c0 + bc) * 512 + bkg0 * 8;

    f32x4 acc[4][CTW];
#pragma unroll
    for (int i = 0; i < 4; ++i)
#pragma unroll
        for (int j = 0; j < CTW; ++j) acc[i][j] = (f32x4){0.f, 0.f, 0.f, 0.f};

    for (int kb = 0; kb < 512; kb += 32) {
        uint4 av = make_uint4(0, 0, 0, 0);
        if (arok) {
            int kg = kb + akg * 8;
            av = (kg < 256) ? *(const uint4*)(am + kg) : *(const uint4*)(ax + (kg - 256));
        }
        *(uint4*)(&Af[arow >> 4][awslot][0]) = av;
#pragma unroll
        for (int q = 0; q < PPT; ++q) {
            uint4 wv = *(const uint4*)(wp0 + kb + q * 8);
            *(uint4*)(&Bf[bc >> 4][(bkg0 + q) * 16 + (bc & 15)][0]) = wv;
        }
        __syncthreads();
        bf16x8 afr[4];
#pragma unroll
        for (int rt = 0; rt < 4; ++rt)
            afr[rt] = *(const bf16x8*)(&Af[rt][arslot][0]);
#pragma unroll
        for (int ctl = 0; ctl < CTW; ++ctl) {
            bf16x8 b = *(const bf16x8*)(&Bf[w * CTW + ctl][lane][0]);
#pragma unroll
            for (int rt = 0; rt < 4; ++rt)
                acc[rt][ctl] = __builtin_amdgcn_mfma_f32_16x16x32_bf16(afr[rt], b, acc[rt][ctl], 0, 0, 0);
        }
        __syncthreads();
    }
    int rb = (lane >> 4) * 4;
    int ccol = lane & 15;
#pragma unroll
    for (int ctl = 0; ctl < CTW; ++ctl) {
        int clocal = (w * CTW + ctl) * 16 + ccol;
        int cg = c0 + clocal;
        float s = bnS[cg], sh = bnB[cg];
#pragma unroll
        for (int rt = 0; rt < 4; ++rt) {
#pragma unroll
            for (int q = 0; q < 4; ++q) {
                int r = row0 + rt * 16 + rb + q;
                if (r < rows)
                    outF[(size_t)r * ostride + out_c0 + clocal] = f2bf(fmaxf(acc[rt][ctl][q] * s + sh, 0.0f));
            }
        }
    }
}

// ---------------- MFMA edge-MLP head (validated) --------------
__launch_bounds__(256)
__global__ void mlp_mfma(const u16* __restrict__ accF, const int* __restrict__ sidx,
                         const int* __restrict__ ridx, const float* __restrict__ txr,
                         const u16* __restrict__ W1c, const float* __restrict__ b1,
                         const float* __restrict__ W2, const float* __restrict__ b2,
                         float* __restrict__ out, int M) {
    __shared__ __align__(16) u16 Af[4][64][8];
    __shared__ __align__(16) u16 Bf[16][64][8];
    __shared__ float red[4][64];
    int tid = threadIdx.x;
    int w = tid >> 6, lane = tid & 63;
    int row0 = blockIdx.x * 64;
    int arow = tid >> 2, akg = tid & 3;
    int grow = row0 + arow;
    bool arok = grow < M;
    int si = arok ? sidx[grow] : 0;
    int ri = arok ? ridx[grow] : 0;
    int awslot = (akg * 16 + (arow & 15)) ^ (akg << 2);
    int arslot = lane ^ ((lane >> 4) << 2);
    const u16* wp0 = W1c + (size_t)tid * 544;

    f32x4 acc[4][4];
#pragma unroll
    for (int i = 0; i < 4; ++i)
#pragma unroll
        for (int j = 0; j < 4; ++j) acc[i][j] = (f32x4){0.f, 0.f, 0.f, 0.f};

    for (int kb = 0; kb < 544; kb += 32) {
        uint4 av = make_uint4(0, 0, 0, 0);
        if (arok) {
            int kg = kb + akg * 8;
            if (kg < 256) av = *(const uint4*)(accF + (size_t)si * H + kg);
            else if (kg < 512) av = *(const uint4*)(accF + (size_t)ri * H + (kg - 256));
            else {
                float4 f0 = *(const float4*)(txr + (size_t)grow * 32 + (kg - 512));
                float4 f1 = *(const float4*)(txr + (size_t)grow * 32 + (kg - 512) + 4);
                av.x = pk2(f0.x, f0.y); av.y = pk2(f0.z, f0.w);
                av.z = pk2(f1.x, f1.y); av.w = pk2(f1.z, f1.w);
            }
        }
        *(uint4*)(&Af[arow >> 4][awslot][0]) = av;
#pragma unroll
        for (int q = 0; q < 4; ++q) {
            uint4 wv = *(const uint4*)(wp0 + kb + q * 8);
            *(uint4*)(&Bf[tid >> 4][q * 16 + (tid & 15)][0]) = wv;
        }
        __syncthreads();
        bf16x8 afr[4];
#pragma unroll
        for (int rt = 0; rt < 4; ++rt)
            afr[rt] = *(const bf16x8*)(&Af[rt][arslot][0]);
#pragma unroll
        for (int ctl = 0; ctl < 4; ++ctl) {
            bf16x8 b = *(const bf16x8*)(&Bf[w * 4 + ctl][lane][0]);
#pragma unroll
            for (int rt = 0; rt < 4; ++rt)
                acc[rt][ctl] = __builtin_amdgcn_mfma_f32_16x16x32_bf16(afr[rt], b, acc[rt][ctl], 0, 0, 0);
        }
        __syncthreads();
    }
    float part[4][4];
#pragma unroll
    for (int rt = 0; rt < 4; ++rt)
#pragma unroll
        for (int q = 0; q < 4; ++q) part[rt][q] = 0.0f;
#pragma unroll
    for (int ctl = 0; ctl < 4; ++ctl) {
        int cg = (w * 4 + ctl) * 16 + (lane & 15);
        float b1v = b1[cg], w2v = W2[cg];
#pragma unroll
        for (int rt = 0; rt < 4; ++rt)
#pragma unroll
            for (int q = 0; q < 4; ++q)
                part[rt][q] += fmaxf(acc[rt][ctl][q] + b1v, 0.0f) * w2v;
    }
    int rb = (lane >> 4) * 4;
#pragma unroll
    for (int rt = 0; rt < 4; ++rt)
#pragma unroll
        for (int q = 0; q < 4; ++q) {
            float p = part[rt][q];
            p += __shfl_xor(p, 1);
            p += __shfl_xor(p, 2);
            p += __shfl_xor(p, 4);
            p += __shfl_xor(p, 8);
            if ((lane & 15) == 0) red[w][rt * 16 + rb + q] = p;
        }
    __syncthreads();
    if (tid < 64) {
        int r = row0 + tid;
        if (r < M)
            out[r] = red[0][tid] + red[1][tid] + red[2][tid] + red[3][tid] + b2[0];
    }
}

// ---------------- host ----------------
static inline void fz(void* p, size_t bytes, hipStream_t s) {
    long long n = (long long)(bytes >> 2);
    int g = (int)(((n + 255) / 256 < 2048) ? (n + 255) / 256 : 2048);
    fillz_kernel<<<g, 256, 0, s>>>((u32*)p, n);
}
static inline size_t al256(size_t x) { return (x + 255) & ~(size_t)255; }

extern "C" void kernel_launch(void* const* d_in, const int* in_sizes, int n_in,
                              void* d_out, int out_size, void* d_ws, size_t ws_size,
                              hipStream_t stream) {
    const float* x_acc  = (const float*)d_in[0];
    const float* x_tx   = (const float*)d_in[1];
    const float* tx_raw = (const float*)d_in[2];
    const int* ei_sends = (const int*)d_in[3];
    const int* ei_recv  = (const int*)d_in[4];
    const int* sidx     = (const int*)d_in[5];
    const int* ridx     = (const int*)d_in[6];
    const float* W_acc  = (const float*)d_in[7];
    const float* b_acc  = (const float*)d_in[8];
    const float* W_tx   = (const float*)d_in[9];
    const float* b_tx   = (const float*)d_in[10];
    const float* Wl_at  = (const float*)d_in[11];
    const float* bl_at  = (const float*)d_in[12];
    const float* Wr_at  = (const float*)d_in[13];
    const float* Wl_ta  = (const float*)d_in[14];
    const float* bl_ta  = (const float*)d_in[15];
    const float* Wr_ta  = (const float*)d_in[16];
    const float* bng    = (const float*)d_in[17];
    const float* bnb    = (const float*)d_in[18];
    const float* bnm    = (const float*)d_in[19];
    const float* bnv    = (const float*)d_in[20];
    const float* W1     = (const float*)d_in[21];
    const float* b1     = (const float*)d_in[22];
    const float* W2     = (const float*)d_in[23];
    const float* b2     = (const float*)d_in[24];
    float* out = (float*)d_out;

    const size_t szFeatA = (size_t)NACC * H * 2;
    const size_t szFeatT = (size_t)NTX * H * 2;
    const size_t szCSR = al256((NTX + 1) * 4) + al256(4096) + al256((NTX + 1) * 4)
                       + al256((size_t)NE * 4) + al256((NACC + 1) * 4) + al256((size_t)NE * 4);
    const size_t szW = 3 * al256(256 * 512 * 2) + al256(256 * 544 * 2)
                     + 2 * al256(3 * 256 * 4) + 2 * al256(256 * 32 * 2);

    size_t needF = szCSR + szW + 2 * al256(szFeatA) + al256(szFeatT) + 65536;
    auto needS = [&](int S, int CC) {
        return 3 * al256(szFeatA) + szCSR + szW + 2 * al256((size_t)CC * H * 2)
             + al256((size_t)NTX * (H / S) * 2) + 65536;
    };
    int plan, S = 2, CC = 16384;
    if (needF <= ws_size)                { plan = 0; }
    else if (needS(2, 16384) <= ws_size) { plan = 1; S = 2; CC = 16384; }
    else if (needS(4, 16384) <= ws_size) { plan = 1; S = 4; CC = 16384; }
    else                                 { plan = 1; S = 4; CC = 2048; }

    char* wsp = (char*)d_ws;
    size_t off = 0;
    auto alloc = [&](size_t bytes) -> void* {
        void* p = wsp + off;
        off = al256(off + bytes);
        return p;
    };
    int* cnt   = (int*)alloc((NTX + 1) * 4);
    int* bsum  = (int*)alloc(4096);
    int* ptrT  = (int*)alloc((NTX + 1) * 4);
    int* permS = (int*)alloc((size_t)NE * 4);
    int* ptrA  = (int*)alloc((NACC + 1) * 4);
    int* permR = (int*)alloc((size_t)NE * 4);
    u16* Wc[3];
    Wc[0] = (u16*)alloc(256 * 512 * 2);
    Wc[1] = (u16*)alloc(256 * 512 * 2);
    Wc[2] = (u16*)alloc(256 * 512 * 2);
    u16* W1c = (u16*)alloc(256 * 544 * 2);
    float* bnS = (float*)alloc(3 * 256 * 4);
    float* bnB = (float*)alloc(3 * 256 * 4);
    u16* WbA = (u16*)alloc(256 * 32 * 2);
    u16* WbT = (u16*)alloc(256 * 32 * 2);
    u16* A0f = (u16*)alloc(szFeatA);
    u16* A1f = (u16*)alloc(szFeatA);

    // ---- weight prep ----
    wcat_kernel<<<256, 256, 0, stream>>>(Wl_ta, Wr_ta, Wc[0]);
    wcat_kernel<<<256, 256, 0, stream>>>(Wl_at, Wr_at, Wc[1]);
    wcat_kernel<<<256, 256, 0, stream>>>(Wl_ta + H * H, Wr_ta + H * H, Wc[2]);
    w1cvt_kernel<<<256, 256, 0, stream>>>(W1, W1c);
    wproj_kernel<<<256, 32, 0, stream>>>(W_acc, WbA, 16);
    wproj_kernel<<<256, 32, 0, stream>>>(W_tx, WbT, 32);
    bnprep_kernel<<<1, 256, 0, stream>>>(bl_ta, bng, bnb, bnm, bnv, bnS, bnB);
    bnprep_kernel<<<1, 256, 0, stream>>>(bl_at, bng, bnb, bnm, bnv, bnS + 256, bnB + 256);
    bnprep_kernel<<<1, 256, 0, stream>>>(bl_ta + H, bng + H, bnb + H, bnm + H, bnv + H,
                                         bnS + 512, bnB + 512);

    // ---- CSR sends (dst = tx) ----
    const int EG = (NE + 255) / 256;
    const int nbT = (NTX + 1023) / 1024, nbA = (NACC + 1023) / 1024;
    fz(cnt, (size_t)NTX * 4, stream);
    count_kernel<<<EG, 256, 0, stream>>>(ei_sends + NE, NE, cnt);
    scan1_kernel<<<nbT, 256, 0, stream>>>(cnt, NTX, ptrT, bsum);
    scan2_kernel<<<1, 1024, 0, stream>>>(bsum, nbT);
    scan3_kernel<<<(NTX + 256) / 256 + 1, 256, 0, stream>>>(ptrT, bsum, NTX, NE);
    fz(cnt, (size_t)NTX * 4, stream);
    fillcsr_kernel<<<EG, 256, 0, stream>>>(ei_sends, ei_sends + NE, NE, ptrT, cnt, permS);
    // ---- CSR recv (dst = acc) ----
    fz(cnt, (size_t)NACC * 4, stream);
    count_kernel<<<EG, 256, 0, stream>>>(ei_recv + NE, NE, cnt);
    scan1_kernel<<<nbA, 256, 0, stream>>>(cnt, NACC, ptrA, bsum);
    scan2_kernel<<<1, 1024, 0, stream>>>(bsum, nbA);
    scan3_kernel<<<(NACC + 256) / 256 + 1, 256, 0, stream>>>(ptrA, bsum, NACC, NE);
    fz(cnt, (size_t)NACC * 4, stream);
    fillcsr_kernel<<<EG, 256, 0, stream>>>(ei_recv, ei_recv + NE, NE, ptrA, cnt, permR);

    // ---- acc projection (MFMA) ----
    proj_mfma<16><<<(NACC + 127) / 128, 256, 0, stream>>>(x_acc, WbA, b_acc, A0f, NACC);

    const int gA = (NACC + 63) / 64, gM = (NM + 63) / 64;

    if (plan == 0) {
        // ======== PLAN FULL (fused gather-combine v2) ========
        u16* T = (u16*)alloc(szFeatT);
        proj_mfma<32><<<(NTX + 127) / 128, 256, 0, stream>>>(x_tx, WbT, b_tx, T, NTX);
        // L0 acc: gather T0 over recv, root A0f -> A1f (must precede in-place T overwrite)
        combine_gather<<<gA, 256, 0, stream>>>(T, ptrA, permR, A0f, Wc[0], bnS, bnB, A1f, NACC);
        // L0 tx: gather A0f over sends, root T0 -> T1 in place
        combine_gather<<<(NTX + 63) / 64, 256, 0, stream>>>(A0f, ptrT, permS, T, Wc[1],
                                                            bnS + 256, bnB + 256, T, NTX);
        // L1 acc: gather T1 over recv, root A1f -> A2 (reuse A0f)
        combine_gather<<<gA, 256, 0, stream>>>(T, ptrA, permR, A1f, Wc[2],
                                               bnS + 512, bnB + 512, A0f, NACC);
        mlp_mfma<<<gM, 256, 0, stream>>>(A0f, sidx, ridx, tx_raw, W1c, b1, W2, b2, out, NM);
    } else {
        // ======== PLAN SLICED (validated fallback) ========
        u16* meanbuf = (u16*)alloc(szFeatA);
        u16* T0c     = (u16*)alloc((size_t)CC * H * 2);
        u16* meanTc  = (u16*)alloc((size_t)CC * H * 2);
        const int WSL = H / S;
        u16* Tslice  = (u16*)alloc((size_t)NTX * WSL * 2);

        for (int s = 0; s < S; ++s) {
            int c0 = s * WSL;
            if (WSL == 128)
                proj2_kernel<32, 128><<<(NTX + 127) / 128, 256, 0, stream>>>(x_tx, W_tx, b_tx, Tslice, NTX, c0, WSL);
            else
                proj2_kernel<32, 64><<<(NTX + 127) / 128, 256, 0, stream>>>(x_tx, W_tx, b_tx, Tslice, NTX, c0, WSL);
            if (WSL == 128)
                gmean_kernel<128><<<(NACC + 7) / 8, 256, 0, stream>>>(Tslice, WSL, ptrA, permR, meanbuf, H, c0, NACC, 0);
            else
                gmean_kernel<64><<<(NACC + 15) / 16, 256, 0, stream>>>(Tslice, WSL, ptrA, permR, meanbuf, H, c0, NACC, 0);
        }
        combine_mfma<256><<<gA, 256, 0, stream>>>(meanbuf, A0f, Wc[0], bnS, bnB, A1f, H, 0, NACC, 0);
        for (int s = 0; s < S; ++s) {
            int c0 = s * WSL;
            for (int lo = 0; lo < NTX; lo += CC) {
                int cur = (NTX - lo < CC) ? (NTX - lo) : CC;
                proj2_kernel<32, 256><<<(cur + 127) / 128, 256, 0, stream>>>(x_tx + (size_t)lo * 32, W_tx, b_tx, T0c, cur, 0, H);
                gmean_kernel<256><<<(cur + 3) / 4, 256, 0, stream>>>(A0f, H, ptrT, permS, meanTc, H, 0, cur, lo);
                if (WSL == 128)
                    combine_mfma<128><<<(cur + 63) / 64, 256, 0, stream>>>(
                        meanTc, T0c, Wc[1], bnS + 256, bnB + 256,
                        Tslice + (size_t)lo * WSL, WSL, 0, cur, c0);
                else
                    combine_mfma<64><<<(cur + 63) / 64, 256, 0, stream>>>(
                        meanTc, T0c, Wc[1], bnS + 256, bnB + 256,
                        Tslice + (size_t)lo * WSL, WSL, 0, cur, c0);
            }
            if (WSL == 128)
                gmean_kernel<128><<<(NACC + 7) / 8, 256, 0, stream>>>(Tslice, WSL, ptrA, permR, meanbuf, H, c0, NACC, 0);
            else
                gmean_kernel<64><<<(NACC + 15) / 16, 256, 0, stream>>>(Tslice, WSL, ptrA, permR, meanbuf, H, c0, NACC, 0);
        }
        combine_mfma<256><<<gA, 256, 0, stream>>>(meanbuf, A1f, Wc[2], bnS + 512, bnB + 512, A0f, H, 0, NACC, 0);
        mlp_mfma<<<gM, 256, 0, stream>>>(A0f, sidx, ridx, tx_raw, W1c, b1, W2, b2, out, NM);
    }
}

// Round 9
// 1087.929 us; speedup vs baseline: 13.1051x; 1.0541x over previous
//
#include <hip/hip_runtime.h>
#include <hip/hip_bf16.h>

#define H 256
#define NACC 100000
#define NTX  300000
#define NE   600000
#define NM   300000

typedef unsigned short u16;
typedef unsigned int u32;
typedef __bf16 bf16x8 __attribute__((ext_vector_type(8)));
typedef float f32x4 __attribute__((ext_vector_type(4)));

__device__ __forceinline__ float bf2f(u32 u) {
    union { u32 i; float f; } v; v.i = u << 16; return v.f;
}
__device__ __forceinline__ u16 f2bf(float f) {
    union { float f; u32 i; } v; v.f = f;
    u32 r = v.i + 0x7FFFu + ((v.i >> 16) & 1u);
    return (u16)(r >> 16);
}
__device__ __forceinline__ u32 pk2(float a, float b) {
    return (u32)f2bf(a) | ((u32)f2bf(b) << 16);
}

// ---------------- zero fill (no hipMemsetAsync: breaks graph capture) ----------------
__global__ void fillz_kernel(u32* __restrict__ p, long long n) {
    long long i = (long long)blockIdx.x * blockDim.x + threadIdx.x;
    long long st = (long long)gridDim.x * blockDim.x;
    for (; i < n; i += st) p[i] = 0u;
}

// ---------------- weight prep ----------------
// plain concat [col][512] (used by sliced fallback)
__global__ void wcat_kernel(const float* __restrict__ Wl, const float* __restrict__ Wr,
                            u16* __restrict__ dst) {
    int c = blockIdx.x, t = threadIdx.x;
    dst[(size_t)c * 512 + t]       = f2bf(Wl[(size_t)c * 256 + t]);
    dst[(size_t)c * 512 + 256 + t] = f2bf(Wr[(size_t)c * 256 + t]);
}
// MFMA fragment-ordered concat: dst[((k>>5)*16 + c>>4)*512 + (((k&31)>>3)*16 + (c&15))*8 + (k&7)]
__global__ void wcat_frag_kernel(const float* __restrict__ Wl, const float* __restrict__ Wr,
                                 u16* __restrict__ dst) {
    int c = blockIdx.x, k = threadIdx.x;   // 256 x 512
    float v = (k < 256) ? Wl[(size_t)c * 256 + k] : Wr[(size_t)c * 256 + (k - 256)];
    int kstep = k >> 5, kg = (k & 31) >> 3, j = k & 7;
    dst[(size_t)((kstep * 16 + (c >> 4)) * 64 + kg * 16 + (c & 15)) * 8 + j] = f2bf(v);
}
// W1 fragment-ordered, K=544 (17 ksteps)
__global__ void w1frag_kernel(const float* __restrict__ W1, u16* __restrict__ dst) {
    int c = blockIdx.x;
    for (int k = threadIdx.x; k < 544; k += 256) {
        float v = W1[(size_t)c * 544 + k];
        int kstep = k >> 5, kg = (k & 31) >> 3, j = k & 7;
        dst[(size_t)((kstep * 16 + (c >> 4)) * 64 + kg * 16 + (c & 15)) * 8 + j] = f2bf(v);
    }
}
// project-weight to bf16 [256][32], zero-padded past K
__global__ void wproj_kernel(const float* __restrict__ W, u16* __restrict__ dst, int K) {
    int c = blockIdx.x, t = threadIdx.x;   // 32 threads
    dst[(size_t)c * 32 + t] = (t < K) ? f2bf(W[(size_t)c * K + t]) : (u16)0;
}
__global__ void bnprep_kernel(const float* __restrict__ bl, const float* __restrict__ g,
                              const float* __restrict__ be, const float* __restrict__ m,
                              const float* __restrict__ v,
                              float* __restrict__ S, float* __restrict__ B) {
    int c = threadIdx.x;
    float s = g[c] * rsqrtf(v[c] + 1e-5f);
    S[c] = s;
    B[c] = (bl[c] - m[c]) * s + be[c];
}

// ---------------- MFMA projection (validated round 7) ------
template <int KK>
__launch_bounds__(256)
__global__ void proj_mfma(const float* __restrict__ x, const u16* __restrict__ Wb,
                          const float* __restrict__ b, u16* __restrict__ out, int N) {
    __shared__ __align__(16) u16 Af[8][64][8];
    __shared__ __align__(16) u16 Bf[16][64][8];
    int tid = threadIdx.x;
    int w = tid >> 6, lane = tid & 63;
    int row0 = blockIdx.x * 128;
    {
        int r = tid >> 1, h = tid & 1;
        int gr = row0 + r;
        int rt = r >> 4, rr = r & 15;
        uint4 p0 = make_uint4(0, 0, 0, 0), p1 = p0;
        if (gr < N && (KK == 32 || h == 0)) {
            const float* xp = x + (size_t)gr * KK + h * 16;
            float4 f0 = *(const float4*)(xp);
            float4 f1 = *(const float4*)(xp + 4);
            float4 f2 = *(const float4*)(xp + 8);
            float4 f3 = *(const float4*)(xp + 12);
            p0 = make_uint4(pk2(f0.x, f0.y), pk2(f0.z, f0.w), pk2(f1.x, f1.y), pk2(f1.z, f1.w));
            p1 = make_uint4(pk2(f2.x, f2.y), pk2(f2.z, f2.w), pk2(f3.x, f3.y), pk2(f3.z, f3.w));
        }
        int kg0 = 2 * h;
        *(uint4*)(&Af[rt][(kg0 * 16 + rr) ^ (kg0 << 2)][0]) = p0;
        *(uint4*)(&Af[rt][((kg0 + 1) * 16 + rr) ^ ((kg0 + 1) << 2)][0]) = p1;
    }
    {
        const u16* wp = Wb + (size_t)tid * 32;
#pragma unroll
        for (int q = 0; q < 4; ++q) {
            uint4 wv = *(const uint4*)(wp + q * 8);
            *(uint4*)(&Bf[tid >> 4][q * 16 + (tid & 15)][0]) = wv;
        }
    }
    __syncthreads();
    int arslot = lane ^ ((lane >> 4) << 2);
    f32x4 acc[8][4];
#pragma unroll
    for (int rt = 0; rt < 8; ++rt) {
        bf16x8 afr = *(const bf16x8*)(&Af[rt][arslot][0]);
#pragma unroll
        for (int ct = 0; ct < 4; ++ct) {
            bf16x8 bfr = *(const bf16x8*)(&Bf[w * 4 + ct][lane][0]);
            acc[rt][ct] = __builtin_amdgcn_mfma_f32_16x16x32_bf16(
                afr, bfr, (f32x4){0.f, 0.f, 0.f, 0.f}, 0, 0, 0);
        }
    }
    int rb = (lane >> 4) * 4, cc = lane & 15;
#pragma unroll
    for (int ct = 0; ct < 4; ++ct) {
        int cg = (w * 4 + ct) * 16 + cc;
        float bv = b[cg];
#pragma unroll
        for (int rt = 0; rt < 8; ++rt)
#pragma unroll
            for (int q = 0; q < 4; ++q) {
                int r = row0 + rt * 16 + rb + q;
                if (r < N)
                    out[(size_t)r * H + cg] = f2bf(fmaxf(acc[rt][ct][q] + bv, 0.0f));
            }
    }
}

// ---------------- CSR build (validated) ----------------
__global__ void count_kernel(const int* __restrict__ dst, int E, int* __restrict__ cnt) {
    int e = blockIdx.x * blockDim.x + threadIdx.x;
    if (e < E) atomicAdd(&cnt[dst[e]], 1);
}
__global__ void scan1_kernel(const int* __restrict__ cnt, int N,
                             int* __restrict__ loc, int* __restrict__ bsum) {
    __shared__ int sh[256];
    int b = blockIdx.x, t = threadIdx.x;
    int base = b * 1024 + t * 4;
    int v0 = (base + 0 < N) ? cnt[base + 0] : 0;
    int v1 = (base + 1 < N) ? cnt[base + 1] : 0;
    int v2 = (base + 2 < N) ? cnt[base + 2] : 0;
    int v3 = (base + 3 < N) ? cnt[base + 3] : 0;
    int s = v0 + v1 + v2 + v3;
    sh[t] = s;
    __syncthreads();
    for (int o = 1; o < 256; o <<= 1) {
        int y = (t >= o) ? sh[t - o] : 0;
        __syncthreads();
        sh[t] += y;
        __syncthreads();
    }
    int run = sh[t] - s;
    if (base + 0 < N) loc[base + 0] = run; run += v0;
    if (base + 1 < N) loc[base + 1] = run; run += v1;
    if (base + 2 < N) loc[base + 2] = run; run += v2;
    if (base + 3 < N) loc[base + 3] = run;
    if (t == 0) bsum[b] = sh[255];
}
__global__ void scan2_kernel(int* __restrict__ bsum, int nb) {
    __shared__ int sh[1024];
    int t = threadIdx.x;
    int v = (t < nb) ? bsum[t] : 0;
    sh[t] = v;
    __syncthreads();
    for (int o = 1; o < 1024; o <<= 1) {
        int y = (t >= o) ? sh[t - o] : 0;
        __syncthreads();
        sh[t] += y;
        __syncthreads();
    }
    if (t < nb) bsum[t] = sh[t] - v;
}
__global__ void scan3_kernel(int* __restrict__ ptr, const int* __restrict__ bsum,
                             int N, int total) {
    int i = blockIdx.x * blockDim.x + threadIdx.x;
    if (i < N) ptr[i] += bsum[i >> 10];
    else if (i == N) ptr[N] = total;
}
__global__ void fillcsr_kernel(const int* __restrict__ src, const int* __restrict__ dst, int E,
                               const int* __restrict__ ptr, int* __restrict__ cur,
                               int* __restrict__ perm) {
    int e = blockIdx.x * blockDim.x + threadIdx.x;
    if (e < E) {
        int d = dst[e];
        int pos = ptr[d] + atomicAdd(&cur[d], 1);
        perm[pos] = src[e];
    }
}

// ---------------- gather-mean (kept for sliced fallback) ------------
template <int WS>
__launch_bounds__(256)
__global__ void gmean_kernel(const u16* __restrict__ feat, int fstride,
                             const int* __restrict__ ptr, const int* __restrict__ perm,
                             u16* __restrict__ out, int ostride, int c0,
                             int rows, int lo) {
    constexpr int LPD = WS / 4;
    constexpr int DPB = 256 / LPD;
    int g = threadIdx.x / LPD;
    int ln = threadIdx.x % LPD;
    int w = blockIdx.x * DPB + g;
    if (w >= rows) return;
    int d = lo + w;
    int e0 = ptr[d], e1 = ptr[d + 1];
    float a0 = 0.f, a1 = 0.f, a2 = 0.f, a3 = 0.f;
    for (int e = e0; e < e1; ++e) {
        int s = perm[e];
        uint2 v = *(const uint2*)(feat + (size_t)s * fstride + (ln << 2));
        a0 += bf2f(v.x & 0xffff); a1 += bf2f(v.x >> 16);
        a2 += bf2f(v.y & 0xffff); a3 += bf2f(v.y >> 16);
    }
    int deg = e1 - e0;
    float sc = (deg > 0) ? (1.0f / (float)deg) : 0.0f;
    uint2 pk;
    pk.x = pk2(a0 * sc, a1 * sc);
    pk.y = pk2(a2 * sc, a3 * sc);
    *(uint2*)(out + (size_t)w * ostride + c0 + (ln << 2)) = pk;
}

// ---------------- proj2 (kept for sliced fallback) ----------------
template <int K, int NC>
__launch_bounds__(256)
__global__ void proj2_kernel(const float* __restrict__ x, const float* __restrict__ W,
                             const float* __restrict__ b, u16* __restrict__ out,
                             int N, int c0, int ost) {
    __shared__ float xs[128][K + 4];
    constexpr int NG = 512 / NC;
    constexpr int RPT = 128 / NG;
    int tid = threadIdx.x;
    int row0 = blockIdx.x * 128;
    constexpr int NF4 = 128 * K / 4;
    for (int f = tid; f < NF4; f += 256) {
        int r = f / (K / 4), kq = (f % (K / 4)) * 4;
        int gr = row0 + r;
        float4 v = (gr < N) ? *(const float4*)(x + (size_t)gr * K + kq)
                            : make_float4(0.f, 0.f, 0.f, 0.f);
        *(float4*)&xs[r][kq] = v;
    }
    int lt2 = (tid % (NC / 2)) * 2;
    int g = tid / (NC / 2);
    float wa[K], wb[K];
    const float* wpa = W + (size_t)(c0 + lt2) * K;
#pragma unroll
    for (int k = 0; k < K; k += 4) {
        float4 va = *(const float4*)(wpa + k);
        float4 vb = *(const float4*)(wpa + K + k);
        wa[k] = va.x; wa[k + 1] = va.y; wa[k + 2] = va.z; wa[k + 3] = va.w;
        wb[k] = vb.x; wb[k + 1] = vb.y; wb[k + 2] = vb.z; wb[k + 3] = vb.w;
    }
    float b0 = b[c0 + lt2], b1 = b[c0 + lt2 + 1];
    __syncthreads();
#pragma unroll
    for (int rr = 0; rr < RPT; ++rr) {
        int r = g * RPT + rr;
        int gr = row0 + r;
        float a0 = b0, a1 = b1;
#pragma unroll
        for (int k = 0; k < K; k += 4) {
            float4 xv = *(const float4*)&xs[r][k];
            a0 += xv.x * wa[k] + xv.y * wa[k + 1] + xv.z * wa[k + 2] + xv.w * wa[k + 3];
            a1 += xv.x * wb[k] + xv.y * wb[k + 1] + xv.z * wb[k + 2] + xv.w * wb[k + 3];
        }
        if (gr < N) {
            u32 pk = (u32)f2bf(fmaxf(a0, 0.f)) | ((u32)f2bf(fmaxf(a1, 0.f)) << 16);
            *(u32*)(out + (size_t)gr * ost + lt2) = pk;
        }
    }
}

// ---------------- fused gather-mean + MFMA combine, v3: barrier-free K-loop ----------------
// Phase 1: block pre-gather of CSR mean into Am (fragment order). One barrier.
// Phase 2: K-loop with A from Am (kb<256) or DIRECT global xd frag loads (kb>=256),
//          B from DIRECT fragment-ordered WcF loads. No LDS staging, no barriers.
// One barrier before epilogue (in-place tx combine: all xd reads complete before stores).
__launch_bounds__(256)
__global__ void combine_gather(const u16* __restrict__ featG, const int* __restrict__ ptr,
                               const int* __restrict__ perm, const u16* __restrict__ xd,
                               const u16* __restrict__ WcF,
                               const float* __restrict__ bnS, const float* __restrict__ bnB,
                               u16* __restrict__ outF, int rows) {
    __shared__ __align__(16) u16 Am[8][4][64][8];   // 32 KB: mean half, fragment-ordered
    int tid = threadIdx.x;
    int w = tid >> 6, lane = tid & 63;
    int row0 = blockIdx.x * 64;

    // ---- phase 1: block-level gather-mean into Am ----
    {
        int r = tid >> 2, g = tid & 3;
        int grow = row0 + r;
        float s[64];
#pragma unroll
        for (int i = 0; i < 64; ++i) s[i] = 0.0f;
        float inv = 0.0f;
        if (grow < rows) {
            int e0 = ptr[grow], e1 = ptr[grow + 1];
            int dg = e1 - e0;
            inv = (dg > 0) ? 1.0f / (float)dg : 0.0f;
            int e = e0;
            for (; e + 1 < e1; e += 2) {
                int n0 = perm[e], n1 = perm[e + 1];
                const u16* p0 = featG + (size_t)n0 * H + g * 64;
                const u16* p1 = featG + (size_t)n1 * H + g * 64;
#pragma unroll
                for (int q = 0; q < 8; ++q) {
                    uint4 v0 = *(const uint4*)(p0 + q * 8);
                    uint4 v1 = *(const uint4*)(p1 + q * 8);
                    s[q * 8 + 0] += bf2f(v0.x & 0xffff) + bf2f(v1.x & 0xffff);
                    s[q * 8 + 1] += bf2f(v0.x >> 16)    + bf2f(v1.x >> 16);
                    s[q * 8 + 2] += bf2f(v0.y & 0xffff) + bf2f(v1.y & 0xffff);
                    s[q * 8 + 3] += bf2f(v0.y >> 16)    + bf2f(v1.y >> 16);
                    s[q * 8 + 4] += bf2f(v0.z & 0xffff) + bf2f(v1.z & 0xffff);
                    s[q * 8 + 5] += bf2f(v0.z >> 16)    + bf2f(v1.z >> 16);
                    s[q * 8 + 6] += bf2f(v0.w & 0xffff) + bf2f(v1.w & 0xffff);
                    s[q * 8 + 7] += bf2f(v0.w >> 16)    + bf2f(v1.w >> 16);
                }
            }
            if (e < e1) {
                int n0 = perm[e];
                const u16* p0 = featG + (size_t)n0 * H + g * 64;
#pragma unroll
                for (int q = 0; q < 8; ++q) {
                    uint4 v0 = *(const uint4*)(p0 + q * 8);
                    s[q * 8 + 0] += bf2f(v0.x & 0xffff);
                    s[q * 8 + 1] += bf2f(v0.x >> 16);
                    s[q * 8 + 2] += bf2f(v0.y & 0xffff);
                    s[q * 8 + 3] += bf2f(v0.y >> 16);
                    s[q * 8 + 4] += bf2f(v0.z & 0xffff);
                    s[q * 8 + 5] += bf2f(v0.z >> 16);
                    s[q * 8 + 6] += bf2f(v0.w & 0xffff);
                    s[q * 8 + 7] += bf2f(v0.w >> 16);
                }
            }
        }
        int rt = r >> 4, rr = r & 15;
#pragma unroll
        for (int q = 0; q < 8; ++q) {
            int kgg = g * 8 + q;                 // global kgroup 0..31
            int kbs = kgg >> 2, akg = kgg & 3;   // kb-step, in-step group
            uint4 pv;
            pv.x = pk2(s[q * 8 + 0] * inv, s[q * 8 + 1] * inv);
            pv.y = pk2(s[q * 8 + 2] * inv, s[q * 8 + 3] * inv);
            pv.z = pk2(s[q * 8 + 4] * inv, s[q * 8 + 5] * inv);
            pv.w = pk2(s[q * 8 + 6] * inv, s[q * 8 + 7] * inv);
            *(uint4*)(&Am[kbs][rt][(akg * 16 + rr) ^ (akg << 2)][0]) = pv;
        }
    }
    __syncthreads();

    // ---- phase 2: barrier-free K-loop ----
    int arslot = lane ^ ((lane >> 4) << 2);
    // direct xd A-fragment base pointers (row clamped; OOB rows never stored)
    const u16* xrow[4];
#pragma unroll
    for (int rt = 0; rt < 4; ++rt) {
        int r = row0 + rt * 16 + (lane & 15);
        if (r > rows - 1) r = rows - 1;
        xrow[rt] = xd + (size_t)r * H + (lane >> 4) * 8;
    }
    const u16* wbase = WcF + (size_t)(w * 4) * 512 + (size_t)lane * 8;

    f32x4 acc[4][4];
#pragma unroll
    for (int i = 0; i < 4; ++i)
#pragma unroll
        for (int j = 0; j < 4; ++j) acc[i][j] = (f32x4){0.f, 0.f, 0.f, 0.f};

#pragma unroll 4
    for (int kb = 0; kb < 512; kb += 32) {
        int kstep = kb >> 5;
        bf16x8 afr[4];
        if (kb < 256) {
#pragma unroll
            for (int rt = 0; rt < 4; ++rt)
                afr[rt] = *(const bf16x8*)(&Am[kstep][rt][arslot][0]);
        } else {
#pragma unroll
            for (int rt = 0; rt < 4; ++rt)
                afr[rt] = *(const bf16x8*)(xrow[rt] + (kb - 256));
        }
#pragma unroll
        for (int ct = 0; ct < 4; ++ct) {
            bf16x8 bfr = *(const bf16x8*)(wbase + (size_t)(kstep * 16 + ct) * 512);
#pragma unroll
            for (int rt = 0; rt < 4; ++rt)
                acc[rt][ct] = __builtin_amdgcn_mfma_f32_16x16x32_bf16(afr[rt], bfr, acc[rt][ct], 0, 0, 0);
        }
    }
    __syncthreads();   // in-place safety: all xd reads done before any store
    int rb = (lane >> 4) * 4, cc = lane & 15;
#pragma unroll
    for (int ct = 0; ct < 4; ++ct) {
        int cg = (w * 4 + ct) * 16 + cc;
        float s = bnS[cg], sh = bnB[cg];
#pragma unroll
        for (int rt = 0; rt < 4; ++rt)
#pragma unroll
            for (int q = 0; q < 4; ++q) {
                int r = row0 + rt * 16 + rb + q;
                if (r < rows)
                    outF[(size_t)r * H + cg] = f2bf(fmaxf(acc[rt][ct][q] * s + sh, 0.0f));
            }
    }
}

// ---------------- MFMA SAGE combine (kept for sliced fallback, plain Wcat) ----------------
template <int COLS>
__launch_bounds__(256)
__global__ void combine_mfma(const u16* __restrict__ mean_, const u16* __restrict__ xd,
                             const u16* __restrict__ Wcat,
                             const float* __restrict__ bnS, const float* __restrict__ bnB,
                             u16* __restrict__ outF, int ostride, int out_c0,
                             int rows, int c0) {
    constexpr int NCT = COLS / 16;
    constexpr int CTW = NCT / 4;
    constexpr int PPT = (COLS * 4) / 256;
    __shared__ __align__(16) u16 Af[4][64][8];
    __shared__ __align__(16) u16 Bf[NCT][64][8];
    int tid = threadIdx.x;
    int w = tid >> 6, lane = tid & 63;
    int row0 = blockIdx.x * 64;
    int arow = tid >> 2, akg = tid & 3;
    bool arok = (row0 + arow) < rows;
    const u16* am = mean_ + (size_t)(row0 + arow) * H;
    const u16* ax = xd + (size_t)(row0 + arow) * H;
    int awslot = (akg * 16 + (arow & 15)) ^ (akg << 2);
    int arslot = lane ^ ((lane >> 4) << 2);
    int bc = tid % COLS;
    int bkg0 = (tid / COLS) * PPT;
    const u16* wp0 = Wcat + (size_t)(c0 + bc) * 512 + bkg0 * 8;

    f32x4 acc[4][CTW];
#pragma unroll
    for (int i = 0; i < 4; ++i)
#pragma unroll
        for (int j = 0; j < CTW; ++j) acc[i][j] = (f32x4){0.f, 0.f, 0.f, 0.f};

    for (int kb = 0; kb < 512; kb += 32) {
        uint4 av = make_uint4(0, 0, 0, 0);
        if (arok) {
            int kg = kb + akg * 8;
            av = (kg < 256) ? *(const uint4*)(am + kg) : *(const uint4*)(ax + (kg - 256));
        }
        *(uint4*)(&Af[arow >> 4][awslot][0]) = av;
#pragma unroll
        for (int q = 0; q < PPT; ++q) {
            uint4 wv = *(const uint4*)(wp0 + kb + q * 8);
            *(uint4*)(&Bf[bc >> 4][(bkg0 + q) * 16 + (bc & 15)][0]) = wv;
        }
        __syncthreads();
        bf16x8 afr[4];
#pragma unroll
        for (int rt = 0; rt < 4; ++rt)
            afr[rt] = *(const bf16x8*)(&Af[rt][arslot][0]);
#pragma unroll
        for (int ctl = 0; ctl < CTW; ++ctl) {
            bf16x8 b = *(const bf16x8*)(&Bf[w * CTW + ctl][lane][0]);
#pragma unroll
            for (int rt = 0; rt < 4; ++rt)
                acc[rt][ctl] = __builtin_amdgcn_mfma_f32_16x16x32_bf16(afr[rt], b, acc[rt][ctl], 0, 0, 0);
        }
        __syncthreads();
    }
    int rb = (lane >> 4) * 4;
    int ccol = lane & 15;
#pragma unroll
    for (int ctl = 0; ctl < CTW; ++ctl) {
        int clocal = (w * CTW + ctl) * 16 + ccol;
        int cg = c0 + clocal;
        float s = bnS[cg], sh = bnB[cg];
#pragma unroll
        for (int rt = 0; rt < 4; ++rt) {
#pragma unroll
            for (int q = 0; q < 4; ++q) {
                int r = row0 + rt * 16 + rb + q;
                if (r < rows)
                    outF[(size_t)r * ostride + out_c0 + clocal] = f2bf(fmaxf(acc[rt][ctl][q] * s + sh, 0.0f));
            }
        }
    }
}

// ---------------- MFMA edge-MLP head v2: B direct from fragment-ordered W1F --------------
__launch_bounds__(256)
__global__ void mlp_mfma(const u16* __restrict__ accF, const int* __restrict__ sidx,
                         const int* __restrict__ ridx, const float* __restrict__ txr,
                         const u16* __restrict__ W1F, const float* __restrict__ b1,
                         const float* __restrict__ W2, const float* __restrict__ b2,
                         float* __restrict__ out, int M) {
    __shared__ __align__(16) u16 Af[4][64][8];
    __shared__ float red[4][64];
    int tid = threadIdx.x;
    int w = tid >> 6, lane = tid & 63;
    int row0 = blockIdx.x * 64;
    int arow = tid >> 2, akg = tid & 3;
    int grow = row0 + arow;
    bool arok = grow < M;
    int si = arok ? sidx[grow] : 0;
    int ri = arok ? ridx[grow] : 0;
    int awslot = (akg * 16 + (arow & 15)) ^ (akg << 2);
    int arslot = lane ^ ((lane >> 4) << 2);
    const u16* wbase = W1F + (size_t)(w * 4) * 512 + (size_t)lane * 8;

    f32x4 acc[4][4];
#pragma unroll
    for (int i = 0; i < 4; ++i)
#pragma unroll
        for (int j = 0; j < 4; ++j) acc[i][j] = (f32x4){0.f, 0.f, 0.f, 0.f};

    for (int kb = 0; kb < 544; kb += 32) {
        uint4 av = make_uint4(0, 0, 0, 0);
        if (arok) {
            int kg = kb + akg * 8;
            if (kg < 256) av = *(const uint4*)(accF + (size_t)si * H + kg);
            else if (kg < 512) av = *(const uint4*)(accF + (size_t)ri * H + (kg - 256));
            else {
                float4 f0 = *(const float4*)(txr + (size_t)grow * 32 + (kg - 512));
                float4 f1 = *(const float4*)(txr + (size_t)grow * 32 + (kg - 512) + 4);
                av.x = pk2(f0.x, f0.y); av.y = pk2(f0.z, f0.w);
                av.z = pk2(f1.x, f1.y); av.w = pk2(f1.z, f1.w);
            }
        }
        *(uint4*)(&Af[arow >> 4][awslot][0]) = av;
        __syncthreads();
        int kstep = kb >> 5;
        bf16x8 afr[4];
#pragma unroll
        for (int rt = 0; rt < 4; ++rt)
            afr[rt] = *(const bf16x8*)(&Af[rt][arslot][0]);
#pragma unroll
        for (int ct = 0; ct < 4; ++ct) {
            bf16x8 bfr = *(const bf16x8*)(wbase + (size_t)(kstep * 16 + ct) * 512);
#pragma unroll
            for (int rt = 0; rt < 4; ++rt)
                acc[rt][ct] = __builtin_amdgcn_mfma_f32_16x16x32_bf16(afr[rt], bfr, acc[rt][ct], 0, 0, 0);
        }
        __syncthreads();
    }
    float part[4][4];
#pragma unroll
    for (int rt = 0; rt < 4; ++rt)
#pragma unroll
        for (int q = 0; q < 4; ++q) part[rt][q] = 0.0f;
#pragma unroll
    for (int ct = 0; ct < 4; ++ct) {
        int cg = (w * 4 + ct) * 16 + (lane & 15);
        float b1v = b1[cg], w2v = W2[cg];
#pragma unroll
        for (int rt = 0; rt < 4; ++rt)
#pragma unroll
            for (int q = 0; q < 4; ++q)
                part[rt][q] += fmaxf(acc[rt][ct][q] + b1v, 0.0f) * w2v;
    }
    int rb = (lane >> 4) * 4;
#pragma unroll
    for (int rt = 0; rt < 4; ++rt)
#pragma unroll
        for (int q = 0; q < 4; ++q) {
            float p = part[rt][q];
            p += __shfl_xor(p, 1);
            p += __shfl_xor(p, 2);
            p += __shfl_xor(p, 4);
            p += __shfl_xor(p, 8);
            if ((lane & 15) == 0) red[w][rt * 16 + rb + q] = p;
        }
    __syncthreads();
    if (tid < 64) {
        int r = row0 + tid;
        if (r < M)
            out[r] = red[0][tid] + red[1][tid] + red[2][tid] + red[3][tid] + b2[0];
    }
}

// ---------------- host ----------------
static inline void fz(void* p, size_t bytes, hipStream_t s) {
    long long n = (long long)(bytes >> 2);
    int g = (int)(((n + 255) / 256 < 2048) ? (n + 255) / 256 : 2048);
    fillz_kernel<<<g, 256, 0, s>>>((u32*)p, n);
}
static inline size_t al256(size_t x) { return (x + 255) & ~(size_t)255; }

extern "C" void kernel_launch(void* const* d_in, const int* in_sizes, int n_in,
                              void* d_out, int out_size, void* d_ws, size_t ws_size,
                              hipStream_t stream) {
    const float* x_acc  = (const float*)d_in[0];
    const float* x_tx   = (const float*)d_in[1];
    const float* tx_raw = (const float*)d_in[2];
    const int* ei_sends = (const int*)d_in[3];
    const int* ei_recv  = (const int*)d_in[4];
    const int* sidx     = (const int*)d_in[5];
    const int* ridx     = (const int*)d_in[6];
    const float* W_acc  = (const float*)d_in[7];
    const float* b_acc  = (const float*)d_in[8];
    const float* W_tx   = (const float*)d_in[9];
    const float* b_tx   = (const float*)d_in[10];
    const float* Wl_at  = (const float*)d_in[11];
    const float* bl_at  = (const float*)d_in[12];
    const float* Wr_at  = (const float*)d_in[13];
    const float* Wl_ta  = (const float*)d_in[14];
    const float* bl_ta  = (const float*)d_in[15];
    const float* Wr_ta  = (const float*)d_in[16];
    const float* bng    = (const float*)d_in[17];
    const float* bnb    = (const float*)d_in[18];
    const float* bnm    = (const float*)d_in[19];
    const float* bnv    = (const float*)d_in[20];
    const float* W1     = (const float*)d_in[21];
    const float* b1     = (const float*)d_in[22];
    const float* W2     = (const float*)d_in[23];
    const float* b2     = (const float*)d_in[24];
    float* out = (float*)d_out;

    const size_t szFeatA = (size_t)NACC * H * 2;
    const size_t szFeatT = (size_t)NTX * H * 2;
    const size_t szCSR = al256((NTX + 1) * 4) + al256(4096) + al256((NTX + 1) * 4)
                       + al256((size_t)NE * 4) + al256((NACC + 1) * 4) + al256((size_t)NE * 4);
    const size_t szW = 3 * al256(256 * 512 * 2) + 3 * al256(16 * 16 * 64 * 8 * 2)
                     + al256(17 * 16 * 64 * 8 * 2)
                     + 2 * al256(3 * 256 * 4) + 2 * al256(256 * 32 * 2);

    size_t needF = szCSR + szW + 2 * al256(szFeatA) + al256(szFeatT) + 65536;
    auto needS = [&](int S, int CC) {
        return 3 * al256(szFeatA) + szCSR + szW + 2 * al256((size_t)CC * H * 2)
             + al256((size_t)NTX * (H / S) * 2) + 65536;
    };
    int plan, S = 2, CC = 16384;
    if (needF <= ws_size)                { plan = 0; }
    else if (needS(2, 16384) <= ws_size) { plan = 1; S = 2; CC = 16384; }
    else if (needS(4, 16384) <= ws_size) { plan = 1; S = 4; CC = 16384; }
    else                                 { plan = 1; S = 4; CC = 2048; }

    char* wsp = (char*)d_ws;
    size_t off = 0;
    auto alloc = [&](size_t bytes) -> void* {
        void* p = wsp + off;
        off = al256(off + bytes);
        return p;
    };
    int* cnt   = (int*)alloc((NTX + 1) * 4);
    int* bsum  = (int*)alloc(4096);
    int* ptrT  = (int*)alloc((NTX + 1) * 4);
    int* permS = (int*)alloc((size_t)NE * 4);
    int* ptrA  = (int*)alloc((NACC + 1) * 4);
    int* permR = (int*)alloc((size_t)NE * 4);
    u16* Wc[3];
    Wc[0] = (u16*)alloc(256 * 512 * 2);
    Wc[1] = (u16*)alloc(256 * 512 * 2);
    Wc[2] = (u16*)alloc(256 * 512 * 2);
    u16* WcF[3];
    WcF[0] = (u16*)alloc(16 * 16 * 64 * 8 * 2);
    WcF[1] = (u16*)alloc(16 * 16 * 64 * 8 * 2);
    WcF[2] = (u16*)alloc(16 * 16 * 64 * 8 * 2);
    u16* W1F = (u16*)alloc(17 * 16 * 64 * 8 * 2);
    float* bnS = (float*)alloc(3 * 256 * 4);
    float* bnB = (float*)alloc(3 * 256 * 4);
    u16* WbA = (u16*)alloc(256 * 32 * 2);
    u16* WbT = (u16*)alloc(256 * 32 * 2);
    u16* A0f = (u16*)alloc(szFeatA);
    u16* A1f = (u16*)alloc(szFeatA);

    // ---- weight prep ----
    wcat_kernel<<<256, 256, 0, stream>>>(Wl_ta, Wr_ta, Wc[0]);
    wcat_kernel<<<256, 256, 0, stream>>>(Wl_at, Wr_at, Wc[1]);
    wcat_kernel<<<256, 256, 0, stream>>>(Wl_ta + H * H, Wr_ta + H * H, Wc[2]);
    wcat_frag_kernel<<<256, 512, 0, stream>>>(Wl_ta, Wr_ta, WcF[0]);
    wcat_frag_kernel<<<256, 512, 0, stream>>>(Wl_at, Wr_at, WcF[1]);
    wcat_frag_kernel<<<256, 512, 0, stream>>>(Wl_ta + H * H, Wr_ta + H * H, WcF[2]);
    w1frag_kernel<<<256, 256, 0, stream>>>(W1, W1F);
    wproj_kernel<<<256, 32, 0, stream>>>(W_acc, WbA, 16);
    wproj_kernel<<<256, 32, 0, stream>>>(W_tx, WbT, 32);
    bnprep_kernel<<<1, 256, 0, stream>>>(bl_ta, bng, bnb, bnm, bnv, bnS, bnB);
    bnprep_kernel<<<1, 256, 0, stream>>>(bl_at, bng, bnb, bnm, bnv, bnS + 256, bnB + 256);
    bnprep_kernel<<<1, 256, 0, stream>>>(bl_ta + H, bng + H, bnb + H, bnm + H, bnv + H,
                                         bnS + 512, bnB + 512);

    // ---- CSR sends (dst = tx) ----
    const int EG = (NE + 255) / 256;
    const int nbT = (NTX + 1023) / 1024, nbA = (NACC + 1023) / 1024;
    fz(cnt, (size_t)NTX * 4, stream);
    count_kernel<<<EG, 256, 0, stream>>>(ei_sends + NE, NE, cnt);
    scan1_kernel<<<nbT, 256, 0, stream>>>(cnt, NTX, ptrT, bsum);
    scan2_kernel<<<1, 1024, 0, stream>>>(bsum, nbT);
    scan3_kernel<<<(NTX + 256) / 256 + 1, 256, 0, stream>>>(ptrT, bsum, NTX, NE);
    fz(cnt, (size_t)NTX * 4, stream);
    fillcsr_kernel<<<EG, 256, 0, stream>>>(ei_sends, ei_sends + NE, NE, ptrT, cnt, permS);
    // ---- CSR recv (dst = acc) ----
    fz(cnt, (size_t)NACC * 4, stream);
    count_kernel<<<EG, 256, 0, stream>>>(ei_recv + NE, NE, cnt);
    scan1_kernel<<<nbA, 256, 0, stream>>>(cnt, NACC, ptrA, bsum);
    scan2_kernel<<<1, 1024, 0, stream>>>(bsum, nbA);
    scan3_kernel<<<(NACC + 256) / 256 + 1, 256, 0, stream>>>(ptrA, bsum, NACC, NE);
    fz(cnt, (size_t)NACC * 4, stream);
    fillcsr_kernel<<<EG, 256, 0, stream>>>(ei_recv, ei_recv + NE, NE, ptrA, cnt, permR);

    // ---- acc projection (MFMA) ----
    proj_mfma<16><<<(NACC + 127) / 128, 256, 0, stream>>>(x_acc, WbA, b_acc, A0f, NACC);

    const int gA = (NACC + 63) / 64, gM = (NM + 63) / 64;

    if (plan == 0) {
        // ======== PLAN FULL (fused gather-combine v3, barrier-free K-loop) ========
        u16* T = (u16*)alloc(szFeatT);
        proj_mfma<32><<<(NTX + 127) / 128, 256, 0, stream>>>(x_tx, WbT, b_tx, T, NTX);
        // L0 acc: gather T0 over recv, root A0f -> A1f (must precede in-place T overwrite)
        combine_gather<<<gA, 256, 0, stream>>>(T, ptrA, permR, A0f, WcF[0], bnS, bnB, A1f, NACC);
        // L0 tx: gather A0f over sends, root T0 -> T1 in place
        combine_gather<<<(NTX + 63) / 64, 256, 0, stream>>>(A0f, ptrT, permS, T, WcF[1],
                                                            bnS + 256, bnB + 256, T, NTX);
        // L1 acc: gather T1 over recv, root A1f -> A2 (reuse A0f)
        combine_gather<<<gA, 256, 0, stream>>>(T, ptrA, permR, A1f, WcF[2],
                                               bnS + 512, bnB + 512, A0f, NACC);
        mlp_mfma<<<gM, 256, 0, stream>>>(A0f, sidx, ridx, tx_raw, W1F, b1, W2, b2, out, NM);
    } else {
        // ======== PLAN SLICED (validated fallback) ========
        u16* meanbuf = (u16*)alloc(szFeatA);
        u16* T0c     = (u16*)alloc((size_t)CC * H * 2);
        u16* meanTc  = (u16*)alloc((size_t)CC * H * 2);
        const int WSL = H / S;
        u16* Tslice  = (u16*)alloc((size_t)NTX * WSL * 2);

        for (int s = 0; s < S; ++s) {
            int c0 = s * WSL;
            if (WSL == 128)
                proj2_kernel<32, 128><<<(NTX + 127) / 128, 256, 0, stream>>>(x_tx, W_tx, b_tx, Tslice, NTX, c0, WSL);
            else
                proj2_kernel<32, 64><<<(NTX + 127) / 128, 256, 0, stream>>>(x_tx, W_tx, b_tx, Tslice, NTX, c0, WSL);
            if (WSL == 128)
                gmean_kernel<128><<<(NACC + 7) / 8, 256, 0, stream>>>(Tslice, WSL, ptrA, permR, meanbuf, H, c0, NACC, 0);
            else
                gmean_kernel<64><<<(NACC + 15) / 16, 256, 0, stream>>>(Tslice, WSL, ptrA, permR, meanbuf, H, c0, NACC, 0);
        }
        combine_mfma<256><<<gA, 256, 0, stream>>>(meanbuf, A0f, Wc[0], bnS, bnB, A1f, H, 0, NACC, 0);
        for (int s = 0; s < S; ++s) {
            int c0 = s * WSL;
            for (int lo = 0; lo < NTX; lo += CC) {
                int cur = (NTX - lo < CC) ? (NTX - lo) : CC;
                proj2_kernel<32, 256><<<(cur + 127) / 128, 256, 0, stream>>>(x_tx + (size_t)lo * 32, W_tx, b_tx, T0c, cur, 0, H);
                gmean_kernel<256><<<(cur + 3) / 4, 256, 0, stream>>>(A0f, H, ptrT, permS, meanTc, H, 0, cur, lo);
                if (WSL == 128)
                    combine_mfma<128><<<(cur + 63) / 64, 256, 0, stream>>>(
                        meanTc, T0c, Wc[1], bnS + 256, bnB + 256,
                        Tslice + (size_t)lo * WSL, WSL, 0, cur, c0);
                else
                    combine_mfma<64><<<(cur + 63) / 64, 256, 0, stream>>>(
                        meanTc, T0c, Wc[1], bnS + 256, bnB + 256,
                        Tslice + (size_t)lo * WSL, WSL, 0, cur, c0);
            }
            if (WSL == 128)
                gmean_kernel<128><<<(NACC + 7) / 8, 256, 0, stream>>>(Tslice, WSL, ptrA, permR, meanbuf, H, c0, NACC, 0);
            else
                gmean_kernel<64><<<(NACC + 15) / 16, 256, 0, stream>>>(Tslice, WSL, ptrA, permR, meanbuf, H, c0, NACC, 0);
        }
        combine_mfma<256><<<gA, 256, 0, stream>>>(meanbuf, A1f, Wc[2], bnS + 512, bnB + 512, A0f, H, 0, NACC, 0);
        mlp_mfma<<<gM, 256, 0, stream>>>(A0f, sidx, ridx, tx_raw, W1F, b1, W2, b2, out, NM);
    }
}